// Round 1
// baseline (13924.081 us; speedup 1.0000x reference)
//
#include <hip/hip_runtime.h>
#include <hip/hip_bf16.h>
#include <math.h>

// Problem constants (from reference)
#define NNODE 10000
#define NEDGE 320000
#define INC   64
#define C     256   // HID == OUT_C == 256

// ---------------------------------------------------------------------------
// Transpose W [rows x cols] -> WT [cols x rows]
// ---------------------------------------------------------------------------
__global__ void transpose_k(const float* __restrict__ W, float* __restrict__ WT,
                            int rows, int cols) {
    int idx = blockIdx.x * 256 + threadIdx.x;
    if (idx < rows * cols) {
        int r = idx / cols, c = idx - r * cols;
        WT[c * rows + r] = W[r * cols + c];
    }
}

// ---------------------------------------------------------------------------
// Linear: H[n, 256] = act(X)[n, K] @ WT[K, 256] + b
// 8 rows per block, 256 threads (one output column per thread).
// ---------------------------------------------------------------------------
template <int K, bool RELU_IN>
__global__ __launch_bounds__(256) void linear_k(const float* __restrict__ X,
                                                const float* __restrict__ WT,
                                                const float* __restrict__ B,
                                                float* __restrict__ H) {
    __shared__ float xs[8 * K];
    const int t = threadIdx.x;
    const size_t rb = (size_t)blockIdx.x * 8;

    // coalesced load of 8 input rows (contiguous 8*K floats)
    for (int i = t; i < 8 * K; i += 256) {
        float v = X[rb * K + i];
        if (RELU_IN) v = fmaxf(v, 0.f);
        xs[i] = v;
    }
    __syncthreads();

    float acc[8];
    const float bv = B[t];
#pragma unroll
    for (int r = 0; r < 8; ++r) acc[r] = bv;

    for (int k = 0; k < K; ++k) {
        float w = WT[k * 256 + t];   // coalesced; broadcast xs across lanes
#pragma unroll
        for (int r = 0; r < 8; ++r) acc[r] = fmaf(xs[r * K + k], w, acc[r]);
    }
#pragma unroll
    for (int r = 0; r < 8; ++r) H[(rb + r) * 256 + t] = acc[r];
}

// ---------------------------------------------------------------------------
// Fused edge kernel: per edge e (incl. self loops):
//   cat = [h[d], h[s]]  (512)
//   hid = relu(Ws1 @ cat + bs1)   (256)
//   score = sigmoid(dot(Ws2, hid) + bs2)
//   atomically: AGG[d] += score * h[s]
// 16 edges per workgroup of 256 threads; 16 threads per edge, each thread
// computes 16 of the 256 hidden outputs (2 tiles of 8 accumulators).
// ---------------------------------------------------------------------------
#define EB 16              // edges per block
#define CATSTRIDE 516      // 512 + 4 floats pad: uniform bank spread for b128

__global__ __launch_bounds__(256) void edge_k(const float* __restrict__ H,
                                              const int* __restrict__ EI,
                                              const float* __restrict__ Ws1,
                                              const float* __restrict__ bs1,
                                              const float* __restrict__ Ws2,
                                              const float* __restrict__ bs2,
                                              float* __restrict__ AGG) {
    __shared__ float cat[EB][CATSTRIDE];
    __shared__ int   sl[EB], dl[EB];
    __shared__ float sc[EB];
    __shared__ float swave[4][EB];

    const int t = threadIdx.x;
    const int ebase = blockIdx.x * EB;

    // --- edge indices (incl. self loops) ---
    if (t < EB) {
        int e = ebase + t;
        int s = 0, d = -1;
        if (e < NEDGE)              { s = EI[e]; d = EI[NEDGE + e]; }
        else if (e < NEDGE + NNODE) { s = d = e - NEDGE; }
        sl[t] = s; dl[t] = d;
    }
    __syncthreads();

    // --- gather xi (= h[d]) -> cols [0,256), xj (= h[s]) -> cols [256,512) ---
    {
        const int e    = t & 15;
        const int half = (t >> 4) & 1;       // 0: xi (dst), 1: xj (src)
        const int seg  = t >> 5;             // 0..7, 32 floats each
        const int node = half ? sl[e] : dl[e];
        float4* dst = (float4*)&cat[e][half * 256 + seg * 32];
        if (node >= 0) {
            const float4* srcp = (const float4*)(H + (size_t)node * 256 + seg * 32);
#pragma unroll
            for (int i = 0; i < 8; ++i) dst[i] = srcp[i];
        } else {
            float4 z = {0.f, 0.f, 0.f, 0.f};
#pragma unroll
            for (int i = 0; i < 8; ++i) dst[i] = z;
        }
    }
    __syncthreads();

    // --- edge MLP: 16 hidden outputs per thread ---
    const int e  = t & 15;
    const int og = t >> 4;                   // 0..15 -> output base og*16
    float score_acc = 0.f;
    const float4* catrow = (const float4*)&cat[e][0];

#pragma unroll 1
    for (int ot = 0; ot < 2; ++ot) {
        const int ob = og * 16 + ot * 8;
        float acc[8];
#pragma unroll
        for (int j = 0; j < 8; ++j) acc[j] = bs1[ob + j];
        const float* wp = Ws1 + (size_t)ob * 512;
        for (int kt = 0; kt < 128; ++kt) {
            float4 c = catrow[kt];           // ds_read_b128, broadcast x4
#pragma unroll
            for (int j = 0; j < 8; ++j) {
                float4 w = *(const float4*)(wp + j * 512 + kt * 4);
                acc[j] = fmaf(c.x, w.x, acc[j]);
                acc[j] = fmaf(c.y, w.y, acc[j]);
                acc[j] = fmaf(c.z, w.z, acc[j]);
                acc[j] = fmaf(c.w, w.w, acc[j]);
            }
        }
#pragma unroll
        for (int j = 0; j < 8; ++j)
            score_acc = fmaf(fmaxf(acc[j], 0.f), Ws2[ob + j], score_acc);
    }

    // --- reduce score over the 16 threads of each edge ---
    float s = score_acc;
    s += __shfl_down(s, 32);
    s += __shfl_down(s, 16);
    const int lane = t & 63, w = t >> 6;
    if (lane < EB) swave[w][lane] = s;
    __syncthreads();
    if (t < EB) {
        float z = bs2[0] + swave[0][t] + swave[1][t] + swave[2][t] + swave[3][t];
        sc[t] = 1.f / (1.f + expf(-z));
    }
    __syncthreads();

    // --- scatter: AGG[d] += score * xj ---
#pragma unroll 1
    for (int e2 = 0; e2 < EB; ++e2) {
        int d = dl[e2];
        if (d >= 0) {
            float v = sc[e2] * cat[e2][256 + t];
            atomicAdd(AGG + (size_t)d * 256 + t, v);
        }
    }
}

// ---------------------------------------------------------------------------
extern "C" void kernel_launch(void* const* d_in, const int* in_sizes, int n_in,
                              void* d_out, int out_size, void* d_ws, size_t ws_size,
                              hipStream_t stream) {
    const float* x    = (const float*)d_in[0];
    const int*   ei   = (const int*)d_in[1];

    const float* Wl1  = (const float*)d_in[2];
    const float* bl1  = (const float*)d_in[3];
    const float* Ws11 = (const float*)d_in[4];
    const float* bs11 = (const float*)d_in[5];
    const float* Ws21 = (const float*)d_in[6];
    const float* bs21 = (const float*)d_in[7];

    const float* Wl2  = (const float*)d_in[8];
    const float* bl2  = (const float*)d_in[9];
    const float* Ws12 = (const float*)d_in[10];
    const float* bs12 = (const float*)d_in[11];
    const float* Ws22 = (const float*)d_in[12];
    const float* bs22 = (const float*)d_in[13];

    const float* Wl3  = (const float*)d_in[14];
    const float* bl3  = (const float*)d_in[15];
    const float* Ws13 = (const float*)d_in[16];
    const float* bs13 = (const float*)d_in[17];
    const float* Ws23 = (const float*)d_in[18];
    const float* bs23 = (const float*)d_in[19];

    float* out = (float*)d_out;

    // workspace layout (floats)
    float* ws   = (float*)d_ws;
    float* WT1  = ws;                 // 64*256
    float* WT2  = WT1 + 64 * 256;     // 256*256
    float* WT3  = WT2 + 256 * 256;    // 256*256
    float* hbuf = WT3 + 256 * 256;    // N*256
    float* agg  = hbuf + NNODE * 256; // N*256

    const size_t NB = (size_t)NNODE * 256 * sizeof(float);
    const int nEdgeBlocks = (NEDGE + NNODE) / EB;   // 330000/16 = 20625
    const int nLinBlocks  = NNODE / 8;              // 1250

    // weight transposes (graph-capture-safe, deterministic)
    transpose_k<<<(256 * 64 + 255) / 256, 256, 0, stream>>>(Wl1, WT1, 256, 64);
    transpose_k<<<(256 * 256 + 255) / 256, 256, 0, stream>>>(Wl2, WT2, 256, 256);
    transpose_k<<<(256 * 256 + 255) / 256, 256, 0, stream>>>(Wl3, WT3, 256, 256);

    // ---- layer 1 ----
    linear_k<64, false><<<nLinBlocks, 256, 0, stream>>>(x, WT1, bl1, hbuf);
    hipMemsetAsync(agg, 0, NB, stream);
    edge_k<<<nEdgeBlocks, 256, 0, stream>>>(hbuf, ei, Ws11, bs11, Ws21, bs21, agg);

    // ---- layer 2 ---- (ReLU of layer-1 output folded into linear load)
    linear_k<256, true><<<nLinBlocks, 256, 0, stream>>>(agg, WT2, bl2, hbuf);
    hipMemsetAsync(agg, 0, NB, stream);
    edge_k<<<nEdgeBlocks, 256, 0, stream>>>(hbuf, ei, Ws12, bs12, Ws22, bs22, agg);

    // ---- layer 3 ----
    linear_k<256, true><<<nLinBlocks, 256, 0, stream>>>(agg, WT3, bl3, hbuf);
    hipMemsetAsync(out, 0, (size_t)out_size * sizeof(float), stream);
    edge_k<<<nEdgeBlocks, 256, 0, stream>>>(hbuf, ei, Ws13, bs13, Ws23, bs23, out);
}

// Round 2
// 5411.062 us; speedup vs baseline: 2.5733x; 2.5733x over previous
//
#include <hip/hip_runtime.h>
#include <hip/hip_bf16.h>
#include <math.h>

// Problem constants (from reference)
#define NNODE 10000
#define NEDGE 320000
#define NTOT  (NEDGE + NNODE)   // 330000 incl. self loops
#define INC   64
#define C     256               // HID == OUT_C == 256

// ---------------------------------------------------------------------------
// Transpose W [rows x cols] -> WT [cols x rows]
// ---------------------------------------------------------------------------
__global__ void transpose_k(const float* __restrict__ W, float* __restrict__ WT,
                            int rows, int cols) {
    int idx = blockIdx.x * 256 + threadIdx.x;
    if (idx < rows * cols) {
        int r = idx / cols, c = idx - r * cols;
        WT[c * rows + r] = W[r * cols + c];
    }
}

// ---------------------------------------------------------------------------
// Linear: H[n, 256] = act(X)[n, K] @ WT[K, 256] + b
// ---------------------------------------------------------------------------
template <int K, bool RELU_IN>
__global__ __launch_bounds__(256) void linear_k(const float* __restrict__ X,
                                                const float* __restrict__ WT,
                                                const float* __restrict__ B,
                                                float* __restrict__ H) {
    __shared__ float xs[8 * K];
    const int t = threadIdx.x;
    const size_t rb = (size_t)blockIdx.x * 8;

    for (int i = t; i < 8 * K; i += 256) {
        float v = X[rb * K + i];
        if (RELU_IN) v = fmaxf(v, 0.f);
        xs[i] = v;
    }
    __syncthreads();

    float acc[8];
    const float bv = B[t];
#pragma unroll
    for (int r = 0; r < 8; ++r) acc[r] = bv;

    for (int k = 0; k < K; ++k) {
        float w = WT[k * 256 + t];
#pragma unroll
        for (int r = 0; r < 8; ++r) acc[r] = fmaf(xs[r * K + k], w, acc[r]);
    }
#pragma unroll
    for (int r = 0; r < 8; ++r) H[(rb + r) * 256 + t] = acc[r];
}

// ---------------------------------------------------------------------------
// Fused edge kernel, register-blocked GEMM formulation.
// Block = 32 edges x 256 outputs, K = 512 (cat = [h[dst], h[src]]).
// 256 threads: tn = t&31 -> output cols {4tn..4tn+3} u {128+4tn..128+4tn+3}
//              tm = t>>5 -> edges {4tm..4tm+3}
// Each thread: 4x8 fp32 accumulators.
// A-tile (cat slice) and B-tile (WT_s1 slice) staged in LDS per BK=32 chunk.
// ---------------------------------------------------------------------------
#define ME 32      // edges per block
#define BK 32      // k-chunk
#define APAD 36    // A-tile row stride (16B-aligned, spreads banks)

__global__ __launch_bounds__(256, 4) void edge_k(const float* __restrict__ H,
                                                 const int* __restrict__ EI,
                                                 const float* __restrict__ WTs1,
                                                 const float* __restrict__ bs1,
                                                 const float* __restrict__ Ws2,
                                                 const float* __restrict__ bs2,
                                                 float* __restrict__ AGG) {
    __shared__ float At[BK][APAD];   // [k][edge]
    __shared__ float Bt[BK * 256];   // [k][n] linear
    __shared__ int   sl[ME], dl[ME];
    __shared__ float sc[ME];

    const int t = threadIdx.x;
    const int ebase = blockIdx.x * ME;

    if (t < ME) {
        int e = ebase + t;
        int s = -1, d = -1;
        if (e < NEDGE)      { s = EI[e]; d = EI[NEDGE + e]; }
        else if (e < NTOT)  { s = d = e - NEDGE; }
        sl[t] = s; dl[t] = d;
    }

    const int tn = t & 31;
    const int tm = t >> 5;

    // accumulators init with bias (bias depends on output col only)
    float acc[4][8];
    {
        float bv[8];
#pragma unroll
        for (int j = 0; j < 4; ++j) bv[j]     = bs1[4 * tn + j];
#pragma unroll
        for (int j = 0; j < 4; ++j) bv[4 + j] = bs1[128 + 4 * tn + j];
#pragma unroll
        for (int i = 0; i < 4; ++i)
#pragma unroll
            for (int j = 0; j < 8; ++j) acc[i][j] = bv[j];
    }

    // staging thread mapping for A: edge = t&31, k-offset = (t>>5)*4
    const int ae = t & 31;
    const int ak = (t >> 5) * 4;

    __syncthreads();   // indices ready

    for (int kc = 0; kc < 16; ++kc) {
        const int k0 = kc * BK;

        // ---- load A fragment (gathered cat) to registers ----
        const int node = (k0 < 256) ? dl[ae] : sl[ae];
        const int col  = (k0 & 255) + ak;
        float4 av = {0.f, 0.f, 0.f, 0.f};
        if (node >= 0) av = *(const float4*)(H + (size_t)node * 256 + col);

        // ---- load B fragment (weights, contiguous) to registers ----
        const float4* wsrc = (const float4*)(WTs1 + (size_t)k0 * 256);
        float4 wv[8];
#pragma unroll
        for (int i = 0; i < 8; ++i) wv[i] = wsrc[t + i * 256];

        __syncthreads();   // previous tile fully consumed

        At[ak + 0][ae] = av.x;
        At[ak + 1][ae] = av.y;
        At[ak + 2][ae] = av.z;
        At[ak + 3][ae] = av.w;
        float4* bdst = (float4*)Bt;
#pragma unroll
        for (int i = 0; i < 8; ++i) bdst[t + i * 256] = wv[i];

        __syncthreads();   // tile ready

        // ---- compute: 32 k-steps ----
#pragma unroll 8
        for (int k = 0; k < BK; ++k) {
            float4 a  = *(const float4*)&At[k][tm * 4];
            float4 b0 = *(const float4*)&Bt[k * 256 + 4 * tn];
            float4 b1 = *(const float4*)&Bt[k * 256 + 128 + 4 * tn];
            float ax[4] = {a.x, a.y, a.z, a.w};
            float bx[8] = {b0.x, b0.y, b0.z, b0.w, b1.x, b1.y, b1.z, b1.w};
#pragma unroll
            for (int i = 0; i < 4; ++i)
#pragma unroll
                for (int j = 0; j < 8; ++j)
                    acc[i][j] = fmaf(ax[i], bx[j], acc[i][j]);
        }
    }

    // ---- score: relu(hid) . Ws2, reduced over the 32 tn-lanes ----
    float w2[8];
#pragma unroll
    for (int j = 0; j < 4; ++j) w2[j]     = Ws2[4 * tn + j];
#pragma unroll
    for (int j = 0; j < 4; ++j) w2[4 + j] = Ws2[128 + 4 * tn + j];

    float s[4];
#pragma unroll
    for (int i = 0; i < 4; ++i) {
        float acc_s = 0.f;
#pragma unroll
        for (int j = 0; j < 8; ++j)
            acc_s = fmaf(fmaxf(acc[i][j], 0.f), w2[j], acc_s);
        s[i] = acc_s;
    }
#pragma unroll
    for (int off = 1; off < 32; off <<= 1) {
#pragma unroll
        for (int i = 0; i < 4; ++i) s[i] += __shfl_xor(s[i], off);
    }
    if (tn == 0) {
        const float b2 = bs2[0];
#pragma unroll
        for (int i = 0; i < 4; ++i)
            sc[tm * 4 + i] = 1.f / (1.f + expf(-(s[i] + b2)));
    }
    __syncthreads();

    // ---- scatter: AGG[d] += score * h[src], one column per thread ----
#pragma unroll 1
    for (int e2 = 0; e2 < ME; ++e2) {
        const int d = dl[e2];
        if (d >= 0) {
            const float v = sc[e2] * H[(size_t)sl[e2] * 256 + t];
            atomicAdd(AGG + (size_t)d * 256 + t, v);
        }
    }
}

// ---------------------------------------------------------------------------
extern "C" void kernel_launch(void* const* d_in, const int* in_sizes, int n_in,
                              void* d_out, int out_size, void* d_ws, size_t ws_size,
                              hipStream_t stream) {
    const float* x    = (const float*)d_in[0];
    const int*   ei   = (const int*)d_in[1];

    const float* Wl1  = (const float*)d_in[2];
    const float* bl1  = (const float*)d_in[3];
    const float* Ws11 = (const float*)d_in[4];
    const float* bs11 = (const float*)d_in[5];
    const float* Ws21 = (const float*)d_in[6];
    const float* bs21 = (const float*)d_in[7];

    const float* Wl2  = (const float*)d_in[8];
    const float* bl2  = (const float*)d_in[9];
    const float* Ws12 = (const float*)d_in[10];
    const float* bs12 = (const float*)d_in[11];
    const float* Ws22 = (const float*)d_in[12];
    const float* bs22 = (const float*)d_in[13];

    const float* Wl3  = (const float*)d_in[14];
    const float* bl3  = (const float*)d_in[15];
    const float* Ws13 = (const float*)d_in[16];
    const float* bs13 = (const float*)d_in[17];
    const float* Ws23 = (const float*)d_in[18];
    const float* bs23 = (const float*)d_in[19];

    float* out = (float*)d_out;

    // workspace layout (floats)
    float* ws    = (float*)d_ws;
    float* WT1   = ws;                     // 64*256
    float* WT2   = WT1 + 64 * 256;         // 256*256
    float* WT3   = WT2 + 256 * 256;        // 256*256
    float* WTs1a = WT3 + 256 * 256;        // 512*256
    float* WTs1b = WTs1a + 512 * 256;      // 512*256
    float* WTs1c = WTs1b + 512 * 256;      // 512*256
    float* hbuf  = WTs1c + 512 * 256;      // N*256
    float* agg   = hbuf + NNODE * 256;     // N*256

    const size_t NB = (size_t)NNODE * 256 * sizeof(float);
    const int nEdgeBlocks = (NTOT + ME - 1) / ME;   // 10313
    const int nLinBlocks  = NNODE / 8;              // 1250

    // weight transposes (deterministic, capture-safe)
    transpose_k<<<(256 * 64 + 255) / 256, 256, 0, stream>>>(Wl1, WT1, 256, 64);
    transpose_k<<<(256 * 256 + 255) / 256, 256, 0, stream>>>(Wl2, WT2, 256, 256);
    transpose_k<<<(256 * 256 + 255) / 256, 256, 0, stream>>>(Wl3, WT3, 256, 256);
    transpose_k<<<(256 * 512 + 255) / 256, 256, 0, stream>>>(Ws11, WTs1a, 256, 512);
    transpose_k<<<(256 * 512 + 255) / 256, 256, 0, stream>>>(Ws12, WTs1b, 256, 512);
    transpose_k<<<(256 * 512 + 255) / 256, 256, 0, stream>>>(Ws13, WTs1c, 256, 512);

    // ---- layer 1 ----
    linear_k<64, false><<<nLinBlocks, 256, 0, stream>>>(x, WT1, bl1, hbuf);
    hipMemsetAsync(agg, 0, NB, stream);
    edge_k<<<nEdgeBlocks, 256, 0, stream>>>(hbuf, ei, WTs1a, bs11, Ws21, bs21, agg);

    // ---- layer 2 ---- (ReLU folded into linear load)
    linear_k<256, true><<<nLinBlocks, 256, 0, stream>>>(agg, WT2, bl2, hbuf);
    hipMemsetAsync(agg, 0, NB, stream);
    edge_k<<<nEdgeBlocks, 256, 0, stream>>>(hbuf, ei, WTs1b, bs12, Ws22, bs22, agg);

    // ---- layer 3 ----
    linear_k<256, true><<<nLinBlocks, 256, 0, stream>>>(agg, WT3, bl3, hbuf);
    hipMemsetAsync(out, 0, (size_t)out_size * sizeof(float), stream);
    edge_k<<<nEdgeBlocks, 256, 0, stream>>>(hbuf, ei, WTs1c, bs13, Ws23, bs23, out);
}

// Round 3
// 3802.871 us; speedup vs baseline: 3.6615x; 1.4229x over previous
//
#include <hip/hip_runtime.h>
#include <hip/hip_bf16.h>
#include <math.h>

// Problem constants (from reference)
#define NNODE 10000
#define NEDGE 320000
#define NTOT  (NEDGE + NNODE)   // 330000 incl. self loops
#define INC   64
#define C     256               // HID == OUT_C == 256

// ---------------------------------------------------------------------------
// Transpose W [rows x cols] -> WT [cols x rows]
// ---------------------------------------------------------------------------
__global__ void transpose_k(const float* __restrict__ W, float* __restrict__ WT,
                            int rows, int cols) {
    int idx = blockIdx.x * 256 + threadIdx.x;
    if (idx < rows * cols) {
        int r = idx / cols, c = idx - r * cols;
        WT[c * rows + r] = W[r * cols + c];
    }
}

// ---------------------------------------------------------------------------
// Linear: H[n, 256] = act(X)[n, K] @ WT[K, 256] + b
// ---------------------------------------------------------------------------
template <int K, bool RELU_IN>
__global__ __launch_bounds__(256) void linear_k(const float* __restrict__ X,
                                                const float* __restrict__ WT,
                                                const float* __restrict__ B,
                                                float* __restrict__ H) {
    __shared__ float xs[8 * K];
    const int t = threadIdx.x;
    const size_t rb = (size_t)blockIdx.x * 8;

    for (int i = t; i < 8 * K; i += 256) {
        float v = X[rb * K + i];
        if (RELU_IN) v = fmaxf(v, 0.f);
        xs[i] = v;
    }
    __syncthreads();

    float acc[8];
    const float bv = B[t];
#pragma unroll
    for (int r = 0; r < 8; ++r) acc[r] = bv;

    for (int k = 0; k < K; ++k) {
        float w = WT[k * 256 + t];
#pragma unroll
        for (int r = 0; r < 8; ++r) acc[r] = fmaf(xs[r * K + k], w, acc[r]);
    }
#pragma unroll
    for (int r = 0; r < 8; ++r) H[(rb + r) * 256 + t] = acc[r];
}

// ---------------------------------------------------------------------------
// CSR build: histogram -> exclusive scan -> scatter -> per-bucket sort
// dst(e) = EI[NEDGE+e] for real edges, e-NEDGE for self loops
// ---------------------------------------------------------------------------
__device__ __forceinline__ int edge_dst(const int* EI, int e) {
    return (e < NEDGE) ? EI[NEDGE + e] : (e - NEDGE);
}
__device__ __forceinline__ int edge_src(const int* EI, int e) {
    return (e < NEDGE) ? EI[e] : (e - NEDGE);
}

__global__ void hist_k(const int* __restrict__ EI, int* __restrict__ counts) {
    int e = blockIdx.x * 256 + threadIdx.x;
    if (e < NTOT) atomicAdd(&counts[edge_dst(EI, e)], 1);
}

__global__ __launch_bounds__(256) void scan_k(const int* __restrict__ counts,
                                              int* __restrict__ start,
                                              int* __restrict__ cursor) {
    __shared__ int chunk[256];
    const int t = threadIdx.x;
    const int per = (NNODE + 255) / 256;   // 40
    const int base = t * per;

    int sum = 0;
    for (int i = 0; i < per; ++i)
        if (base + i < NNODE) sum += counts[base + i];
    chunk[t] = sum;
    __syncthreads();
    if (t == 0) {
        int acc = 0;
        for (int i = 0; i < 256; ++i) { int v = chunk[i]; chunk[i] = acc; acc += v; }
        start[NNODE] = acc;
    }
    __syncthreads();
    int acc = chunk[t];
    for (int i = 0; i < per; ++i) {
        int idx = base + i;
        if (idx < NNODE) {
            start[idx] = acc;
            cursor[idx] = acc;
            acc += counts[idx];
        }
    }
}

__global__ void scatter_k(const int* __restrict__ EI, int* __restrict__ cursor,
                          int* __restrict__ elist) {
    int e = blockIdx.x * 256 + threadIdx.x;
    if (e < NTOT) {
        int d = edge_dst(EI, e);
        int pos = atomicAdd(&cursor[d], 1);
        elist[pos] = e;
    }
}

// deterministic order: rank-sort each bucket by edge id
__global__ __launch_bounds__(256) void sortbucket_k(int* __restrict__ elist,
                                                    const int* __restrict__ start) {
    __shared__ int buf[2048];
    const int d = blockIdx.x;
    const int st = start[d], en = start[d + 1];
    const int deg = en - st;
    if (deg <= 1 || deg > 2048) return;
    const int t = threadIdx.x;
    for (int i = t; i < deg; i += 256) buf[i] = elist[st + i];
    __syncthreads();
    for (int i = t; i < deg; i += 256) {
        int id = buf[i], r = 0;
        for (int j = 0; j < deg; ++j) r += (buf[j] < id);
        elist[st + r] = id;
    }
}

// ---------------------------------------------------------------------------
// Edge scorer: GEMM formulation, 64 edges x 256 outputs per block, K=512.
// 256 threads: tn = t&31 -> cols {4tn..4tn+3} u {128+4tn..128+4tn+3}
//              tm = t>>5 -> edges {8tm..8tm+7}
// 8x8 fp32 register tile. Writes only score[e] (sigmoid of Ws2 . relu(hid)).
// ---------------------------------------------------------------------------
#define ME 64      // edges per block
#define BK 32      // k-chunk
#define APAD 68    // A-tile row stride in floats (16B-aligned, spreads banks)

__global__ __launch_bounds__(256, 2) void edge_k(const float* __restrict__ H,
                                                 const int* __restrict__ EI,
                                                 const float* __restrict__ WTs1,
                                                 const float* __restrict__ bs1,
                                                 const float* __restrict__ Ws2,
                                                 const float* __restrict__ bs2,
                                                 float* __restrict__ score) {
    __shared__ float At[BK][APAD];   // [k][edge]
    __shared__ float Bt[BK * 256];   // [k][n] linear
    __shared__ int   sl[ME], dl[ME];

    const int t = threadIdx.x;
    const int ebase = blockIdx.x * ME;

    if (t < ME) {
        int e = ebase + t;
        int s = -1, d = -1;
        if (e < NEDGE)     { s = EI[e]; d = EI[NEDGE + e]; }
        else if (e < NTOT) { s = d = e - NEDGE; }
        sl[t] = s; dl[t] = d;
    }

    const int tn = t & 31;
    const int tm = t >> 5;

    // accumulators init with bias (bias depends on output col only)
    float acc[8][8];
    {
        float bv[8];
#pragma unroll
        for (int j = 0; j < 4; ++j) bv[j]     = bs1[4 * tn + j];
#pragma unroll
        for (int j = 0; j < 4; ++j) bv[4 + j] = bs1[128 + 4 * tn + j];
#pragma unroll
        for (int i = 0; i < 8; ++i)
#pragma unroll
            for (int j = 0; j < 8; ++j) acc[i][j] = bv[j];
    }

    // staging mapping for A: edge = t&63, k-offset = (t>>6)*8 (2 float4 each)
    const int ae = t & 63;
    const int ak = (t >> 6) * 8;

    __syncthreads();   // indices ready

    for (int kc = 0; kc < 16; ++kc) {
        const int k0 = kc * BK;

        // ---- load A fragment (gathered cat rows) to registers ----
        const int node = (k0 < 256) ? dl[ae] : sl[ae];
        const int col  = (k0 & 255) + ak;
        float4 av0 = {0.f, 0.f, 0.f, 0.f}, av1 = {0.f, 0.f, 0.f, 0.f};
        if (node >= 0) {
            const float* hp = H + (size_t)node * 256 + col;
            av0 = *(const float4*)hp;
            av1 = *(const float4*)(hp + 4);
        }

        // ---- load B fragment (weights, contiguous) to registers ----
        const float4* wsrc = (const float4*)(WTs1 + (size_t)k0 * 256);
        float4 wv[8];
#pragma unroll
        for (int i = 0; i < 8; ++i) wv[i] = wsrc[t + i * 256];

        __syncthreads();   // previous tile fully consumed

        At[ak + 0][ae] = av0.x;
        At[ak + 1][ae] = av0.y;
        At[ak + 2][ae] = av0.z;
        At[ak + 3][ae] = av0.w;
        At[ak + 4][ae] = av1.x;
        At[ak + 5][ae] = av1.y;
        At[ak + 6][ae] = av1.z;
        At[ak + 7][ae] = av1.w;
        float4* bdst = (float4*)Bt;
#pragma unroll
        for (int i = 0; i < 8; ++i) bdst[t + i * 256] = wv[i];

        __syncthreads();   // tile ready

        // ---- compute: 32 k-steps, 64 FMA per step per thread ----
#pragma unroll 4
        for (int k = 0; k < BK; ++k) {
            float4 a0 = *(const float4*)&At[k][tm * 8];
            float4 a1 = *(const float4*)&At[k][tm * 8 + 4];
            float4 b0 = *(const float4*)&Bt[k * 256 + 4 * tn];
            float4 b1 = *(const float4*)&Bt[k * 256 + 128 + 4 * tn];
            float ax[8] = {a0.x, a0.y, a0.z, a0.w, a1.x, a1.y, a1.z, a1.w};
            float bx[8] = {b0.x, b0.y, b0.z, b0.w, b1.x, b1.y, b1.z, b1.w};
#pragma unroll
            for (int i = 0; i < 8; ++i)
#pragma unroll
                for (int j = 0; j < 8; ++j)
                    acc[i][j] = fmaf(ax[i], bx[j], acc[i][j]);
        }
    }

    // ---- score: relu(hid) . Ws2, reduced over the 32 tn-lanes ----
    float w2[8];
#pragma unroll
    for (int j = 0; j < 4; ++j) w2[j]     = Ws2[4 * tn + j];
#pragma unroll
    for (int j = 0; j < 4; ++j) w2[4 + j] = Ws2[128 + 4 * tn + j];

    float s[8];
#pragma unroll
    for (int i = 0; i < 8; ++i) {
        float acc_s = 0.f;
#pragma unroll
        for (int j = 0; j < 8; ++j)
            acc_s = fmaf(fmaxf(acc[i][j], 0.f), w2[j], acc_s);
        s[i] = acc_s;
    }
#pragma unroll
    for (int off = 1; off < 32; off <<= 1) {
#pragma unroll
        for (int i = 0; i < 8; ++i) s[i] += __shfl_xor(s[i], off);
    }
    if (tn == 0) {
        const float b2 = bs2[0];
#pragma unroll
        for (int i = 0; i < 8; ++i) {
            int e = ebase + 8 * tm + i;
            if (e < NTOT) score[e] = 1.f / (1.f + expf(-(s[i] + b2)));
        }
    }
}

// ---------------------------------------------------------------------------
// Aggregation: one block per node; thread t owns column t.
// OUT[d][t] = sum over incoming edges e of score[e] * H[src(e)][t]
// Deterministic: elist buckets are sorted by edge id.
// ---------------------------------------------------------------------------
__global__ __launch_bounds__(256) void aggr_k(const float* __restrict__ H,
                                              const int* __restrict__ EI,
                                              const int* __restrict__ elist,
                                              const int* __restrict__ start,
                                              const float* __restrict__ score,
                                              float* __restrict__ OUT) {
    __shared__ int   se[256];
    __shared__ float ssc[256];
    const int d = blockIdx.x;
    const int t = threadIdx.x;
    const int st = start[d], en = start[d + 1];

    float acc = 0.f;
    for (int base = st; base < en; base += 256) {
        const int i = base + t;
        if (i < en) {
            const int e = elist[i];
            se[t]  = edge_src(EI, e);
            ssc[t] = score[e];
        }
        __syncthreads();
        const int cnt = min(256, en - base);
        for (int j = 0; j < cnt; ++j)
            acc = fmaf(ssc[j], H[(size_t)se[j] * 256 + t], acc);
        __syncthreads();
    }
    OUT[(size_t)d * 256 + t] = acc;
}

// ---------------------------------------------------------------------------
extern "C" void kernel_launch(void* const* d_in, const int* in_sizes, int n_in,
                              void* d_out, int out_size, void* d_ws, size_t ws_size,
                              hipStream_t stream) {
    const float* x    = (const float*)d_in[0];
    const int*   ei   = (const int*)d_in[1];

    const float* Wl1  = (const float*)d_in[2];
    const float* bl1  = (const float*)d_in[3];
    const float* Ws11 = (const float*)d_in[4];
    const float* bs11 = (const float*)d_in[5];
    const float* Ws21 = (const float*)d_in[6];
    const float* bs21 = (const float*)d_in[7];

    const float* Wl2  = (const float*)d_in[8];
    const float* bl2  = (const float*)d_in[9];
    const float* Ws12 = (const float*)d_in[10];
    const float* bs12 = (const float*)d_in[11];
    const float* Ws22 = (const float*)d_in[12];
    const float* bs22 = (const float*)d_in[13];

    const float* Wl3  = (const float*)d_in[14];
    const float* bl3  = (const float*)d_in[15];
    const float* Ws13 = (const float*)d_in[16];
    const float* bs13 = (const float*)d_in[17];
    const float* Ws23 = (const float*)d_in[18];
    const float* bs23 = (const float*)d_in[19];

    float* out = (float*)d_out;

    // workspace layout
    float* ws    = (float*)d_ws;
    float* WT1   = ws;                     // 64*256
    float* WT2   = WT1 + 64 * 256;         // 256*256
    float* WT3   = WT2 + 256 * 256;        // 256*256
    float* WTs1a = WT3 + 256 * 256;        // 512*256
    float* WTs1b = WTs1a + 512 * 256;      // 512*256
    float* WTs1c = WTs1b + 512 * 256;      // 512*256
    float* hbuf  = WTs1c + 512 * 256;      // N*256
    float* agg   = hbuf + NNODE * 256;     // N*256
    float* score = agg + NNODE * 256;      // NTOT
    int*   counts = (int*)(score + NTOT);  // N
    int*   startp = counts + NNODE;        // N+1
    int*   cursor = startp + NNODE + 1;    // N
    int*   elist  = cursor + NNODE;        // NTOT

    const int nEdgeBlocks = (NTOT + ME - 1) / ME;       // 5157
    const int nLinBlocks  = NNODE / 8;                  // 1250
    const int nFlat       = (NTOT + 255) / 256;         // 1290

    // weight transposes (deterministic, capture-safe)
    transpose_k<<<(256 * 64 + 255) / 256, 256, 0, stream>>>(Wl1, WT1, 256, 64);
    transpose_k<<<(256 * 256 + 255) / 256, 256, 0, stream>>>(Wl2, WT2, 256, 256);
    transpose_k<<<(256 * 256 + 255) / 256, 256, 0, stream>>>(Wl3, WT3, 256, 256);
    transpose_k<<<(256 * 512 + 255) / 256, 256, 0, stream>>>(Ws11, WTs1a, 256, 512);
    transpose_k<<<(256 * 512 + 255) / 256, 256, 0, stream>>>(Ws12, WTs1b, 256, 512);
    transpose_k<<<(256 * 512 + 255) / 256, 256, 0, stream>>>(Ws13, WTs1c, 256, 512);

    // CSR build (once; graph shared by all 3 layers)
    hipMemsetAsync(counts, 0, NNODE * sizeof(int), stream);
    hist_k<<<nFlat, 256, 0, stream>>>(ei, counts);
    scan_k<<<1, 256, 0, stream>>>(counts, startp, cursor);
    scatter_k<<<nFlat, 256, 0, stream>>>(ei, cursor, elist);
    sortbucket_k<<<NNODE, 256, 0, stream>>>(elist, startp);

    // ---- layer 1 ----
    linear_k<64, false><<<nLinBlocks, 256, 0, stream>>>(x, WT1, bl1, hbuf);
    edge_k<<<nEdgeBlocks, 256, 0, stream>>>(hbuf, ei, WTs1a, bs11, Ws21, bs21, score);
    aggr_k<<<NNODE, 256, 0, stream>>>(hbuf, ei, elist, startp, score, agg);

    // ---- layer 2 ---- (ReLU folded into linear load)
    linear_k<256, true><<<nLinBlocks, 256, 0, stream>>>(agg, WT2, bl2, hbuf);
    edge_k<<<nEdgeBlocks, 256, 0, stream>>>(hbuf, ei, WTs1b, bs12, Ws22, bs22, score);
    aggr_k<<<NNODE, 256, 0, stream>>>(hbuf, ei, elist, startp, score, agg);

    // ---- layer 3 ----
    linear_k<256, true><<<nLinBlocks, 256, 0, stream>>>(agg, WT3, bl3, hbuf);
    edge_k<<<nEdgeBlocks, 256, 0, stream>>>(hbuf, ei, WTs1c, bs13, Ws23, bs23, score);
    aggr_k<<<NNODE, 256, 0, stream>>>(hbuf, ei, elist, startp, score, out);
}

// Round 4
// 1201.383 us; speedup vs baseline: 11.5900x; 3.1654x over previous
//
#include <hip/hip_runtime.h>
#include <hip/hip_bf16.h>
#include <math.h>

// Problem constants (from reference)
#define NNODE 10000
#define NEDGE 320000
#define NTOT  (NEDGE + NNODE)   // 330000 incl. self loops
#define INC   64
#define C     256               // HID == OUT_C == 256

typedef short bf16x8 __attribute__((ext_vector_type(8)));
typedef float f32x4  __attribute__((ext_vector_type(4)));

union I4B { int4 i4; bf16x8 b; };

__device__ __forceinline__ unsigned short f2bf(float v) {
    __hip_bfloat16 b = __float2bfloat16(v);   // RNE
    return *reinterpret_cast<unsigned short*>(&b);
}

// ---------------------------------------------------------------------------
// Transpose W [rows x cols] -> WT [cols x rows]  (for linear_k)
// ---------------------------------------------------------------------------
__global__ void transpose_k(const float* __restrict__ W, float* __restrict__ WT,
                            int rows, int cols) {
    int idx = blockIdx.x * 256 + threadIdx.x;
    if (idx < rows * cols) {
        int r = idx / cols, c = idx - r * cols;
        WT[c * rows + r] = W[r * cols + c];
    }
}

// cast fp32 -> bf16 (RNE)
__global__ void cast_k(const float* __restrict__ src, unsigned short* __restrict__ dst,
                       int n) {
    int i = blockIdx.x * 256 + threadIdx.x;
    if (i < n) dst[i] = f2bf(src[i]);
}

// ---------------------------------------------------------------------------
// Linear: H[n, 256] = act(X)[n, K] @ WT[K, 256] + b ; also emits bf16 copy HB
// ---------------------------------------------------------------------------
template <int K, bool RELU_IN>
__global__ __launch_bounds__(256) void linear_k(const float* __restrict__ X,
                                                const float* __restrict__ WT,
                                                const float* __restrict__ B,
                                                float* __restrict__ H,
                                                unsigned short* __restrict__ HB) {
    __shared__ float xs[8 * K];
    const int t = threadIdx.x;
    const size_t rb = (size_t)blockIdx.x * 8;

    for (int i = t; i < 8 * K; i += 256) {
        float v = X[rb * K + i];
        if (RELU_IN) v = fmaxf(v, 0.f);
        xs[i] = v;
    }
    __syncthreads();

    float acc[8];
    const float bv = B[t];
#pragma unroll
    for (int r = 0; r < 8; ++r) acc[r] = bv;

    for (int k = 0; k < K; ++k) {
        float w = WT[k * 256 + t];
#pragma unroll
        for (int r = 0; r < 8; ++r) acc[r] = fmaf(xs[r * K + k], w, acc[r]);
    }
#pragma unroll
    for (int r = 0; r < 8; ++r) {
        H[(rb + r) * 256 + t]  = acc[r];
        HB[(rb + r) * 256 + t] = f2bf(acc[r]);
    }
}

// ---------------------------------------------------------------------------
// CSR build: histogram -> exclusive scan -> scatter -> per-bucket sort
// ---------------------------------------------------------------------------
__device__ __forceinline__ int edge_dst(const int* EI, int e) {
    return (e < NEDGE) ? EI[NEDGE + e] : (e - NEDGE);
}
__device__ __forceinline__ int edge_src(const int* EI, int e) {
    return (e < NEDGE) ? EI[e] : (e - NEDGE);
}

__global__ void hist_k(const int* __restrict__ EI, int* __restrict__ counts) {
    int e = blockIdx.x * 256 + threadIdx.x;
    if (e < NTOT) atomicAdd(&counts[edge_dst(EI, e)], 1);
}

__global__ __launch_bounds__(256) void scan_k(const int* __restrict__ counts,
                                              int* __restrict__ start,
                                              int* __restrict__ cursor) {
    __shared__ int chunk[256];
    const int t = threadIdx.x;
    const int per = (NNODE + 255) / 256;   // 40
    const int base = t * per;

    int sum = 0;
    for (int i = 0; i < per; ++i)
        if (base + i < NNODE) sum += counts[base + i];
    chunk[t] = sum;
    __syncthreads();
    if (t == 0) {
        int acc = 0;
        for (int i = 0; i < 256; ++i) { int v = chunk[i]; chunk[i] = acc; acc += v; }
        start[NNODE] = acc;
    }
    __syncthreads();
    int acc = chunk[t];
    for (int i = 0; i < per; ++i) {
        int idx = base + i;
        if (idx < NNODE) {
            start[idx] = acc;
            cursor[idx] = acc;
            acc += counts[idx];
        }
    }
}

__global__ void scatter_k(const int* __restrict__ EI, int* __restrict__ cursor,
                          int* __restrict__ elist) {
    int e = blockIdx.x * 256 + threadIdx.x;
    if (e < NTOT) {
        int d = edge_dst(EI, e);
        int pos = atomicAdd(&cursor[d], 1);
        elist[pos] = e;
    }
}

// deterministic order: rank-sort each bucket by edge id
__global__ __launch_bounds__(256) void sortbucket_k(int* __restrict__ elist,
                                                    const int* __restrict__ start) {
    __shared__ int buf[2048];
    const int d = blockIdx.x;
    const int st = start[d], en = start[d + 1];
    const int deg = en - st;
    if (deg <= 1 || deg > 2048) return;
    const int t = threadIdx.x;
    for (int i = t; i < deg; i += 256) buf[i] = elist[st + i];
    __syncthreads();
    for (int i = t; i < deg; i += 256) {
        int id = buf[i], r = 0;
        for (int j = 0; j < deg; ++j) r += (buf[j] < id);
        elist[st + r] = id;
    }
}

// ---------------------------------------------------------------------------
// Edge scorer via bf16 MFMA. Block = 64 edges x 256 hid cols, 4 waves.
// Wave w owns cols [64w, 64w+64): 4 (M) x 4 (N) fragments of 16x16x32.
// A (gathered cat rows) and B (Ws1 bf16, native [256][512] layout) are loaded
// DIRECTLY from global (L2-resident) -- no LDS staging, no k-loop barriers.
// Fragment layouts (gfx950, 16x16x32 bf16):
//   A: row = lane&15,  k = (lane>>4)*8 + j
//   B: col = lane&15,  k = (lane>>4)*8 + j
//   D: col = lane&15,  row = (lane>>4)*4 + reg
// ---------------------------------------------------------------------------
#define ME 64      // edges per block

__global__ __launch_bounds__(256, 2) void edge_k(const unsigned short* __restrict__ HB,
                                                 const int* __restrict__ EI,
                                                 const unsigned short* __restrict__ WB,
                                                 const float* __restrict__ bs1,
                                                 const float* __restrict__ Ws2,
                                                 const float* __restrict__ bs2,
                                                 float* __restrict__ score) {
    __shared__ int   sl[ME], dl[ME];
    __shared__ float swave[4][ME];

    const int t = threadIdx.x;
    const int ebase = blockIdx.x * ME;

    if (t < ME) {
        int e = ebase + t;
        int s = -1, d = -1;
        if (e < NEDGE)     { s = EI[e]; d = EI[NEDGE + e]; }
        else if (e < NTOT) { s = d = e - NEDGE; }
        sl[t] = s; dl[t] = d;
    }
    __syncthreads();

    const int lane = t & 63, wid = t >> 6;
    const int l15 = lane & 15, l4 = lane >> 4;

    // per-lane nodes for the 4 M-fragments (A row = 16m + l15)
    int nd[4], ns[4];
#pragma unroll
    for (int m = 0; m < 4; ++m) { nd[m] = dl[16 * m + l15]; ns[m] = sl[16 * m + l15]; }

    // B base pointers per N-fragment: col = 64*wid + 16*n + l15, k offset l4*8
    const unsigned short* pb[4];
#pragma unroll
    for (int n = 0; n < 4; ++n)
        pb[n] = WB + (size_t)(64 * wid + 16 * n + l15) * 512 + l4 * 8;

    f32x4 acc[4][4];
#pragma unroll
    for (int m = 0; m < 4; ++m)
#pragma unroll
        for (int n = 0; n < 4; ++n) acc[m][n] = (f32x4)(0.f);

    const int4 zero4 = {0, 0, 0, 0};

#pragma unroll 1
    for (int half = 0; half < 2; ++half) {
        // A row base per m-frag: h[dst] for k<256, h[src] for k>=256
        const unsigned short* pa[4];
#pragma unroll
        for (int m = 0; m < 4; ++m) {
            const int node = half ? ns[m] : nd[m];
            pa[m] = (node >= 0) ? HB + (size_t)node * 256 + l4 * 8 : nullptr;
        }
#pragma unroll 4
        for (int c = 0; c < 8; ++c) {
            bf16x8 af[4], bfr[4];
#pragma unroll
            for (int m = 0; m < 4; ++m) {
                I4B u; u.i4 = pa[m] ? *(const int4*)(pa[m] + c * 32) : zero4;
                af[m] = u.b;
            }
#pragma unroll
            for (int n = 0; n < 4; ++n) {
                I4B u; u.i4 = *(const int4*)(pb[n] + half * 256 + c * 32);
                bfr[n] = u.b;
            }
#pragma unroll
            for (int m = 0; m < 4; ++m)
#pragma unroll
                for (int n = 0; n < 4; ++n)
                    acc[m][n] = __builtin_amdgcn_mfma_f32_16x16x32_bf16(
                        af[m], bfr[n], acc[m][n], 0, 0, 0);
        }
    }

    // ---- epilogue: relu + dot(Ws2) + reductions + sigmoid ----
    float b1v[4], w2v[4];
#pragma unroll
    for (int n = 0; n < 4; ++n) {
        const int col = 64 * wid + 16 * n + l15;
        b1v[n] = bs1[col];
        w2v[n] = Ws2[col];
    }

    float ps[4][4];
#pragma unroll
    for (int m = 0; m < 4; ++m) {
#pragma unroll
        for (int r = 0; r < 4; ++r) {
            float v = 0.f;
#pragma unroll
            for (int n = 0; n < 4; ++n)
                v = fmaf(fmaxf(acc[m][n][r] + b1v[n], 0.f), w2v[n], v);
            v += __shfl_xor(v, 1);
            v += __shfl_xor(v, 2);
            v += __shfl_xor(v, 4);
            v += __shfl_xor(v, 8);
            ps[m][r] = v;   // per-edge partial: edge = 16m + 4*l4 + r
        }
    }
    if (l15 == 0) {
#pragma unroll
        for (int m = 0; m < 4; ++m)
#pragma unroll
            for (int r = 0; r < 4; ++r)
                swave[wid][16 * m + 4 * l4 + r] = ps[m][r];
    }
    __syncthreads();
    if (t < ME) {
        const int e = ebase + t;
        if (e < NTOT) {
            const float z = bs2[0] + swave[0][t] + swave[1][t] + swave[2][t] + swave[3][t];
            score[e] = 1.f / (1.f + expf(-z));
        }
    }
}

// ---------------------------------------------------------------------------
// Aggregation: one block per node; thread t owns column t. Deterministic.
// ---------------------------------------------------------------------------
__global__ __launch_bounds__(256) void aggr_k(const float* __restrict__ H,
                                              const int* __restrict__ EI,
                                              const int* __restrict__ elist,
                                              const int* __restrict__ start,
                                              const float* __restrict__ score,
                                              float* __restrict__ OUT) {
    __shared__ int   se[256];
    __shared__ float ssc[256];
    const int d = blockIdx.x;
    const int t = threadIdx.x;
    const int st = start[d], en = start[d + 1];

    float acc = 0.f;
    for (int base = st; base < en; base += 256) {
        const int i = base + t;
        if (i < en) {
            const int e = elist[i];
            se[t]  = edge_src(EI, e);
            ssc[t] = score[e];
        }
        __syncthreads();
        const int cnt = min(256, en - base);
        for (int j = 0; j < cnt; ++j)
            acc = fmaf(ssc[j], H[(size_t)se[j] * 256 + t], acc);
        __syncthreads();
    }
    OUT[(size_t)d * 256 + t] = acc;
}

// ---------------------------------------------------------------------------
extern "C" void kernel_launch(void* const* d_in, const int* in_sizes, int n_in,
                              void* d_out, int out_size, void* d_ws, size_t ws_size,
                              hipStream_t stream) {
    const float* x    = (const float*)d_in[0];
    const int*   ei   = (const int*)d_in[1];

    const float* Wl1  = (const float*)d_in[2];
    const float* bl1  = (const float*)d_in[3];
    const float* Ws11 = (const float*)d_in[4];
    const float* bs11 = (const float*)d_in[5];
    const float* Ws21 = (const float*)d_in[6];
    const float* bs21 = (const float*)d_in[7];

    const float* Wl2  = (const float*)d_in[8];
    const float* bl2  = (const float*)d_in[9];
    const float* Ws12 = (const float*)d_in[10];
    const float* bs12 = (const float*)d_in[11];
    const float* Ws22 = (const float*)d_in[12];
    const float* bs22 = (const float*)d_in[13];

    const float* Wl3  = (const float*)d_in[14];
    const float* bl3  = (const float*)d_in[15];
    const float* Ws13 = (const float*)d_in[16];
    const float* bs13 = (const float*)d_in[17];
    const float* Ws23 = (const float*)d_in[18];
    const float* bs23 = (const float*)d_in[19];

    float* out = (float*)d_out;

    // workspace layout (16B-aligned sections first)
    char* p = (char*)d_ws;
    unsigned short* Hbf = (unsigned short*)p; p += (size_t)NNODE * 256 * 2;  // 5.12 MB
    unsigned short* Wb1 = (unsigned short*)p; p += 256 * 512 * 2;
    unsigned short* Wb2 = (unsigned short*)p; p += 256 * 512 * 2;
    unsigned short* Wb3 = (unsigned short*)p; p += 256 * 512 * 2;
    float* WT1   = (float*)p; p += 64 * 256 * 4;
    float* WT2   = (float*)p; p += 256 * 256 * 4;
    float* WT3   = (float*)p; p += 256 * 256 * 4;
    float* hbuf  = (float*)p; p += (size_t)NNODE * 256 * 4;
    float* agg   = (float*)p; p += (size_t)NNODE * 256 * 4;
    float* score = (float*)p; p += (size_t)NTOT * 4;
    int*   counts = (int*)p;  p += NNODE * 4;
    int*   startp = (int*)p;  p += (NNODE + 1) * 4;
    int*   cursor = (int*)p;  p += NNODE * 4;
    int*   elist  = (int*)p;  p += (size_t)NTOT * 4;

    const int nEdgeBlocks = (NTOT + ME - 1) / ME;       // 5157
    const int nLinBlocks  = NNODE / 8;                  // 1250
    const int nFlat       = (NTOT + 255) / 256;         // 1290

    // weight prep (deterministic, capture-safe)
    transpose_k<<<(256 * 64 + 255) / 256, 256, 0, stream>>>(Wl1, WT1, 256, 64);
    transpose_k<<<(256 * 256 + 255) / 256, 256, 0, stream>>>(Wl2, WT2, 256, 256);
    transpose_k<<<(256 * 256 + 255) / 256, 256, 0, stream>>>(Wl3, WT3, 256, 256);
    cast_k<<<512, 256, 0, stream>>>(Ws11, Wb1, 256 * 512);
    cast_k<<<512, 256, 0, stream>>>(Ws12, Wb2, 256 * 512);
    cast_k<<<512, 256, 0, stream>>>(Ws13, Wb3, 256 * 512);

    // CSR build (once; graph shared by all 3 layers)
    hipMemsetAsync(counts, 0, NNODE * sizeof(int), stream);
    hist_k<<<nFlat, 256, 0, stream>>>(ei, counts);
    scan_k<<<1, 256, 0, stream>>>(counts, startp, cursor);
    scatter_k<<<nFlat, 256, 0, stream>>>(ei, cursor, elist);
    sortbucket_k<<<NNODE, 256, 0, stream>>>(elist, startp);

    // ---- layer 1 ----
    linear_k<64, false><<<nLinBlocks, 256, 0, stream>>>(x, WT1, bl1, hbuf, Hbf);
    edge_k<<<nEdgeBlocks, 256, 0, stream>>>(Hbf, ei, Wb1, bs11, Ws21, bs21, score);
    aggr_k<<<NNODE, 256, 0, stream>>>(hbuf, ei, elist, startp, score, agg);

    // ---- layer 2 ---- (ReLU folded into linear load)
    linear_k<256, true><<<nLinBlocks, 256, 0, stream>>>(agg, WT2, bl2, hbuf, Hbf);
    edge_k<<<nEdgeBlocks, 256, 0, stream>>>(Hbf, ei, Wb2, bs12, Ws22, bs22, score);
    aggr_k<<<NNODE, 256, 0, stream>>>(hbuf, ei, elist, startp, score, agg);

    // ---- layer 3 ----
    linear_k<256, true><<<nLinBlocks, 256, 0, stream>>>(agg, WT3, bl3, hbuf, Hbf);
    edge_k<<<nEdgeBlocks, 256, 0, stream>>>(Hbf, ei, Wb3, bs13, Ws23, bs23, score);
    aggr_k<<<NNODE, 256, 0, stream>>>(hbuf, ei, elist, startp, score, out);
}

// Round 5
// 1201.059 us; speedup vs baseline: 11.5932x; 1.0003x over previous
//
#include <hip/hip_runtime.h>
#include <hip/hip_bf16.h>
#include <math.h>

// Problem constants (from reference)
#define NNODE 10000
#define NEDGE 320000
#define NTOT  (NEDGE + NNODE)   // 330000 incl. self loops
#define INC   64
#define C     256               // HID == OUT_C == 256

typedef short bf16x8 __attribute__((ext_vector_type(8)));
typedef float f32x4  __attribute__((ext_vector_type(4)));

union I4B { int4 i4; bf16x8 b; };

__device__ __forceinline__ unsigned short f2bf(float v) {
    __hip_bfloat16 b = __float2bfloat16(v);   // RNE
    return *reinterpret_cast<unsigned short*>(&b);
}

// ---------------------------------------------------------------------------
// Transpose W [rows x cols] -> WT [cols x rows]  (for linear_k)
// ---------------------------------------------------------------------------
__global__ void transpose_k(const float* __restrict__ W, float* __restrict__ WT,
                            int rows, int cols) {
    int idx = blockIdx.x * 256 + threadIdx.x;
    if (idx < rows * cols) {
        int r = idx / cols, c = idx - r * cols;
        WT[c * rows + r] = W[r * cols + c];
    }
}

// cast fp32 -> bf16 (RNE)
__global__ void cast_k(const float* __restrict__ src, unsigned short* __restrict__ dst,
                       int n) {
    int i = blockIdx.x * 256 + threadIdx.x;
    if (i < n) dst[i] = f2bf(src[i]);
}

// ---------------------------------------------------------------------------
// Linear: H[n, 256] = act(X)[n, K] @ WT[K, 256] + b ; also emits bf16 copy HB
// ---------------------------------------------------------------------------
template <int K, bool RELU_IN>
__global__ __launch_bounds__(256) void linear_k(const float* __restrict__ X,
                                                const float* __restrict__ WT,
                                                const float* __restrict__ B,
                                                float* __restrict__ H,
                                                unsigned short* __restrict__ HB) {
    __shared__ float xs[8 * K];
    const int t = threadIdx.x;
    const size_t rb = (size_t)blockIdx.x * 8;

    for (int i = t; i < 8 * K; i += 256) {
        float v = X[rb * K + i];
        if (RELU_IN) v = fmaxf(v, 0.f);
        xs[i] = v;
    }
    __syncthreads();

    float acc[8];
    const float bv = B[t];
#pragma unroll
    for (int r = 0; r < 8; ++r) acc[r] = bv;

    for (int k = 0; k < K; ++k) {
        float w = WT[k * 256 + t];
#pragma unroll
        for (int r = 0; r < 8; ++r) acc[r] = fmaf(xs[r * K + k], w, acc[r]);
    }
#pragma unroll
    for (int r = 0; r < 8; ++r) {
        H[(rb + r) * 256 + t]  = acc[r];
        HB[(rb + r) * 256 + t] = f2bf(acc[r]);
    }
}

// ---------------------------------------------------------------------------
// CSR build: histogram -> exclusive scan -> scatter -> per-bucket sort
// ---------------------------------------------------------------------------
__device__ __forceinline__ int edge_dst(const int* EI, int e) {
    return (e < NEDGE) ? EI[NEDGE + e] : (e - NEDGE);
}
__device__ __forceinline__ int edge_src(const int* EI, int e) {
    return (e < NEDGE) ? EI[e] : (e - NEDGE);
}

__global__ void hist_k(const int* __restrict__ EI, int* __restrict__ counts) {
    int e = blockIdx.x * 256 + threadIdx.x;
    if (e < NTOT) atomicAdd(&counts[edge_dst(EI, e)], 1);
}

__global__ __launch_bounds__(256) void scan_k(const int* __restrict__ counts,
                                              int* __restrict__ start,
                                              int* __restrict__ cursor) {
    __shared__ int chunk[256];
    const int t = threadIdx.x;
    const int per = (NNODE + 255) / 256;   // 40
    const int base = t * per;

    int sum = 0;
    for (int i = 0; i < per; ++i)
        if (base + i < NNODE) sum += counts[base + i];
    chunk[t] = sum;
    __syncthreads();
    if (t == 0) {
        int acc = 0;
        for (int i = 0; i < 256; ++i) { int v = chunk[i]; chunk[i] = acc; acc += v; }
        start[NNODE] = acc;
    }
    __syncthreads();
    int acc = chunk[t];
    for (int i = 0; i < per; ++i) {
        int idx = base + i;
        if (idx < NNODE) {
            start[idx] = acc;
            cursor[idx] = acc;
            acc += counts[idx];
        }
    }
}

__global__ void scatter_k(const int* __restrict__ EI, int* __restrict__ cursor,
                          int* __restrict__ elist) {
    int e = blockIdx.x * 256 + threadIdx.x;
    if (e < NTOT) {
        int d = edge_dst(EI, e);
        int pos = atomicAdd(&cursor[d], 1);
        elist[pos] = e;
    }
}

// deterministic order: rank-sort each bucket by edge id
__global__ __launch_bounds__(256) void sortbucket_k(int* __restrict__ elist,
                                                    const int* __restrict__ start) {
    __shared__ int buf[2048];
    const int d = blockIdx.x;
    const int st = start[d], en = start[d + 1];
    const int deg = en - st;
    if (deg <= 1 || deg > 2048) return;
    const int t = threadIdx.x;
    for (int i = t; i < deg; i += 256) buf[i] = elist[st + i];
    __syncthreads();
    for (int i = t; i < deg; i += 256) {
        int id = buf[i], r = 0;
        for (int j = 0; j < deg; ++j) r += (buf[j] < id);
        elist[st + r] = id;
    }
}

// ---------------------------------------------------------------------------
// Edge scorer via bf16 MFMA. Block = 64 edges x 256 hid cols, 4 waves.
// Wave w owns cols [64w, 64w+64): 4 (M) x 4 (N) fragments of 16x16x32.
// A (gathered cat rows) and B (Ws1 bf16, native [256][512] layout) are loaded
// DIRECTLY from global (L2-resident) -- no LDS staging, no k-loop barriers.
// Fragment layouts (gfx950, 16x16x32 bf16):
//   A: row = lane&15,  k = (lane>>4)*8 + j
//   B: col = lane&15,  k = (lane>>4)*8 + j
//   D: col = lane&15,  row = (lane>>4)*4 + reg
// ---------------------------------------------------------------------------
#define ME 64      // edges per block

__global__ __launch_bounds__(256, 2) void edge_k(const unsigned short* __restrict__ HB,
                                                 const int* __restrict__ EI,
                                                 const unsigned short* __restrict__ WB,
                                                 const float* __restrict__ bs1,
                                                 const float* __restrict__ Ws2,
                                                 const float* __restrict__ bs2,
                                                 float* __restrict__ score) {
    __shared__ int   sl[ME], dl[ME];
    __shared__ float swave[4][ME];

    const int t = threadIdx.x;
    const int ebase = blockIdx.x * ME;

    if (t < ME) {
        int e = ebase + t;
        int s = -1, d = -1;
        if (e < NEDGE)     { s = EI[e]; d = EI[NEDGE + e]; }
        else if (e < NTOT) { s = d = e - NEDGE; }
        sl[t] = s; dl[t] = d;
    }
    __syncthreads();

    const int lane = t & 63, wid = t >> 6;
    const int l15 = lane & 15, l4 = lane >> 4;

    // per-lane nodes for the 4 M-fragments (A row = 16m + l15)
    int nd[4], ns[4];
#pragma unroll
    for (int m = 0; m < 4; ++m) { nd[m] = dl[16 * m + l15]; ns[m] = sl[16 * m + l15]; }

    // B base pointers per N-fragment: col = 64*wid + 16*n + l15, k offset l4*8
    const unsigned short* pb[4];
#pragma unroll
    for (int n = 0; n < 4; ++n)
        pb[n] = WB + (size_t)(64 * wid + 16 * n + l15) * 512 + l4 * 8;

    f32x4 acc[4][4];
#pragma unroll
    for (int m = 0; m < 4; ++m)
#pragma unroll
        for (int n = 0; n < 4; ++n) acc[m][n] = (f32x4)(0.f);

    const int4 zero4 = {0, 0, 0, 0};

#pragma unroll 1
    for (int half = 0; half < 2; ++half) {
        // A row base per m-frag: h[dst] for k<256, h[src] for k>=256
        const unsigned short* pa[4];
#pragma unroll
        for (int m = 0; m < 4; ++m) {
            const int node = half ? ns[m] : nd[m];
            pa[m] = (node >= 0) ? HB + (size_t)node * 256 + l4 * 8 : nullptr;
        }
#pragma unroll 4
        for (int c = 0; c < 8; ++c) {
            bf16x8 af[4], bfr[4];
#pragma unroll
            for (int m = 0; m < 4; ++m) {
                I4B u; u.i4 = pa[m] ? *(const int4*)(pa[m] + c * 32) : zero4;
                af[m] = u.b;
            }
#pragma unroll
            for (int n = 0; n < 4; ++n) {
                I4B u; u.i4 = *(const int4*)(pb[n] + half * 256 + c * 32);
                bfr[n] = u.b;
            }
#pragma unroll
            for (int m = 0; m < 4; ++m)
#pragma unroll
                for (int n = 0; n < 4; ++n)
                    acc[m][n] = __builtin_amdgcn_mfma_f32_16x16x32_bf16(
                        af[m], bfr[n], acc[m][n], 0, 0, 0);
        }
    }

    // ---- epilogue: relu + dot(Ws2) + reductions + sigmoid ----
    float b1v[4], w2v[4];
#pragma unroll
    for (int n = 0; n < 4; ++n) {
        const int col = 64 * wid + 16 * n + l15;
        b1v[n] = bs1[col];
        w2v[n] = Ws2[col];
    }

    float ps[4][4];
#pragma unroll
    for (int m = 0; m < 4; ++m) {
#pragma unroll
        for (int r = 0; r < 4; ++r) {
            float v = 0.f;
#pragma unroll
            for (int n = 0; n < 4; ++n)
                v = fmaf(fmaxf(acc[m][n][r] + b1v[n], 0.f), w2v[n], v);
            v += __shfl_xor(v, 1);
            v += __shfl_xor(v, 2);
            v += __shfl_xor(v, 4);
            v += __shfl_xor(v, 8);
            ps[m][r] = v;   // per-edge partial: edge = 16m + 4*l4 + r
        }
    }
    if (l15 == 0) {
#pragma unroll
        for (int m = 0; m < 4; ++m)
#pragma unroll
            for (int r = 0; r < 4; ++r)
                swave[wid][16 * m + 4 * l4 + r] = ps[m][r];
    }
    __syncthreads();
    if (t < ME) {
        const int e = ebase + t;
        if (e < NTOT) {
            const float z = bs2[0] + swave[0][t] + swave[1][t] + swave[2][t] + swave[3][t];
            score[e] = 1.f / (1.f + expf(-z));
        }
    }
}

// ---------------------------------------------------------------------------
// Aggregation: one block per node; thread t owns column t. Deterministic.
// ---------------------------------------------------------------------------
__global__ __launch_bounds__(256) void aggr_k(const float* __restrict__ H,
                                              const int* __restrict__ EI,
                                              const int* __restrict__ elist,
                                              const int* __restrict__ start,
                                              const float* __restrict__ score,
                                              float* __restrict__ OUT) {
    __shared__ int   se[256];
    __shared__ float ssc[256];
    const int d = blockIdx.x;
    const int t = threadIdx.x;
    const int st = start[d], en = start[d + 1];

    float acc = 0.f;
    for (int base = st; base < en; base += 256) {
        const int i = base + t;
        if (i < en) {
            const int e = elist[i];
            se[t]  = edge_src(EI, e);
            ssc[t] = score[e];
        }
        __syncthreads();
        const int cnt = min(256, en - base);
        for (int j = 0; j < cnt; ++j)
            acc = fmaf(ssc[j], H[(size_t)se[j] * 256 + t], acc);
        __syncthreads();
    }
    OUT[(size_t)d * 256 + t] = acc;
}

// ---------------------------------------------------------------------------
extern "C" void kernel_launch(void* const* d_in, const int* in_sizes, int n_in,
                              void* d_out, int out_size, void* d_ws, size_t ws_size,
                              hipStream_t stream) {
    const float* x    = (const float*)d_in[0];
    const int*   ei   = (const int*)d_in[1];

    const float* Wl1  = (const float*)d_in[2];
    const float* bl1  = (const float*)d_in[3];
    const float* Ws11 = (const float*)d_in[4];
    const float* bs11 = (const float*)d_in[5];
    const float* Ws21 = (const float*)d_in[6];
    const float* bs21 = (const float*)d_in[7];

    const float* Wl2  = (const float*)d_in[8];
    const float* bl2  = (const float*)d_in[9];
    const float* Ws12 = (const float*)d_in[10];
    const float* bs12 = (const float*)d_in[11];
    const float* Ws22 = (const float*)d_in[12];
    const float* bs22 = (const float*)d_in[13];

    const float* Wl3  = (const float*)d_in[14];
    const float* bl3  = (const float*)d_in[15];
    const float* Ws13 = (const float*)d_in[16];
    const float* bs13 = (const float*)d_in[17];
    const float* Ws23 = (const float*)d_in[18];
    const float* bs23 = (const float*)d_in[19];

    float* out = (float*)d_out;

    // workspace layout (16B-aligned sections first)
    char* p = (char*)d_ws;
    unsigned short* Hbf = (unsigned short*)p; p += (size_t)NNODE * 256 * 2;  // 5.12 MB
    unsigned short* Wb1 = (unsigned short*)p; p += 256 * 512 * 2;
    unsigned short* Wb2 = (unsigned short*)p; p += 256 * 512 * 2;
    unsigned short* Wb3 = (unsigned short*)p; p += 256 * 512 * 2;
    float* WT1   = (float*)p; p += 64 * 256 * 4;
    float* WT2   = (float*)p; p += 256 * 256 * 4;
    float* WT3   = (float*)p; p += 256 * 256 * 4;
    float* hbuf  = (float*)p; p += (size_t)NNODE * 256 * 4;
    float* agg   = (float*)p; p += (size_t)NNODE * 256 * 4;
    float* score = (float*)p; p += (size_t)NTOT * 4;
    int*   counts = (int*)p;  p += NNODE * 4;
    int*   startp = (int*)p;  p += (NNODE + 1) * 4;
    int*   cursor = (int*)p;  p += NNODE * 4;
    int*   elist  = (int*)p;  p += (size_t)NTOT * 4;

    const int nEdgeBlocks = (NTOT + ME - 1) / ME;       // 5157
    const int nLinBlocks  = NNODE / 8;                  // 1250
    const int nFlat       = (NTOT + 255) / 256;         // 1290

    // weight prep (deterministic, capture-safe)
    transpose_k<<<(256 * 64 + 255) / 256, 256, 0, stream>>>(Wl1, WT1, 256, 64);
    transpose_k<<<(256 * 256 + 255) / 256, 256, 0, stream>>>(Wl2, WT2, 256, 256);
    transpose_k<<<(256 * 256 + 255) / 256, 256, 0, stream>>>(Wl3, WT3, 256, 256);
    cast_k<<<512, 256, 0, stream>>>(Ws11, Wb1, 256 * 512);
    cast_k<<<512, 256, 0, stream>>>(Ws12, Wb2, 256 * 512);
    cast_k<<<512, 256, 0, stream>>>(Ws13, Wb3, 256 * 512);

    // CSR build (once; graph shared by all 3 layers)
    hipMemsetAsync(counts, 0, NNODE * sizeof(int), stream);
    hist_k<<<nFlat, 256, 0, stream>>>(ei, counts);
    scan_k<<<1, 256, 0, stream>>>(counts, startp, cursor);
    scatter_k<<<nFlat, 256, 0, stream>>>(ei, cursor, elist);
    sortbucket_k<<<NNODE, 256, 0, stream>>>(elist, startp);

    // ---- layer 1 ----
    linear_k<64, false><<<nLinBlocks, 256, 0, stream>>>(x, WT1, bl1, hbuf, Hbf);
    edge_k<<<nEdgeBlocks, 256, 0, stream>>>(Hbf, ei, Wb1, bs11, Ws21, bs21, score);
    aggr_k<<<NNODE, 256, 0, stream>>>(hbuf, ei, elist, startp, score, agg);

    // ---- layer 2 ---- (ReLU folded into linear load)
    linear_k<256, true><<<nLinBlocks, 256, 0, stream>>>(agg, WT2, bl2, hbuf, Hbf);
    edge_k<<<nEdgeBlocks, 256, 0, stream>>>(Hbf, ei, Wb2, bs12, Ws22, bs22, score);
    aggr_k<<<NNODE, 256, 0, stream>>>(hbuf, ei, elist, startp, score, agg);

    // ---- layer 3 ----
    linear_k<256, true><<<nLinBlocks, 256, 0, stream>>>(agg, WT3, bl3, hbuf, Hbf);
    edge_k<<<nEdgeBlocks, 256, 0, stream>>>(Hbf, ei, Wb3, bs13, Ws23, bs23, score);
    aggr_k<<<NNODE, 256, 0, stream>>>(hbuf, ei, elist, startp, score, out);
}

// Round 6
// 555.740 us; speedup vs baseline: 25.0550x; 2.1612x over previous
//
#include <hip/hip_runtime.h>
#include <hip/hip_bf16.h>
#include <math.h>

// Problem constants (from reference)
#define NNODE 10000
#define NEDGE 320000
#define NTOT  (NEDGE + NNODE)   // 330000 incl. self loops
#define INC   64
#define C     256               // HID == OUT_C == 256

__device__ __forceinline__ unsigned short f2bf(float v) {
    __hip_bfloat16 b = __float2bfloat16(v);   // RNE
    return *reinterpret_cast<unsigned short*>(&b);
}
__device__ __forceinline__ float bflo(unsigned u) { return __uint_as_float(u << 16); }
__device__ __forceinline__ float bfhi(unsigned u) { return __uint_as_float(u & 0xffff0000u); }

// ---------------------------------------------------------------------------
// Transpose W [rows x cols] -> WT [cols x rows]
// ---------------------------------------------------------------------------
__global__ void transpose_k(const float* __restrict__ W, float* __restrict__ WT,
                            int rows, int cols) {
    int idx = blockIdx.x * 256 + threadIdx.x;
    if (idx < rows * cols) {
        int r = idx / cols, c = idx - r * cols;
        WT[c * rows + r] = W[r * cols + c];
    }
}

// ---------------------------------------------------------------------------
// Fused node linear + edge-MLP projection.
//   h[n]        = act(X[n]) @ WT + b                (fp32, -> H)
//   P[n][0:256]   = h[n] @ WTs1[0:256]   + b1       (bf16, -> PB, "Pi'")
//   P[n][256:512] = h[n] @ WTs1[256:512]            (bf16, "Pj")
// 8 rows per block, 256 threads (thread t = output col t).
// ---------------------------------------------------------------------------
template <int K, bool RELU_IN>
__global__ __launch_bounds__(256) void linproj_k(const float* __restrict__ X,
                                                 const float* __restrict__ WT,
                                                 const float* __restrict__ B,
                                                 const float* __restrict__ WTs1,
                                                 const float* __restrict__ bs1,
                                                 float* __restrict__ H,
                                                 unsigned short* __restrict__ PB) {
    __shared__ float xs[8 * K];
    __shared__ float hs[8 * 256];
    const int t = threadIdx.x;
    const size_t rb = (size_t)blockIdx.x * 8;

    for (int i = t; i < 8 * K; i += 256) {
        float v = X[rb * K + i];
        if (RELU_IN) v = fmaxf(v, 0.f);
        xs[i] = v;
    }
    __syncthreads();

    // ---- phase 1: h = xs @ WT + b ----
    {
        float acc[8];
        const float bv = B[t];
#pragma unroll
        for (int r = 0; r < 8; ++r) acc[r] = bv;
        for (int k4 = 0; k4 < K; k4 += 4) {
            float w0 = WT[(k4 + 0) * 256 + t];
            float w1 = WT[(k4 + 1) * 256 + t];
            float w2 = WT[(k4 + 2) * 256 + t];
            float w3 = WT[(k4 + 3) * 256 + t];
#pragma unroll
            for (int r = 0; r < 8; ++r) {
                float4 xv = *(const float4*)&xs[r * K + k4];
                acc[r] = fmaf(xv.x, w0, acc[r]);
                acc[r] = fmaf(xv.y, w1, acc[r]);
                acc[r] = fmaf(xv.z, w2, acc[r]);
                acc[r] = fmaf(xv.w, w3, acc[r]);
            }
        }
#pragma unroll
        for (int r = 0; r < 8; ++r) {
            H[(rb + r) * 256 + t] = acc[r];
            hs[r * 256 + t] = acc[r];
        }
    }
    __syncthreads();

    // ---- phase 2: P = hs @ WTs1 (+b1 on first half) ----
    float a0[8], a1[8];
    const float b1v = bs1[t];
#pragma unroll
    for (int r = 0; r < 8; ++r) { a0[r] = b1v; a1[r] = 0.f; }
    for (int k4 = 0; k4 < 256; k4 += 4) {
        float wi[4], wj[4];
#pragma unroll
        for (int j = 0; j < 4; ++j) {
            wi[j] = WTs1[(k4 + j) * 256 + t];
            wj[j] = WTs1[(256 + k4 + j) * 256 + t];
        }
#pragma unroll
        for (int r = 0; r < 8; ++r) {
            float4 hv = *(const float4*)&hs[r * 256 + k4];
            a0[r] = fmaf(hv.x, wi[0], a0[r]);
            a0[r] = fmaf(hv.y, wi[1], a0[r]);
            a0[r] = fmaf(hv.z, wi[2], a0[r]);
            a0[r] = fmaf(hv.w, wi[3], a0[r]);
            a1[r] = fmaf(hv.x, wj[0], a1[r]);
            a1[r] = fmaf(hv.y, wj[1], a1[r]);
            a1[r] = fmaf(hv.z, wj[2], a1[r]);
            a1[r] = fmaf(hv.w, wj[3], a1[r]);
        }
    }
#pragma unroll
    for (int r = 0; r < 8; ++r) {
        PB[(rb + r) * 512 + t]       = f2bf(a0[r]);
        PB[(rb + r) * 512 + 256 + t] = f2bf(a1[r]);
    }
}

// ---------------------------------------------------------------------------
// CSR build: histogram -> exclusive scan -> scatter -> per-bucket sort
// ---------------------------------------------------------------------------
__device__ __forceinline__ int edge_dst(const int* EI, int e) {
    return (e < NEDGE) ? EI[NEDGE + e] : (e - NEDGE);
}
__device__ __forceinline__ int edge_src(const int* EI, int e) {
    return (e < NEDGE) ? EI[e] : (e - NEDGE);
}

__global__ void hist_k(const int* __restrict__ EI, int* __restrict__ counts) {
    int e = blockIdx.x * 256 + threadIdx.x;
    if (e < NTOT) atomicAdd(&counts[edge_dst(EI, e)], 1);
}

__global__ __launch_bounds__(256) void scan_k(const int* __restrict__ counts,
                                              int* __restrict__ start,
                                              int* __restrict__ cursor) {
    __shared__ int chunk[256];
    const int t = threadIdx.x;
    const int per = (NNODE + 255) / 256;   // 40
    const int base = t * per;

    int sum = 0;
    for (int i = 0; i < per; ++i)
        if (base + i < NNODE) sum += counts[base + i];
    chunk[t] = sum;
    __syncthreads();
    if (t == 0) {
        int acc = 0;
        for (int i = 0; i < 256; ++i) { int v = chunk[i]; chunk[i] = acc; acc += v; }
        start[NNODE] = acc;
    }
    __syncthreads();
    int acc = chunk[t];
    for (int i = 0; i < per; ++i) {
        int idx = base + i;
        if (idx < NNODE) {
            start[idx] = acc;
            cursor[idx] = acc;
            acc += counts[idx];
        }
    }
}

__global__ void scatter_k(const int* __restrict__ EI, int* __restrict__ cursor,
                          int* __restrict__ elist) {
    int e = blockIdx.x * 256 + threadIdx.x;
    if (e < NTOT) {
        int d = edge_dst(EI, e);
        int pos = atomicAdd(&cursor[d], 1);
        elist[pos] = e;
    }
}

// deterministic order: rank-sort each bucket by edge id
__global__ __launch_bounds__(256) void sortbucket_k(int* __restrict__ elist,
                                                    const int* __restrict__ start) {
    __shared__ int buf[2048];
    const int d = blockIdx.x;
    const int st = start[d], en = start[d + 1];
    const int deg = en - st;
    if (deg <= 1 || deg > 2048) return;
    const int t = threadIdx.x;
    for (int i = t; i < deg; i += 256) buf[i] = elist[st + i];
    __syncthreads();
    for (int i = t; i < deg; i += 256) {
        int id = buf[i], r = 0;
        for (int j = 0; j < deg; ++j) r += (buf[j] < id);
        elist[st + r] = id;
    }
}

// ---------------------------------------------------------------------------
// Edge scorer from node projections:
//   score[e] = sigmoid( Ws2 . relu(Pi'[dst] + Pj[src]) + b2 )
// One wave handles EPW edges; lane l owns cols 4l..4l+3; 64-lane shfl reduce.
// ---------------------------------------------------------------------------
#define EPW 8

__global__ __launch_bounds__(256) void score_k(const unsigned short* __restrict__ PB,
                                               const int* __restrict__ EI,
                                               const float* __restrict__ Ws2,
                                               const float* __restrict__ bs2,
                                               float* __restrict__ score) {
    const int t = threadIdx.x;
    const int lane = t & 63;
    const int gw = blockIdx.x * 4 + (t >> 6);
    const int base = gw * EPW;

    float w2[4];
#pragma unroll
    for (int j = 0; j < 4; ++j) w2[j] = Ws2[4 * lane + j];
    const float b2 = bs2[0];

    int sl[EPW], dl[EPW];
#pragma unroll
    for (int i = 0; i < EPW; ++i) {
        const int e = base + i;
        int s = 0, d = 0;
        if (e < NEDGE)     { s = EI[e]; d = EI[NEDGE + e]; }
        else if (e < NTOT) { s = d = e - NEDGE; }
        sl[i] = s; dl[i] = d;
    }

    uint2 pi[EPW], pj[EPW];
#pragma unroll
    for (int i = 0; i < EPW; ++i) {
        pi[i] = *(const uint2*)(PB + (size_t)dl[i] * 512 + 4 * lane);
        pj[i] = *(const uint2*)(PB + (size_t)sl[i] * 512 + 256 + 4 * lane);
    }

#pragma unroll
    for (int i = 0; i < EPW; ++i) {
        float z, dot = 0.f;
        z = bflo(pi[i].x) + bflo(pj[i].x); dot = fmaf(fmaxf(z, 0.f), w2[0], dot);
        z = bfhi(pi[i].x) + bfhi(pj[i].x); dot = fmaf(fmaxf(z, 0.f), w2[1], dot);
        z = bflo(pi[i].y) + bflo(pj[i].y); dot = fmaf(fmaxf(z, 0.f), w2[2], dot);
        z = bfhi(pi[i].y) + bfhi(pj[i].y); dot = fmaf(fmaxf(z, 0.f), w2[3], dot);
#pragma unroll
        for (int off = 32; off >= 1; off >>= 1) dot += __shfl_xor(dot, off);
        if (lane == 0 && base + i < NTOT)
            score[base + i] = 1.f / (1.f + expf(-(dot + b2)));
    }
}

// ---------------------------------------------------------------------------
// Aggregation: one block per node; thread t owns column t. Deterministic.
// ---------------------------------------------------------------------------
__global__ __launch_bounds__(256) void aggr_k(const float* __restrict__ H,
                                              const int* __restrict__ EI,
                                              const int* __restrict__ elist,
                                              const int* __restrict__ start,
                                              const float* __restrict__ score,
                                              float* __restrict__ OUT) {
    __shared__ int   se[256];
    __shared__ float ssc[256];
    const int d = blockIdx.x;
    const int t = threadIdx.x;
    const int st = start[d], en = start[d + 1];

    float acc = 0.f;
    for (int base = st; base < en; base += 256) {
        const int i = base + t;
        if (i < en) {
            const int e = elist[i];
            se[t]  = edge_src(EI, e);
            ssc[t] = score[e];
        }
        __syncthreads();
        const int cnt = min(256, en - base);
        for (int j = 0; j < cnt; ++j)
            acc = fmaf(ssc[j], H[(size_t)se[j] * 256 + t], acc);
        __syncthreads();
    }
    OUT[(size_t)d * 256 + t] = acc;
}

// ---------------------------------------------------------------------------
extern "C" void kernel_launch(void* const* d_in, const int* in_sizes, int n_in,
                              void* d_out, int out_size, void* d_ws, size_t ws_size,
                              hipStream_t stream) {
    const float* x    = (const float*)d_in[0];
    const int*   ei   = (const int*)d_in[1];

    const float* Wl[3]  = {(const float*)d_in[2],  (const float*)d_in[8],  (const float*)d_in[14]};
    const float* bl[3]  = {(const float*)d_in[3],  (const float*)d_in[9],  (const float*)d_in[15]};
    const float* Ws1[3] = {(const float*)d_in[4],  (const float*)d_in[10], (const float*)d_in[16]};
    const float* bs1[3] = {(const float*)d_in[5],  (const float*)d_in[11], (const float*)d_in[17]};
    const float* Ws2[3] = {(const float*)d_in[6],  (const float*)d_in[12], (const float*)d_in[18]};
    const float* bs2[3] = {(const float*)d_in[7],  (const float*)d_in[13], (const float*)d_in[19]};

    float* out = (float*)d_out;

    // workspace layout
    char* p = (char*)d_ws;
    unsigned short* PB = (unsigned short*)p; p += (size_t)NNODE * 512 * 2;  // 10.24 MB
    float* WT    = (float*)p; p += 256 * 256 * 4;        // shared, re-filled per layer
    float* WTs1  = (float*)p; p += 512 * 256 * 4;        // shared, re-filled per layer
    float* hbuf  = (float*)p; p += (size_t)NNODE * 256 * 4;
    float* agg   = (float*)p; p += (size_t)NNODE * 256 * 4;
    float* score = (float*)p; p += (size_t)NTOT * 4;
    int*   counts = (int*)p;  p += NNODE * 4;
    int*   startp = (int*)p;  p += (NNODE + 4) * 4;
    int*   cursor = (int*)p;  p += NNODE * 4;
    int*   elist  = (int*)p;  p += (size_t)NTOT * 4;

    const int nLinBlocks   = NNODE / 8;                  // 1250
    const int nFlat        = (NTOT + 255) / 256;         // 1290
    const int nScoreBlocks = (NTOT + 4 * EPW - 1) / (4 * EPW);  // 10313

    // CSR build (once; graph shared by all 3 layers)
    hipMemsetAsync(counts, 0, NNODE * sizeof(int), stream);
    hist_k<<<nFlat, 256, 0, stream>>>(ei, counts);
    scan_k<<<1, 256, 0, stream>>>(counts, startp, cursor);
    scatter_k<<<nFlat, 256, 0, stream>>>(ei, cursor, elist);
    sortbucket_k<<<NNODE, 256, 0, stream>>>(elist, startp);

    for (int L = 0; L < 3; ++L) {
        const int K = (L == 0) ? 64 : 256;
        const float* in  = (L == 0) ? x : agg;
        float* dst = (L == 2) ? out : agg;

        // per-layer weight prep into shared buffers (stream-ordered)
        transpose_k<<<(256 * K + 255) / 256, 256, 0, stream>>>(Wl[L], WT, 256, K);
        transpose_k<<<(256 * 512 + 255) / 256, 256, 0, stream>>>(Ws1[L], WTs1, 256, 512);

        if (L == 0)
            linproj_k<64, false><<<nLinBlocks, 256, 0, stream>>>(in, WT, bl[L], WTs1, bs1[L], hbuf, PB);
        else
            linproj_k<256, true><<<nLinBlocks, 256, 0, stream>>>(in, WT, bl[L], WTs1, bs1[L], hbuf, PB);

        score_k<<<nScoreBlocks, 256, 0, stream>>>(PB, ei, Ws2[L], bs2[L], score);
        aggr_k<<<NNODE, 256, 0, stream>>>(hbuf, ei, elist, startp, score, dst);
    }
}

// Round 7
// 436.488 us; speedup vs baseline: 31.9003x; 1.2732x over previous
//
#include <hip/hip_runtime.h>
#include <hip/hip_bf16.h>
#include <math.h>

// Problem constants (from reference)
#define NNODE 10000
#define NPAD  10048             // padded to 64-row multiple for MFMA tiles
#define NEDGE 320000
#define NTOT  (NEDGE + NNODE)   // 330000 incl. self loops
#define INC   64
#define C     256               // HID == OUT_C == 256

typedef short bf16x8 __attribute__((ext_vector_type(8)));
typedef float f32x4  __attribute__((ext_vector_type(4)));

union I4B { int4 i4; bf16x8 b; };

__device__ __forceinline__ unsigned short f2bf(float v) {
    __hip_bfloat16 b = __float2bfloat16(v);   // RNE
    return *reinterpret_cast<unsigned short*>(&b);
}
__device__ __forceinline__ float bflo(unsigned u) { return __uint_as_float(u << 16); }
__device__ __forceinline__ float bfhi(unsigned u) { return __uint_as_float(u & 0xffff0000u); }

// ---------------------------------------------------------------------------
// Transpose W [rows x cols] -> WT [cols x rows]   (for linear_k)
// ---------------------------------------------------------------------------
__global__ void transpose_k(const float* __restrict__ W, float* __restrict__ WT,
                            int rows, int cols) {
    int idx = blockIdx.x * 256 + threadIdx.x;
    if (idx < rows * cols) {
        int r = idx / cols, c = idx - r * cols;
        WT[c * rows + r] = W[r * cols + c];
    }
}

// ---------------------------------------------------------------------------
// Build MFMA B-operand for the projection:
//   BW[c][k] (512 cols x 256 k, bf16):
//     c < 256 : Ws1[c][k]        (Wi -> Pi)
//     c >= 256: Ws1[c-256][256+k] (Wj -> Pj)
// ---------------------------------------------------------------------------
__global__ void castB_k(const float* __restrict__ Ws1, unsigned short* __restrict__ BW) {
    int idx = blockIdx.x * 256 + threadIdx.x;   // 512*256 total
    int c = idx >> 8, k = idx & 255;
    float v = (c < 256) ? Ws1[c * 512 + k] : Ws1[(c - 256) * 512 + 256 + k];
    BW[idx] = f2bf(v);
}

// ---------------------------------------------------------------------------
// Node linear: Hbf[n][t] = bf16( act(X[n]) @ WT + b )
// 8 rows per block, 256 threads (thread t = output col t).
// ---------------------------------------------------------------------------
template <int K, bool RELU_IN>
__global__ __launch_bounds__(256) void linear_k(const float* __restrict__ X,
                                                const float* __restrict__ WT,
                                                const float* __restrict__ B,
                                                unsigned short* __restrict__ HB) {
    __shared__ float xs[8 * K];
    const int t = threadIdx.x;
    const size_t rb = (size_t)blockIdx.x * 8;

    for (int i = t; i < 8 * K; i += 256) {
        float v = X[rb * K + i];
        if (RELU_IN) v = fmaxf(v, 0.f);
        xs[i] = v;
    }
    __syncthreads();

    float acc[8];
    const float bv = B[t];
#pragma unroll
    for (int r = 0; r < 8; ++r) acc[r] = bv;

    for (int k4 = 0; k4 < K; k4 += 4) {
        float w0 = WT[(k4 + 0) * 256 + t];
        float w1 = WT[(k4 + 1) * 256 + t];
        float w2 = WT[(k4 + 2) * 256 + t];
        float w3 = WT[(k4 + 3) * 256 + t];
#pragma unroll
        for (int r = 0; r < 8; ++r) {
            float4 xv = *(const float4*)&xs[r * K + k4];
            acc[r] = fmaf(xv.x, w0, acc[r]);
            acc[r] = fmaf(xv.y, w1, acc[r]);
            acc[r] = fmaf(xv.z, w2, acc[r]);
            acc[r] = fmaf(xv.w, w3, acc[r]);
        }
    }
#pragma unroll
    for (int r = 0; r < 8; ++r) HB[(rb + r) * 256 + t] = f2bf(acc[r]);
}

// ---------------------------------------------------------------------------
// Projection via bf16 MFMA:  PB[n][c] = Hbf[n] . BW[c]  (+ bs1 for c<256)
// Block = 64 rows x 256 cols (4 waves, wave w -> cols [64w,64w+64)).
// grid (NPAD/64, 2): blockIdx.y selects col half (0..255 / 256..511).
// Fragment layouts (verified round 5):
//   A: row = lane&15, k = (lane>>4)*8+j   B: col = lane&15, same k
//   D: col = lane&15, row = (lane>>4)*4+reg
// ---------------------------------------------------------------------------
__global__ __launch_bounds__(256, 2) void proj_k(const unsigned short* __restrict__ HB,
                                                 const unsigned short* __restrict__ BW,
                                                 const float* __restrict__ bs1,
                                                 unsigned short* __restrict__ PB) {
    const int t = threadIdx.x;
    const int lane = t & 63, wid = t >> 6;
    const int l15 = lane & 15, l4 = lane >> 4;
    const int rb = blockIdx.x * 64;
    const int co = blockIdx.y * 256 + wid * 64;

    const unsigned short* pa[4];
#pragma unroll
    for (int m = 0; m < 4; ++m)
        pa[m] = HB + (size_t)(rb + 16 * m + l15) * 256 + l4 * 8;
    const unsigned short* pb[4];
#pragma unroll
    for (int n = 0; n < 4; ++n)
        pb[n] = BW + (size_t)(co + 16 * n + l15) * 256 + l4 * 8;

    f32x4 acc[4][4];
#pragma unroll
    for (int m = 0; m < 4; ++m)
#pragma unroll
        for (int n = 0; n < 4; ++n) acc[m][n] = (f32x4)(0.f);

#pragma unroll
    for (int ks = 0; ks < 8; ++ks) {
        bf16x8 af[4], bfr[4];
#pragma unroll
        for (int m = 0; m < 4; ++m) {
            I4B u; u.i4 = *(const int4*)(pa[m] + ks * 32); af[m] = u.b;
        }
#pragma unroll
        for (int n = 0; n < 4; ++n) {
            I4B u; u.i4 = *(const int4*)(pb[n] + ks * 32); bfr[n] = u.b;
        }
#pragma unroll
        for (int m = 0; m < 4; ++m)
#pragma unroll
            for (int n = 0; n < 4; ++n)
                acc[m][n] = __builtin_amdgcn_mfma_f32_16x16x32_bf16(
                    af[m], bfr[n], acc[m][n], 0, 0, 0);
    }

    float bcol[4];
#pragma unroll
    for (int n = 0; n < 4; ++n) {
        const int col = co + 16 * n + l15;
        bcol[n] = (col < 256) ? bs1[col] : 0.f;
    }
#pragma unroll
    for (int m = 0; m < 4; ++m) {
        const int row = rb + 16 * m + 4 * l4;
        if (row + 3 < NNODE) {
#pragma unroll
            for (int n = 0; n < 4; ++n)
#pragma unroll
                for (int r = 0; r < 4; ++r)
                    PB[(size_t)(row + r) * 512 + co + 16 * n + l15] =
                        f2bf(acc[m][n][r] + bcol[n]);
        } else {
#pragma unroll
            for (int n = 0; n < 4; ++n)
#pragma unroll
                for (int r = 0; r < 4; ++r)
                    if (row + r < NNODE)
                        PB[(size_t)(row + r) * 512 + co + 16 * n + l15] =
                            f2bf(acc[m][n][r] + bcol[n]);
        }
    }
}

// ---------------------------------------------------------------------------
// CSR build: histogram -> exclusive scan -> scatter -> per-bucket sort
// ---------------------------------------------------------------------------
__device__ __forceinline__ int edge_dst(const int* EI, int e) {
    return (e < NEDGE) ? EI[NEDGE + e] : (e - NEDGE);
}
__device__ __forceinline__ int edge_src(const int* EI, int e) {
    return (e < NEDGE) ? EI[e] : (e - NEDGE);
}

__global__ void hist_k(const int* __restrict__ EI, int* __restrict__ counts) {
    int e = blockIdx.x * 256 + threadIdx.x;
    if (e < NTOT) atomicAdd(&counts[edge_dst(EI, e)], 1);
}

__global__ __launch_bounds__(256) void scan_k(const int* __restrict__ counts,
                                              int* __restrict__ start,
                                              int* __restrict__ cursor) {
    __shared__ int chunk[256];
    const int t = threadIdx.x;
    const int per = (NNODE + 255) / 256;   // 40
    const int base = t * per;

    int sum = 0;
    for (int i = 0; i < per; ++i)
        if (base + i < NNODE) sum += counts[base + i];
    chunk[t] = sum;
    __syncthreads();
    if (t == 0) {
        int acc = 0;
        for (int i = 0; i < 256; ++i) { int v = chunk[i]; chunk[i] = acc; acc += v; }
        start[NNODE] = acc;
    }
    __syncthreads();
    int acc = chunk[t];
    for (int i = 0; i < per; ++i) {
        int idx = base + i;
        if (idx < NNODE) {
            start[idx] = acc;
            cursor[idx] = acc;
            acc += counts[idx];
        }
    }
}

__global__ void scatter_k(const int* __restrict__ EI, int* __restrict__ cursor,
                          int* __restrict__ elist) {
    int e = blockIdx.x * 256 + threadIdx.x;
    if (e < NTOT) {
        int d = edge_dst(EI, e);
        int pos = atomicAdd(&cursor[d], 1);
        elist[pos] = e;
    }
}

// deterministic order: rank-sort each bucket by edge id
__global__ __launch_bounds__(256) void sortbucket_k(int* __restrict__ elist,
                                                    const int* __restrict__ start) {
    __shared__ int buf[2048];
    const int d = blockIdx.x;
    const int st = start[d], en = start[d + 1];
    const int deg = en - st;
    if (deg <= 1 || deg > 2048) return;
    const int t = threadIdx.x;
    for (int i = t; i < deg; i += 256) buf[i] = elist[st + i];
    __syncthreads();
    for (int i = t; i < deg; i += 256) {
        int id = buf[i], r = 0;
        for (int j = 0; j < deg; ++j) r += (buf[j] < id);
        elist[st + r] = id;
    }
}

// ---------------------------------------------------------------------------
// Fused score + aggregation, one block (4 waves) per dst node.
//   z(e)   = Ws2 . relu(Pi'[d] + Pj[src e]) + b2
//   OUT[d] = sum_e sigmoid(z) * h[src e]          (bf16 h, fp32 accum)
// Wave w handles edges st+w, st+4+w, ... (fixed partition -> deterministic);
// lane l owns columns 4l..4l+3; per-edge 64-lane shfl reduce for z.
// ---------------------------------------------------------------------------
__global__ __launch_bounds__(256) void scoreaggr_k(const unsigned short* __restrict__ PB,
                                                   const unsigned short* __restrict__ HB,
                                                   const int* __restrict__ EI,
                                                   const int* __restrict__ elist,
                                                   const int* __restrict__ start,
                                                   const float* __restrict__ Ws2,
                                                   const float* __restrict__ bs2,
                                                   float* __restrict__ OUT) {
    __shared__ float sdata[4][256];
    const int t = threadIdx.x;
    const int lane = t & 63, wid = t >> 6;
    const int d = blockIdx.x;
    const int st = start[d], en = start[d + 1];

    float w2[4];
#pragma unroll
    for (int j = 0; j < 4; ++j) w2[j] = Ws2[4 * lane + j];
    const float b2 = bs2[0];

    // Pi' (bias already folded by proj_k)
    const uint2 piu = *(const uint2*)(PB + (size_t)d * 512 + 4 * lane);
    const float pi0 = bflo(piu.x), pi1 = bfhi(piu.x);
    const float pi2 = bflo(piu.y), pi3 = bfhi(piu.y);

    float acc[4] = {0.f, 0.f, 0.f, 0.f};

    for (int i = st + wid; i < en; i += 4) {
        const int e = elist[i];
        const int s = edge_src(EI, e);
        const uint2 pj = *(const uint2*)(PB + (size_t)s * 512 + 256 + 4 * lane);
        const uint2 hv = *(const uint2*)(HB + (size_t)s * 256 + 4 * lane);

        float dot = 0.f;
        dot = fmaf(fmaxf(pi0 + bflo(pj.x), 0.f), w2[0], dot);
        dot = fmaf(fmaxf(pi1 + bfhi(pj.x), 0.f), w2[1], dot);
        dot = fmaf(fmaxf(pi2 + bflo(pj.y), 0.f), w2[2], dot);
        dot = fmaf(fmaxf(pi3 + bfhi(pj.y), 0.f), w2[3], dot);
#pragma unroll
        for (int off = 32; off >= 1; off >>= 1) dot += __shfl_xor(dot, off);

        const float sc = 1.f / (1.f + expf(-(dot + b2)));
        acc[0] = fmaf(sc, bflo(hv.x), acc[0]);
        acc[1] = fmaf(sc, bfhi(hv.x), acc[1]);
        acc[2] = fmaf(sc, bflo(hv.y), acc[2]);
        acc[3] = fmaf(sc, bfhi(hv.y), acc[3]);
    }

#pragma unroll
    for (int j = 0; j < 4; ++j) sdata[wid][4 * lane + j] = acc[j];
    __syncthreads();
    OUT[(size_t)d * 256 + t] =
        sdata[0][t] + sdata[1][t] + sdata[2][t] + sdata[3][t];
}

// ---------------------------------------------------------------------------
extern "C" void kernel_launch(void* const* d_in, const int* in_sizes, int n_in,
                              void* d_out, int out_size, void* d_ws, size_t ws_size,
                              hipStream_t stream) {
    const float* x    = (const float*)d_in[0];
    const int*   ei   = (const int*)d_in[1];

    const float* Wl[3]  = {(const float*)d_in[2],  (const float*)d_in[8],  (const float*)d_in[14]};
    const float* bl[3]  = {(const float*)d_in[3],  (const float*)d_in[9],  (const float*)d_in[15]};
    const float* Ws1[3] = {(const float*)d_in[4],  (const float*)d_in[10], (const float*)d_in[16]};
    const float* bs1[3] = {(const float*)d_in[5],  (const float*)d_in[11], (const float*)d_in[17]};
    const float* Ws2[3] = {(const float*)d_in[6],  (const float*)d_in[12], (const float*)d_in[18]};
    const float* bs2[3] = {(const float*)d_in[7],  (const float*)d_in[13], (const float*)d_in[19]};

    float* out = (float*)d_out;

    // workspace layout
    char* p = (char*)d_ws;
    unsigned short* PB = (unsigned short*)p; p += (size_t)NPAD * 512 * 2;   // 10.3 MB
    unsigned short* HB = (unsigned short*)p; p += (size_t)NPAD * 256 * 2;   // 5.1 MB
    unsigned short* BW = (unsigned short*)p; p += 512 * 256 * 2;            // 256 KB
    float* WT    = (float*)p; p += 256 * 256 * 4;
    float* agg   = (float*)p; p += (size_t)NNODE * 256 * 4;
    int*   counts = (int*)p;  p += NNODE * 4;
    int*   startp = (int*)p;  p += (NNODE + 4) * 4;
    int*   cursor = (int*)p;  p += NNODE * 4;
    int*   elist  = (int*)p;  p += (size_t)NTOT * 4;

    const int nLinBlocks = NNODE / 8;             // 1250
    const int nFlat      = (NTOT + 255) / 256;    // 1290
    const dim3 projGrid(NPAD / 64, 2);            // 157 x 2

    // CSR build (once; graph shared by all 3 layers)
    hipMemsetAsync(counts, 0, NNODE * sizeof(int), stream);
    hist_k<<<nFlat, 256, 0, stream>>>(ei, counts);
    scan_k<<<1, 256, 0, stream>>>(counts, startp, cursor);
    scatter_k<<<nFlat, 256, 0, stream>>>(ei, cursor, elist);
    sortbucket_k<<<NNODE, 256, 0, stream>>>(elist, startp);

    for (int L = 0; L < 3; ++L) {
        const int K = (L == 0) ? 64 : 256;
        const float* in = (L == 0) ? x : agg;
        float* dst = (L == 2) ? out : agg;

        transpose_k<<<(256 * K + 255) / 256, 256, 0, stream>>>(Wl[L], WT, 256, K);
        castB_k<<<512, 256, 0, stream>>>(Ws1[L], BW);

        if (L == 0)
            linear_k<64, false><<<nLinBlocks, 256, 0, stream>>>(in, WT, bl[L], HB);
        else
            linear_k<256, true><<<nLinBlocks, 256, 0, stream>>>(in, WT, bl[L], HB);

        proj_k<<<projGrid, 256, 0, stream>>>(HB, BW, bs1[L], PB);
        scoreaggr_k<<<NNODE, 256, 0, stream>>>(PB, HB, ei, elist, startp,
                                               Ws2[L], bs2[L], dst);
    }
}

// Round 8
// 338.588 us; speedup vs baseline: 41.1239x; 1.2891x over previous
//
#include <hip/hip_runtime.h>
#include <hip/hip_bf16.h>
#include <math.h>

// Problem constants (from reference)
#define NNODE 10000
#define NPAD  10048             // padded to 64-row multiple for MFMA tiles
#define NEDGE 320000
#define NTOT  (NEDGE + NNODE)   // 330000 incl. self loops
#define INC   64
#define C     256               // HID == OUT_C == 256

typedef short bf16x8 __attribute__((ext_vector_type(8)));
typedef float f32x4  __attribute__((ext_vector_type(4)));

union I4B { int4 i4; bf16x8 b; };

__device__ __forceinline__ unsigned short f2bf(float v) {
    __hip_bfloat16 b = __float2bfloat16(v);   // RNE
    return *reinterpret_cast<unsigned short*>(&b);
}
__device__ __forceinline__ float bflo(unsigned u) { return __uint_as_float(u << 16); }
__device__ __forceinline__ float bfhi(unsigned u) { return __uint_as_float(u & 0xffff0000u); }

// ---------------------------------------------------------------------------
// Layer-1 A operand: XB1[NPAD x 64] = bf16(x), zero-padded rows >= NNODE
// ---------------------------------------------------------------------------
__global__ void castx_k(const float* __restrict__ x, unsigned short* __restrict__ XB1) {
    int i = blockIdx.x * 256 + threadIdx.x;
    if (i < NPAD * 64) XB1[i] = (i < NNODE * 64) ? f2bf(x[i]) : (unsigned short)0;
}

// ---------------------------------------------------------------------------
// Weight combine:  WCB[768][K] bf16, BIAS[768] fp32
//   c in [0,256)   : WCB[c] = Wl[c], BIAS = bl[c]                (h)
//   c in [256,512) : WCB[c] = Wi[c-256] @ Wl, BIAS = Wi.bl + bs1 (Pi)
//   c in [512,768) : WCB[c] = Wj[c-512] @ Wl, BIAS = Wj.bl       (Pj)
// Wi = Ws1[:, :256], Wj = Ws1[:, 256:]; Wl is [256][K].
// ---------------------------------------------------------------------------
template <int K>
__global__ __launch_bounds__(256) void combine_k(const float* __restrict__ Wl,
                                                 const float* __restrict__ bl,
                                                 const float* __restrict__ Ws1,
                                                 const float* __restrict__ bs1,
                                                 unsigned short* __restrict__ WCB,
                                                 float* __restrict__ BIAS) {
    int idx = blockIdx.x * 256 + threadIdx.x;
    if (idx >= 768 * K) return;
    int c = idx / K, k = idx - c * K;
    float v;
    if (c < 256) {
        v = Wl[c * K + k];
    } else {
        const int cc = c & 255;
        const int off = (c < 512) ? 0 : 256;
        float s = 0.f;
        for (int m = 0; m < 256; ++m)
            s = fmaf(Ws1[cc * 512 + off + m], Wl[m * K + k], s);
        v = s;
    }
    WCB[c * K + k] = f2bf(v);
    if (k == 0) {
        float b;
        if (c < 256) b = bl[c];
        else {
            const int cc = c & 255;
            const int off = (c < 512) ? 0 : 256;
            float s = (c < 512) ? bs1[cc] : 0.f;
            for (int m = 0; m < 256; ++m)
                s = fmaf(Ws1[cc * 512 + off + m], bl[m], s);
            b = s;
        }
        BIAS[c] = b;
    }
}

// ---------------------------------------------------------------------------
// Fused GEMM via bf16 MFMA:  [h | Pi | Pj] = A @ WCB^T + BIAS
// A = XB [NPAD x K] bf16, WCB = [768][K] bf16 (row = output col).
// Block: 64 rows x 256 cols (4 waves); grid (NPAD/64, 3); blockIdx.y = group
//   (0: h -> PJH h-slots, 1: Pi -> PI, 2: Pj -> PJH pj-slots).
// PJH record per node (1 KB): 64 chunks of {pj[4c..4c+3], h[4c..4c+3]} bf16.
// Fragment layouts (verified rounds 5/6):
//   A: row = lane&15, k = (lane>>4)*8+j ; B: col = lane&15, same k
//   D: col = lane&15, row = (lane>>4)*4+reg
// ---------------------------------------------------------------------------
template <int K>
__global__ __launch_bounds__(256, 2) void gemm_k(const unsigned short* __restrict__ XB,
                                                 const unsigned short* __restrict__ WCB,
                                                 const float* __restrict__ BIAS,
                                                 unsigned short* __restrict__ PI,
                                                 unsigned short* __restrict__ PJH) {
    const int t = threadIdx.x;
    const int lane = t & 63, wid = t >> 6;
    const int l15 = lane & 15, l4 = lane >> 4;
    const int rb = blockIdx.x * 64;
    const int grp = blockIdx.y;                 // 0:h 1:Pi 2:Pj
    const int co = wid * 64;                    // col within group [0,256)

    const unsigned short* pa[4];
#pragma unroll
    for (int m = 0; m < 4; ++m)
        pa[m] = XB + (size_t)(rb + 16 * m + l15) * K + l4 * 8;
    const unsigned short* pb[4];
#pragma unroll
    for (int n = 0; n < 4; ++n)
        pb[n] = WCB + (size_t)(grp * 256 + co + 16 * n + l15) * K + l4 * 8;

    f32x4 acc[4][4];
#pragma unroll
    for (int m = 0; m < 4; ++m)
#pragma unroll
        for (int n = 0; n < 4; ++n) acc[m][n] = (f32x4)(0.f);

#pragma unroll
    for (int ks = 0; ks < K / 32; ++ks) {
        bf16x8 af[4], bfr[4];
#pragma unroll
        for (int m = 0; m < 4; ++m) {
            I4B u; u.i4 = *(const int4*)(pa[m] + ks * 32); af[m] = u.b;
        }
#pragma unroll
        for (int n = 0; n < 4; ++n) {
            I4B u; u.i4 = *(const int4*)(pb[n] + ks * 32); bfr[n] = u.b;
        }
#pragma unroll
        for (int m = 0; m < 4; ++m)
#pragma unroll
            for (int n = 0; n < 4; ++n)
                acc[m][n] = __builtin_amdgcn_mfma_f32_16x16x32_bf16(
                    af[m], bfr[n], acc[m][n], 0, 0, 0);
    }

    float bcol[4];
#pragma unroll
    for (int n = 0; n < 4; ++n) bcol[n] = BIAS[grp * 256 + co + 16 * n + l15];

#pragma unroll
    for (int m = 0; m < 4; ++m) {
        const int row = rb + 16 * m + 4 * l4;
#pragma unroll
        for (int r = 0; r < 4; ++r) {
            if (row + r >= NNODE) continue;
#pragma unroll
            for (int n = 0; n < 4; ++n) {
                const int cc = co + 16 * n + l15;
                const unsigned short v = f2bf(acc[m][n][r] + bcol[n]);
                if (grp == 0)
                    PJH[(size_t)(row + r) * 512 + (cc >> 2) * 8 + 4 + (cc & 3)] = v;
                else if (grp == 1)
                    PI[(size_t)(row + r) * 256 + cc] = v;
                else
                    PJH[(size_t)(row + r) * 512 + (cc >> 2) * 8 + (cc & 3)] = v;
            }
        }
    }
}

// ---------------------------------------------------------------------------
// CSR build: histogram -> exclusive scan -> scatter -> per-bucket sort -> src
// ---------------------------------------------------------------------------
__device__ __forceinline__ int edge_dst(const int* EI, int e) {
    return (e < NEDGE) ? EI[NEDGE + e] : (e - NEDGE);
}
__device__ __forceinline__ int edge_src(const int* EI, int e) {
    return (e < NEDGE) ? EI[e] : (e - NEDGE);
}

__global__ void hist_k(const int* __restrict__ EI, int* __restrict__ counts) {
    int e = blockIdx.x * 256 + threadIdx.x;
    if (e < NTOT) atomicAdd(&counts[edge_dst(EI, e)], 1);
}

__global__ __launch_bounds__(256) void scan_k(const int* __restrict__ counts,
                                              int* __restrict__ start,
                                              int* __restrict__ cursor) {
    __shared__ int chunk[256];
    const int t = threadIdx.x;
    const int per = (NNODE + 255) / 256;   // 40
    const int base = t * per;

    int sum = 0;
    for (int i = 0; i < per; ++i)
        if (base + i < NNODE) sum += counts[base + i];
    chunk[t] = sum;
    __syncthreads();
    if (t == 0) {
        int acc = 0;
        for (int i = 0; i < 256; ++i) { int v = chunk[i]; chunk[i] = acc; acc += v; }
        start[NNODE] = acc;
    }
    __syncthreads();
    int acc = chunk[t];
    for (int i = 0; i < per; ++i) {
        int idx = base + i;
        if (idx < NNODE) {
            start[idx] = acc;
            cursor[idx] = acc;
            acc += counts[idx];
        }
    }
}

__global__ void scatter_k(const int* __restrict__ EI, int* __restrict__ cursor,
                          int* __restrict__ elist) {
    int e = blockIdx.x * 256 + threadIdx.x;
    if (e < NTOT) {
        int d = edge_dst(EI, e);
        int pos = atomicAdd(&cursor[d], 1);
        elist[pos] = e;
    }
}

// deterministic order: rank-sort each bucket by edge id
__global__ __launch_bounds__(256) void sortbucket_k(int* __restrict__ elist,
                                                    const int* __restrict__ start) {
    __shared__ int buf[2048];
    const int d = blockIdx.x;
    const int st = start[d], en = start[d + 1];
    const int deg = en - st;
    if (deg <= 1 || deg > 2048) return;
    const int t = threadIdx.x;
    for (int i = t; i < deg; i += 256) buf[i] = elist[st + i];
    __syncthreads();
    for (int i = t; i < deg; i += 256) {
        int id = buf[i], r = 0;
        for (int j = 0; j < deg; ++j) r += (buf[j] < id);
        elist[st + r] = id;
    }
}

__global__ void srcconv_k(const int* __restrict__ EI, const int* __restrict__ elist,
                          int* __restrict__ elsrc) {
    int i = blockIdx.x * 256 + threadIdx.x;
    if (i < NTOT) elsrc[i] = edge_src(EI, elist[i]);
}

// ---------------------------------------------------------------------------
// Fused score + aggregation: ONE WAVE per dst node (4 nodes per block).
//   z(e)  = Ws2 . relu(Pi[d] + Pj[src e]) + b2
//   acc  += sigmoid(z) * h[src e]      (per lane: 4 columns, fp32)
// One dwordx4 per edge per lane (pj+h interleaved record). 4-deep unroll.
// LAST: write fp32 OUT; else write bf16 relu(acc) -> XB (next layer's A).
// ---------------------------------------------------------------------------
template <bool LAST>
__global__ __launch_bounds__(256) void scoreaggr_k(const unsigned short* __restrict__ PI,
                                                   const unsigned short* __restrict__ PJH,
                                                   const int* __restrict__ elsrc,
                                                   const int* __restrict__ start,
                                                   const float* __restrict__ Ws2,
                                                   const float* __restrict__ bs2,
                                                   float* __restrict__ OUT,
                                                   unsigned short* __restrict__ XB) {
    const int t = threadIdx.x;
    const int lane = t & 63, wid = t >> 6;
    const int d = blockIdx.x * 4 + wid;
    const int st = start[d], en = start[d + 1];

    float w2[4];
#pragma unroll
    for (int j = 0; j < 4; ++j) w2[j] = Ws2[4 * lane + j];
    const float b2 = bs2[0];

    const uint2 piu = *(const uint2*)(PI + (size_t)d * 256 + 4 * lane);
    const float pi0 = bflo(piu.x), pi1 = bfhi(piu.x);
    const float pi2 = bflo(piu.y), pi3 = bfhi(piu.y);

    float acc0 = 0.f, acc1 = 0.f, acc2 = 0.f, acc3 = 0.f;

#define SA_PROC(R)                                                              \
    {                                                                           \
        float dot = 0.f;                                                        \
        dot = fmaf(fmaxf(pi0 + bflo((R).x), 0.f), w2[0], dot);                  \
        dot = fmaf(fmaxf(pi1 + bfhi((R).x), 0.f), w2[1], dot);                  \
        dot = fmaf(fmaxf(pi2 + bflo((R).y), 0.f), w2[2], dot);                  \
        dot = fmaf(fmaxf(pi3 + bfhi((R).y), 0.f), w2[3], dot);                  \
        dot += __shfl_xor(dot, 32); dot += __shfl_xor(dot, 16);                 \
        dot += __shfl_xor(dot, 8);  dot += __shfl_xor(dot, 4);                  \
        dot += __shfl_xor(dot, 2);  dot += __shfl_xor(dot, 1);                  \
        const float sc = 1.f / (1.f + __expf(-(dot + b2)));                     \
        acc0 = fmaf(sc, bflo((R).z), acc0);                                     \
        acc1 = fmaf(sc, bfhi((R).z), acc1);                                     \
        acc2 = fmaf(sc, bflo((R).w), acc2);                                     \
        acc3 = fmaf(sc, bfhi((R).w), acc3);                                     \
    }

    int i = st;
    for (; i + 4 <= en; i += 4) {
        const int s0 = elsrc[i], s1 = elsrc[i + 1];
        const int s2 = elsrc[i + 2], s3 = elsrc[i + 3];
        const uint4 r0 = *(const uint4*)(PJH + (size_t)s0 * 512 + 8 * lane);
        const uint4 r1 = *(const uint4*)(PJH + (size_t)s1 * 512 + 8 * lane);
        const uint4 r2 = *(const uint4*)(PJH + (size_t)s2 * 512 + 8 * lane);
        const uint4 r3 = *(const uint4*)(PJH + (size_t)s3 * 512 + 8 * lane);
        SA_PROC(r0) SA_PROC(r1) SA_PROC(r2) SA_PROC(r3)
    }
    for (; i < en; ++i) {
        const int s = elsrc[i];
        const uint4 r = *(const uint4*)(PJH + (size_t)s * 512 + 8 * lane);
        SA_PROC(r)
    }
#undef SA_PROC

    if (LAST) {
        float4* op = (float4*)(OUT + (size_t)d * 256 + 4 * lane);
        *op = make_float4(acc0, acc1, acc2, acc3);
    } else {
        ushort4 v;
        v.x = f2bf(fmaxf(acc0, 0.f));
        v.y = f2bf(fmaxf(acc1, 0.f));
        v.z = f2bf(fmaxf(acc2, 0.f));
        v.w = f2bf(fmaxf(acc3, 0.f));
        *(ushort4*)(XB + (size_t)d * 256 + 4 * lane) = v;
    }
}

// ---------------------------------------------------------------------------
extern "C" void kernel_launch(void* const* d_in, const int* in_sizes, int n_in,
                              void* d_out, int out_size, void* d_ws, size_t ws_size,
                              hipStream_t stream) {
    const float* x  = (const float*)d_in[0];
    const int*   ei = (const int*)d_in[1];

    const float* Wl[3]  = {(const float*)d_in[2],  (const float*)d_in[8],  (const float*)d_in[14]};
    const float* bl[3]  = {(const float*)d_in[3],  (const float*)d_in[9],  (const float*)d_in[15]};
    const float* Ws1[3] = {(const float*)d_in[4],  (const float*)d_in[10], (const float*)d_in[16]};
    const float* bs1[3] = {(const float*)d_in[5],  (const float*)d_in[11], (const float*)d_in[17]};
    const float* Ws2[3] = {(const float*)d_in[6],  (const float*)d_in[12], (const float*)d_in[18]};
    const float* bs2[3] = {(const float*)d_in[7],  (const float*)d_in[13], (const float*)d_in[19]};

    float* out = (float*)d_out;

    // workspace layout
    char* p = (char*)d_ws;
    unsigned short* PJH = (unsigned short*)p; p += (size_t)NPAD * 512 * 2;  // 10.3 MB
    unsigned short* PI  = (unsigned short*)p; p += (size_t)NPAD * 256 * 2;  // 5.1 MB
    unsigned short* XB  = (unsigned short*)p; p += (size_t)NPAD * 256 * 2;  // 5.1 MB
    unsigned short* XB1 = (unsigned short*)p; p += (size_t)NPAD * 64 * 2;   // 1.3 MB
    unsigned short* WCB = (unsigned short*)p; p += 768 * 256 * 2;           // 384 KB
    float* BIAS  = (float*)p; p += 768 * 4;
    int*   counts = (int*)p;  p += NNODE * 4;
    int*   startp = (int*)p;  p += (NNODE + 4) * 4;
    int*   cursor = (int*)p;  p += NNODE * 4;
    int*   elist  = (int*)p;  p += (size_t)NTOT * 4;
    int*   elsrc  = (int*)p;  p += (size_t)NTOT * 4;

    const int nFlat = (NTOT + 255) / 256;    // 1290

    // CSR build (once; graph shared by all 3 layers)
    hipMemsetAsync(counts, 0, NNODE * sizeof(int), stream);
    hist_k<<<nFlat, 256, 0, stream>>>(ei, counts);
    scan_k<<<1, 256, 0, stream>>>(counts, startp, cursor);
    scatter_k<<<nFlat, 256, 0, stream>>>(ei, cursor, elist);
    sortbucket_k<<<NNODE, 256, 0, stream>>>(elist, startp);
    srcconv_k<<<nFlat, 256, 0, stream>>>(ei, elist, elsrc);

    // layer-1 A operand; zero XB pad rows once per launch
    castx_k<<<(NPAD * 64 + 255) / 256, 256, 0, stream>>>(x, XB1);
    hipMemsetAsync(XB + (size_t)NNODE * 256, 0, (size_t)(NPAD - NNODE) * 256 * 2, stream);

    for (int L = 0; L < 3; ++L) {
        if (L == 0) {
            combine_k<64><<<(768 * 64 + 255) / 256, 256, 0, stream>>>(
                Wl[0], bl[0], Ws1[0], bs1[0], WCB, BIAS);
            gemm_k<64><<<dim3(NPAD / 64, 3), 256, 0, stream>>>(XB1, WCB, BIAS, PI, PJH);
        } else {
            combine_k<256><<<(768 * 256 + 255) / 256, 256, 0, stream>>>(
                Wl[L], bl[L], Ws1[L], bs1[L], WCB, BIAS);
            gemm_k<256><<<dim3(NPAD / 64, 3), 256, 0, stream>>>(XB, WCB, BIAS, PI, PJH);
        }
        if (L == 2)
            scoreaggr_k<true><<<NNODE / 4, 256, 0, stream>>>(PI, PJH, elsrc, startp,
                                                             Ws2[L], bs2[L], out, nullptr);
        else
            scoreaggr_k<false><<<NNODE / 4, 256, 0, stream>>>(PI, PJH, elsrc, startp,
                                                              Ws2[L], bs2[L], nullptr, XB);
    }
}

// Round 9
// 302.133 us; speedup vs baseline: 46.0860x; 1.1207x over previous
//
#include <hip/hip_runtime.h>
#include <hip/hip_bf16.h>
#include <math.h>

// Problem constants (from reference)
#define NNODE 10000
#define NPAD  10048             // padded to 64-row multiple for MFMA tiles
#define NEDGE 320000
#define NTOT  (NEDGE + NNODE)   // 330000 incl. self loops
#define INC   64
#define C     256               // HID == OUT_C == 256

typedef short bf16x8 __attribute__((ext_vector_type(8)));
typedef float f32x4  __attribute__((ext_vector_type(4)));

union I4B { int4 i4; bf16x8 b; };

__device__ __forceinline__ unsigned short f2bf(float v) {
    __hip_bfloat16 b = __float2bfloat16(v);   // RNE
    return *reinterpret_cast<unsigned short*>(&b);
}
__device__ __forceinline__ float bflo(unsigned u) { return __uint_as_float(u << 16); }
__device__ __forceinline__ float bfhi(unsigned u) { return __uint_as_float(u & 0xffff0000u); }

// ---------------------------------------------------------------------------
// Layer-1 A operand: XB1[NPAD x 64] = bf16(x), zero pad rows; also zero the
// pad rows of XB (layers 2/3 A operand).
// ---------------------------------------------------------------------------
__global__ void castx_k(const float* __restrict__ x, unsigned short* __restrict__ XB1,
                        unsigned short* __restrict__ XBpad) {
    int i = blockIdx.x * 256 + threadIdx.x;
    if (i < NPAD * 64) XB1[i] = (i < NNODE * 64) ? f2bf(x[i]) : (unsigned short)0;
    if (i < (NPAD - NNODE) * 256) XBpad[i] = 0;
}

// ---------------------------------------------------------------------------
// prep_k: (a) flat bf16 copy of Wl into WCB rows [0,256) for all 3 layers
//         (b) BIAS[L][768]:
//             c<256: bl[c]; c<512: bs1[cc] + Wi[cc].bl; else Wj[cc].bl
// ---------------------------------------------------------------------------
__global__ __launch_bounds__(256) void prep_k(
        const float* __restrict__ Wl1, const float* __restrict__ Wl2,
        const float* __restrict__ Wl3,
        const float* __restrict__ bl1, const float* __restrict__ bl2,
        const float* __restrict__ bl3,
        const float* __restrict__ Ws11, const float* __restrict__ Ws12,
        const float* __restrict__ Ws13,
        const float* __restrict__ bs11, const float* __restrict__ bs12,
        const float* __restrict__ bs13,
        unsigned short* __restrict__ WCB1, unsigned short* __restrict__ WCB2,
        unsigned short* __restrict__ WCB3, float* __restrict__ BIAS) {
    const int idx = blockIdx.x * 256 + threadIdx.x;

    // flat copies: rows 0..255 of each WCB are Wl cast to bf16 (contiguous)
    if (idx < 256 * 64) WCB1[idx] = f2bf(Wl1[idx]);
    else if (idx < 256 * 64 + 256 * 256) {
        int i2 = idx - 256 * 64; WCB2[i2] = f2bf(Wl2[i2]);
    } else if (idx < 256 * 64 + 2 * 256 * 256) {
        int i3 = idx - 256 * 64 - 256 * 256; WCB3[i3] = f2bf(Wl3[i3]);
    }

    // bias job
    if (idx < 3 * 768) {
        const int L = idx / 768, c = idx - L * 768;
        const float* bl  = (L == 0) ? bl1  : (L == 1) ? bl2  : bl3;
        const float* Ws1 = (L == 0) ? Ws11 : (L == 1) ? Ws12 : Ws13;
        const float* bs1 = (L == 0) ? bs11 : (L == 1) ? bs12 : bs13;
        float b;
        if (c < 256) b = bl[c];
        else {
            const int cc = c & 255;
            const int off = (c < 512) ? 0 : 256;
            float s = (c < 512) ? bs1[cc] : 0.f;
            for (int m = 0; m < 256; ++m)
                s = fmaf(Ws1[cc * 512 + off + m], bl[m], s);
            b = s;
        }
        BIAS[L * 768 + c] = b;
    }
}

// ---------------------------------------------------------------------------
// combW_k: WCB rows [256,768) = bf16( A @ Wl ), A[r][m] = Ws1[r&255][off+m],
// off = (r<256 ? 0 : 256).  Tiled 64x64, LDS-staged, all 3 layers.
// grid (8, 4, 3): x = r-tile, y = k-tile (guarded for K=64), z = layer.
// ---------------------------------------------------------------------------
__global__ __launch_bounds__(256) void combW_k(
        const float* __restrict__ Wl1, const float* __restrict__ Wl2,
        const float* __restrict__ Wl3,
        const float* __restrict__ Ws11, const float* __restrict__ Ws12,
        const float* __restrict__ Ws13,
        unsigned short* __restrict__ WCB1, unsigned short* __restrict__ WCB2,
        unsigned short* __restrict__ WCB3) {
    const int L = blockIdx.z;
    const int K = (L == 0) ? 64 : 256;
    const int kt = blockIdx.y;
    if (kt * 64 >= K) return;
    const int rt = blockIdx.x;

    const float* Wl  = (L == 0) ? Wl1  : (L == 1) ? Wl2  : Wl3;
    const float* Ws1 = (L == 0) ? Ws11 : (L == 1) ? Ws12 : Ws13;
    unsigned short* WCB = (L == 0) ? WCB1 : (L == 1) ? WCB2 : WCB3;

    __shared__ float As[32][68];
    __shared__ float Bs[32][68];

    const int t = threadIdx.x;
    const int tr = t >> 4, tk = t & 15;

    float acc[4][4];
#pragma unroll
    for (int i = 0; i < 4; ++i)
#pragma unroll
        for (int j = 0; j < 4; ++j) acc[i][j] = 0.f;

    for (int mb = 0; mb < 256; mb += 32) {
        // stage A: As[m][r] (transposed)
        {
            const int r = t >> 2, mg = t & 3;
            const int gr = rt * 64 + r;
            const int cc = gr & 255;
            const int off = (gr < 256) ? 0 : 256;
            const float* src = Ws1 + (size_t)cc * 512 + off + mb + mg * 8;
            float4 a0 = *(const float4*)src;
            float4 a1 = *(const float4*)(src + 4);
            As[mg * 8 + 0][r] = a0.x; As[mg * 8 + 1][r] = a0.y;
            As[mg * 8 + 2][r] = a0.z; As[mg * 8 + 3][r] = a0.w;
            As[mg * 8 + 4][r] = a1.x; As[mg * 8 + 5][r] = a1.y;
            As[mg * 8 + 6][r] = a1.z; As[mg * 8 + 7][r] = a1.w;
        }
        // stage B: Bs[m][k]
        {
            const int m = t >> 3, kg = t & 7;
            const float* src = Wl + (size_t)(mb + m) * K + kt * 64 + kg * 8;
            *(float4*)&Bs[m][kg * 8]     = *(const float4*)src;
            *(float4*)&Bs[m][kg * 8 + 4] = *(const float4*)(src + 4);
        }
        __syncthreads();

#pragma unroll 8
        for (int m = 0; m < 32; ++m) {
            float4 av = *(const float4*)&As[m][tr * 4];
            float4 bv = *(const float4*)&Bs[m][tk * 4];
            float ax[4] = {av.x, av.y, av.z, av.w};
            float bx[4] = {bv.x, bv.y, bv.z, bv.w};
#pragma unroll
            for (int i = 0; i < 4; ++i)
#pragma unroll
                for (int j = 0; j < 4; ++j)
                    acc[i][j] = fmaf(ax[i], bx[j], acc[i][j]);
        }
        __syncthreads();
    }

#pragma unroll
    for (int i = 0; i < 4; ++i) {
        const int row = 256 + rt * 64 + tr * 4 + i;
#pragma unroll
        for (int j = 0; j < 4; ++j)
            WCB[(size_t)row * K + kt * 64 + tk * 4 + j] = f2bf(acc[i][j]);
    }
}

// ---------------------------------------------------------------------------
// Fused GEMM via bf16 MFMA:  [h | Pi | Pj] = A @ WCB^T + BIAS
// Block: 64 rows x 256 cols (4 waves); grid (NPAD/64, 3); blockIdx.y = group
//   (0: h -> PJH h-slots, 1: Pi -> PI, 2: Pj -> PJH pj-slots).
// PJH record per node (1 KB): 64 chunks of {pj[4c..4c+3], h[4c..4c+3]} bf16.
// ---------------------------------------------------------------------------
template <int K>
__global__ __launch_bounds__(256, 2) void gemm_k(const unsigned short* __restrict__ XB,
                                                 const unsigned short* __restrict__ WCB,
                                                 const float* __restrict__ BIAS,
                                                 unsigned short* __restrict__ PI,
                                                 unsigned short* __restrict__ PJH) {
    const int t = threadIdx.x;
    const int lane = t & 63, wid = t >> 6;
    const int l15 = lane & 15, l4 = lane >> 4;
    const int rb = blockIdx.x * 64;
    const int grp = blockIdx.y;                 // 0:h 1:Pi 2:Pj
    const int co = wid * 64;                    // col within group [0,256)

    const unsigned short* pa[4];
#pragma unroll
    for (int m = 0; m < 4; ++m)
        pa[m] = XB + (size_t)(rb + 16 * m + l15) * K + l4 * 8;
    const unsigned short* pb[4];
#pragma unroll
    for (int n = 0; n < 4; ++n)
        pb[n] = WCB + (size_t)(grp * 256 + co + 16 * n + l15) * K + l4 * 8;

    f32x4 acc[4][4];
#pragma unroll
    for (int m = 0; m < 4; ++m)
#pragma unroll
        for (int n = 0; n < 4; ++n) acc[m][n] = (f32x4)(0.f);

#pragma unroll
    for (int ks = 0; ks < K / 32; ++ks) {
        bf16x8 af[4], bfr[4];
#pragma unroll
        for (int m = 0; m < 4; ++m) {
            I4B u; u.i4 = *(const int4*)(pa[m] + ks * 32); af[m] = u.b;
        }
#pragma unroll
        for (int n = 0; n < 4; ++n) {
            I4B u; u.i4 = *(const int4*)(pb[n] + ks * 32); bfr[n] = u.b;
        }
#pragma unroll
        for (int m = 0; m < 4; ++m)
#pragma unroll
            for (int n = 0; n < 4; ++n)
                acc[m][n] = __builtin_amdgcn_mfma_f32_16x16x32_bf16(
                    af[m], bfr[n], acc[m][n], 0, 0, 0);
    }

    float bcol[4];
#pragma unroll
    for (int n = 0; n < 4; ++n) bcol[n] = BIAS[grp * 256 + co + 16 * n + l15];

#pragma unroll
    for (int m = 0; m < 4; ++m) {
        const int row = rb + 16 * m + 4 * l4;
#pragma unroll
        for (int r = 0; r < 4; ++r) {
            if (row + r >= NNODE) continue;
#pragma unroll
            for (int n = 0; n < 4; ++n) {
                const int cc = co + 16 * n + l15;
                const unsigned short v = f2bf(acc[m][n][r] + bcol[n]);
                if (grp == 0)
                    PJH[(size_t)(row + r) * 512 + (cc >> 2) * 8 + 4 + (cc & 3)] = v;
                else if (grp == 1)
                    PI[(size_t)(row + r) * 256 + cc] = v;
                else
                    PJH[(size_t)(row + r) * 512 + (cc >> 2) * 8 + (cc & 3)] = v;
            }
        }
    }
}

// ---------------------------------------------------------------------------
// CSR build
// ---------------------------------------------------------------------------
__device__ __forceinline__ int edge_dst(const int* EI, int e) {
    return (e < NEDGE) ? EI[NEDGE + e] : (e - NEDGE);
}
__device__ __forceinline__ int edge_src(const int* EI, int e) {
    return (e < NEDGE) ? EI[e] : (e - NEDGE);
}

__global__ void hist_k(const int* __restrict__ EI, int* __restrict__ counts) {
    int e = blockIdx.x * 256 + threadIdx.x;
    if (e < NTOT) atomicAdd(&counts[edge_dst(EI, e)], 1);
}

__global__ __launch_bounds__(256) void scan_k(const int* __restrict__ counts,
                                              int* __restrict__ start,
                                              int* __restrict__ cursor) {
    __shared__ int chunk[256];
    const int t = threadIdx.x;
    const int per = (NNODE + 255) / 256;   // 40
    const int base = t * per;

    int sum = 0;
    for (int i = 0; i < per; ++i)
        if (base + i < NNODE) sum += counts[base + i];
    chunk[t] = sum;
    __syncthreads();
    if (t == 0) {
        int acc = 0;
        for (int i = 0; i < 256; ++i) { int v = chunk[i]; chunk[i] = acc; acc += v; }
        start[NNODE] = acc;
    }
    __syncthreads();
    int acc = chunk[t];
    for (int i = 0; i < per; ++i) {
        int idx = base + i;
        if (idx < NNODE) {
            start[idx] = acc;
            cursor[idx] = acc;
            acc += counts[idx];
        }
    }
}

__global__ void scatter_k(const int* __restrict__ EI, int* __restrict__ cursor,
                          int* __restrict__ elist) {
    int e = blockIdx.x * 256 + threadIdx.x;
    if (e < NTOT) {
        int d = edge_dst(EI, e);
        int pos = atomicAdd(&cursor[d], 1);
        elist[pos] = e;
    }
}

// deterministic order (rank-sort by edge id) + src conversion, fused
__global__ __launch_bounds__(256) void sortsrc_k(const int* __restrict__ EI,
                                                 int* __restrict__ elist,
                                                 const int* __restrict__ start,
                                                 int* __restrict__ elsrc) {
    __shared__ int buf[2048];
    const int d = blockIdx.x;
    const int st = start[d], en = start[d + 1];
    const int deg = en - st;
    const int t = threadIdx.x;

    if (deg > 1 && deg <= 2048) {
        for (int i = t; i < deg; i += 256) buf[i] = elist[st + i];
        __syncthreads();
        for (int i = t; i < deg; i += 256) {
            int id = buf[i], r = 0;
            for (int j = 0; j < deg; ++j) r += (buf[j] < id);
            elist[st + r] = id;
            elsrc[st + r] = edge_src(EI, id);
        }
    } else {
        for (int i = st + t; i < en; i += 256) elsrc[i] = edge_src(EI, elist[i]);
    }
}

// ---------------------------------------------------------------------------
// Fused score + aggregation v4: one wave per dst node, HALF-WAVE per edge.
// Lanes 0-31 process even-index edges, 32-63 odd; lane li owns cols 8li..8li+7.
//   z(e)  = Ws2 . relu(Pi[d] + Pj[src e]) + b2   (5-level shfl per 2 edges)
//   acc  += sigmoid(z) * h[src e]
// Final cross-half combine via shfl_xor(32). Deterministic (fixed partition).
// ---------------------------------------------------------------------------
template <bool LAST>
__global__ __launch_bounds__(256) void scoreaggr_k(const unsigned short* __restrict__ PI,
                                                   const unsigned short* __restrict__ PJH,
                                                   const int* __restrict__ elsrc,
                                                   const int* __restrict__ start,
                                                   const float* __restrict__ Ws2,
                                                   const float* __restrict__ bs2,
                                                   float* __restrict__ OUT,
                                                   unsigned short* __restrict__ XB) {
    const int t = threadIdx.x;
    const int lane = t & 63, wid = t >> 6;
    const int li = lane & 31, half = lane >> 5;
    const int d = blockIdx.x * 4 + wid;
    const int st = start[d], en = start[d + 1];

    float w2[8];
#pragma unroll
    for (int j = 0; j < 8; ++j) w2[j] = Ws2[8 * li + j];
    const float b2 = bs2[0];

    const uint4 piu = *(const uint4*)(PI + (size_t)d * 256 + 8 * li);
    float pi_[8] = {bflo(piu.x), bfhi(piu.x), bflo(piu.y), bfhi(piu.y),
                    bflo(piu.z), bfhi(piu.z), bflo(piu.w), bfhi(piu.w)};

    float acc[8] = {0.f, 0.f, 0.f, 0.f, 0.f, 0.f, 0.f, 0.f};

#define SA_STEP(SV, MASKED)                                                     \
    {                                                                           \
        const unsigned short* rp = PJH + (size_t)(SV) * 512 + 16 * li;          \
        const uint4 r0 = *(const uint4*)rp;                                     \
        const uint4 r1 = *(const uint4*)(rp + 8);                               \
        float dot = 0.f;                                                        \
        dot = fmaf(fmaxf(pi_[0] + bflo(r0.x), 0.f), w2[0], dot);                \
        dot = fmaf(fmaxf(pi_[1] + bfhi(r0.x), 0.f), w2[1], dot);                \
        dot = fmaf(fmaxf(pi_[2] + bflo(r0.y), 0.f), w2[2], dot);                \
        dot = fmaf(fmaxf(pi_[3] + bfhi(r0.y), 0.f), w2[3], dot);                \
        dot = fmaf(fmaxf(pi_[4] + bflo(r1.x), 0.f), w2[4], dot);                \
        dot = fmaf(fmaxf(pi_[5] + bfhi(r1.x), 0.f), w2[5], dot);                \
        dot = fmaf(fmaxf(pi_[6] + bflo(r1.y), 0.f), w2[6], dot);                \
        dot = fmaf(fmaxf(pi_[7] + bfhi(r1.y), 0.f), w2[7], dot);                \
        dot += __shfl_xor(dot, 16); dot += __shfl_xor(dot, 8);                  \
        dot += __shfl_xor(dot, 4);  dot += __shfl_xor(dot, 2);                  \
        dot += __shfl_xor(dot, 1);                                              \
        float sc = 1.f / (1.f + __expf(-(dot + b2)));                           \
        if (MASKED) sc = half ? 0.f : sc;                                       \
        acc[0] = fmaf(sc, bflo(r0.z), acc[0]);                                  \
        acc[1] = fmaf(sc, bfhi(r0.z), acc[1]);                                  \
        acc[2] = fmaf(sc, bflo(r0.w), acc[2]);                                  \
        acc[3] = fmaf(sc, bfhi(r0.w), acc[3]);                                  \
        acc[4] = fmaf(sc, bflo(r1.z), acc[4]);                                  \
        acc[5] = fmaf(sc, bfhi(r1.z), acc[5]);                                  \
        acc[6] = fmaf(sc, bflo(r1.w), acc[6]);                                  \
        acc[7] = fmaf(sc, bfhi(r1.w), acc[7]);                                  \
    }

    int i = st;
    for (; i + 4 <= en; i += 4) {
        const int sA = elsrc[i + half];
        const int sB = elsrc[i + 2 + half];
        SA_STEP(sA, false)
        SA_STEP(sB, false)
    }
    if (i + 2 <= en) {
        const int sA = elsrc[i + half];
        SA_STEP(sA, false)
        i += 2;
    }
    if (i < en) {
        const int sA = elsrc[i];       // both halves load the same edge
        SA_STEP(sA, true)              // half-1 contribution masked to 0
    }
#undef SA_STEP

#pragma unroll
    for (int j = 0; j < 8; ++j) acc[j] += __shfl_xor(acc[j], 32);

    if (half == 0) {
        if (LAST) {
            float4* op = (float4*)(OUT + (size_t)d * 256 + 8 * li);
            op[0] = make_float4(acc[0], acc[1], acc[2], acc[3]);
            op[1] = make_float4(acc[4], acc[5], acc[6], acc[7]);
        } else {
            ushort4 v0, v1;
            v0.x = f2bf(fmaxf(acc[0], 0.f)); v0.y = f2bf(fmaxf(acc[1], 0.f));
            v0.z = f2bf(fmaxf(acc[2], 0.f)); v0.w = f2bf(fmaxf(acc[3], 0.f));
            v1.x = f2bf(fmaxf(acc[4], 0.f)); v1.y = f2bf(fmaxf(acc[5], 0.f));
            v1.z = f2bf(fmaxf(acc[6], 0.f)); v1.w = f2bf(fmaxf(acc[7], 0.f));
            ushort4* xp = (ushort4*)(XB + (size_t)d * 256 + 8 * li);
            xp[0] = v0; xp[1] = v1;
        }
    }
}

// ---------------------------------------------------------------------------
extern "C" void kernel_launch(void* const* d_in, const int* in_sizes, int n_in,
                              void* d_out, int out_size, void* d_ws, size_t ws_size,
                              hipStream_t stream) {
    const float* x  = (const float*)d_in[0];
    const int*   ei = (const int*)d_in[1];

    const float* Wl[3]  = {(const float*)d_in[2],  (const float*)d_in[8],  (const float*)d_in[14]};
    const float* bl[3]  = {(const float*)d_in[3],  (const float*)d_in[9],  (const float*)d_in[15]};
    const float* Ws1[3] = {(const float*)d_in[4],  (const float*)d_in[10], (const float*)d_in[16]};
    const float* bs1[3] = {(const float*)d_in[5],  (const float*)d_in[11], (const float*)d_in[17]};
    const float* Ws2[3] = {(const float*)d_in[6],  (const float*)d_in[12], (const float*)d_in[18]};
    const float* bs2[3] = {(const float*)d_in[7],  (const float*)d_in[13], (const float*)d_in[19]};

    float* out = (float*)d_out;

    // workspace layout
    char* p = (char*)d_ws;
    unsigned short* PJH  = (unsigned short*)p; p += (size_t)NPAD * 512 * 2;  // 10.3 MB
    unsigned short* PI   = (unsigned short*)p; p += (size_t)NPAD * 256 * 2;  // 5.1 MB
    unsigned short* XB   = (unsigned short*)p; p += (size_t)NPAD * 256 * 2;  // 5.1 MB
    unsigned short* XB1  = (unsigned short*)p; p += (size_t)NPAD * 64 * 2;   // 1.3 MB
    unsigned short* WCB1 = (unsigned short*)p; p += 768 * 64 * 2;
    unsigned short* WCB2 = (unsigned short*)p; p += 768 * 256 * 2;
    unsigned short* WCB3 = (unsigned short*)p; p += 768 * 256 * 2;
    float* BIAS   = (float*)p; p += 3 * 768 * 4;
    int*   counts = (int*)p;  p += NNODE * 4;
    int*   startp = (int*)p;  p += (NNODE + 4) * 4;
    int*   cursor = (int*)p;  p += NNODE * 4;
    int*   elist  = (int*)p;  p += (size_t)NTOT * 4;
    int*   elsrc  = (int*)p;  p += (size_t)NTOT * 4;

    const int nFlat = (NTOT + 255) / 256;    // 1290

    // weight prep (all 3 layers, hoisted)
    prep_k<<<(256 * 64 + 2 * 256 * 256 + 255) / 256, 256, 0, stream>>>(
        Wl[0], Wl[1], Wl[2], bl[0], bl[1], bl[2],
        Ws1[0], Ws1[1], Ws1[2], bs1[0], bs1[1], bs1[2],
        WCB1, WCB2, WCB3, BIAS);
    combW_k<<<dim3(8, 4, 3), 256, 0, stream>>>(
        Wl[0], Wl[1], Wl[2], Ws1[0], Ws1[1], Ws1[2], WCB1, WCB2, WCB3);

    // CSR build (once; graph shared by all 3 layers)
    hipMemsetAsync(counts, 0, NNODE * sizeof(int), stream);
    hist_k<<<nFlat, 256, 0, stream>>>(ei, counts);
    scan_k<<<1, 256, 0, stream>>>(counts, startp, cursor);
    scatter_k<<<nFlat, 256, 0, stream>>>(ei, cursor, elist);
    sortsrc_k<<<NNODE, 256, 0, stream>>>(ei, elist, startp, elsrc);

    // layer-1 A operand + XB pad zero
    castx_k<<<(NPAD * 64 + 255) / 256, 256, 0, stream>>>(x, XB1, XB + (size_t)NNODE * 256);

    const unsigned short* WCBs[3] = {WCB1, WCB2, WCB3};
    for (int L = 0; L < 3; ++L) {
        if (L == 0)
            gemm_k<64><<<dim3(NPAD / 64, 3), 256, 0, stream>>>(XB1, WCBs[0], BIAS, PI, PJH);
        else
            gemm_k<256><<<dim3(NPAD / 64, 3), 256, 0, stream>>>(XB, WCBs[L], BIAS + L * 768, PI, PJH);

        if (L == 2)
            scoreaggr_k<true><<<NNODE / 4, 256, 0, stream>>>(PI, PJH, elsrc, startp,
                                                             Ws2[L], bs2[L], out, nullptr);
        else
            scoreaggr_k<false><<<NNODE / 4, 256, 0, stream>>>(PI, PJH, elsrc, startp,
                                                              Ws2[L], bs2[L], nullptr, XB);
    }
}

// Round 10
// 292.429 us; speedup vs baseline: 47.6153x; 1.0332x over previous
//
#include <hip/hip_runtime.h>
#include <hip/hip_bf16.h>
#include <math.h>

// Problem constants (from reference)
#define NNODE 10000
#define NPAD  10048             // padded to 64-row multiple for MFMA tiles
#define NEDGE 320000
#define NTOT  (NEDGE + NNODE)   // 330000 incl. self loops
#define INC   64
#define C     256               // HID == OUT_C == 256

typedef short bf16x8 __attribute__((ext_vector_type(8)));
typedef float f32x4  __attribute__((ext_vector_type(4)));

union I4B { int4 i4; bf16x8 b; };

__device__ __forceinline__ unsigned short f2bf(float v) {
    __hip_bfloat16 b = __float2bfloat16(v);   // RNE
    return *reinterpret_cast<unsigned short*>(&b);
}
__device__ __forceinline__ float bflo(unsigned u) { return __uint_as_float(u << 16); }
__device__ __forceinline__ float bfhi(unsigned u) { return __uint_as_float(u & 0xffff0000u); }

// ---------------------------------------------------------------------------
// setup_k: fused one-shot prep (saves 3 dispatches)
//   - XB1[NPAD x 64] = bf16(x), zero pad rows          (layer-1 A operand)
//   - zero pad rows of XB                               (layers-2/3 A operand)
//   - counts[] = 0                                      (CSR histogram init)
//   - WCB rows [0,256) = bf16(Wl) flat copy, 3 layers
//   - BIAS[L][768]: c<256: bl; c<512: bs1+Wi.bl; else Wj.bl
// ---------------------------------------------------------------------------
__global__ __launch_bounds__(256) void setup_k(
        const float* __restrict__ x, unsigned short* __restrict__ XB1,
        unsigned short* __restrict__ XBpad, int* __restrict__ counts,
        const float* __restrict__ Wl1, const float* __restrict__ Wl2,
        const float* __restrict__ Wl3,
        const float* __restrict__ bl1, const float* __restrict__ bl2,
        const float* __restrict__ bl3,
        const float* __restrict__ Ws11, const float* __restrict__ Ws12,
        const float* __restrict__ Ws13,
        const float* __restrict__ bs11, const float* __restrict__ bs12,
        const float* __restrict__ bs13,
        unsigned short* __restrict__ WCB1, unsigned short* __restrict__ WCB2,
        unsigned short* __restrict__ WCB3, float* __restrict__ BIAS) {
    const int i = blockIdx.x * 256 + threadIdx.x;

    if (i < NPAD * 64) XB1[i] = (i < NNODE * 64) ? f2bf(x[i]) : (unsigned short)0;
    if (i < (NPAD - NNODE) * 256) XBpad[i] = 0;
    if (i < NNODE) counts[i] = 0;

    if (i < 256 * 64) WCB1[i] = f2bf(Wl1[i]);
    else if (i < 256 * 64 + 256 * 256) {
        int i2 = i - 256 * 64; WCB2[i2] = f2bf(Wl2[i2]);
    } else if (i < 256 * 64 + 2 * 256 * 256) {
        int i3 = i - 256 * 64 - 256 * 256; WCB3[i3] = f2bf(Wl3[i3]);
    }

    if (i < 3 * 768) {
        const int L = i / 768, c = i - L * 768;
        const float* bl  = (L == 0) ? bl1  : (L == 1) ? bl2  : bl3;
        const float* Ws1 = (L == 0) ? Ws11 : (L == 1) ? Ws12 : Ws13;
        const float* bs1 = (L == 0) ? bs11 : (L == 1) ? bs12 : bs13;
        float b;
        if (c < 256) b = bl[c];
        else {
            const int cc = c & 255;
            const int off = (c < 512) ? 0 : 256;
            float s = (c < 512) ? bs1[cc] : 0.f;
            for (int m = 0; m < 256; ++m)
                s = fmaf(Ws1[cc * 512 + off + m], bl[m], s);
            b = s;
        }
        BIAS[L * 768 + c] = b;
    }
}

// ---------------------------------------------------------------------------
// combW_k: WCB rows [256,768) = bf16( A @ Wl ), A[r][m] = Ws1[r&255][off+m],
// off = (r<256 ? 0 : 256).  Tiled 64x64, LDS-staged, all 3 layers.
// grid (8, 4, 3): x = r-tile, y = k-tile (guarded for K=64), z = layer.
// ---------------------------------------------------------------------------
__global__ __launch_bounds__(256) void combW_k(
        const float* __restrict__ Wl1, const float* __restrict__ Wl2,
        const float* __restrict__ Wl3,
        const float* __restrict__ Ws11, const float* __restrict__ Ws12,
        const float* __restrict__ Ws13,
        unsigned short* __restrict__ WCB1, unsigned short* __restrict__ WCB2,
        unsigned short* __restrict__ WCB3) {
    const int L = blockIdx.z;
    const int K = (L == 0) ? 64 : 256;
    const int kt = blockIdx.y;
    if (kt * 64 >= K) return;
    const int rt = blockIdx.x;

    const float* Wl  = (L == 0) ? Wl1  : (L == 1) ? Wl2  : Wl3;
    const float* Ws1 = (L == 0) ? Ws11 : (L == 1) ? Ws12 : Ws13;
    unsigned short* WCB = (L == 0) ? WCB1 : (L == 1) ? WCB2 : WCB3;

    __shared__ float As[32][68];
    __shared__ float Bs[32][68];

    const int t = threadIdx.x;
    const int tr = t >> 4, tk = t & 15;

    float acc[4][4];
#pragma unroll
    for (int i = 0; i < 4; ++i)
#pragma unroll
        for (int j = 0; j < 4; ++j) acc[i][j] = 0.f;

    for (int mb = 0; mb < 256; mb += 32) {
        {
            const int r = t >> 2, mg = t & 3;
            const int gr = rt * 64 + r;
            const int cc = gr & 255;
            const int off = (gr < 256) ? 0 : 256;
            const float* src = Ws1 + (size_t)cc * 512 + off + mb + mg * 8;
            float4 a0 = *(const float4*)src;
            float4 a1 = *(const float4*)(src + 4);
            As[mg * 8 + 0][r] = a0.x; As[mg * 8 + 1][r] = a0.y;
            As[mg * 8 + 2][r] = a0.z; As[mg * 8 + 3][r] = a0.w;
            As[mg * 8 + 4][r] = a1.x; As[mg * 8 + 5][r] = a1.y;
            As[mg * 8 + 6][r] = a1.z; As[mg * 8 + 7][r] = a1.w;
        }
        {
            const int m = t >> 3, kg = t & 7;
            const float* src = Wl + (size_t)(mb + m) * K + kt * 64 + kg * 8;
            *(float4*)&Bs[m][kg * 8]     = *(const float4*)src;
            *(float4*)&Bs[m][kg * 8 + 4] = *(const float4*)(src + 4);
        }
        __syncthreads();

#pragma unroll 8
        for (int m = 0; m < 32; ++m) {
            float4 av = *(const float4*)&As[m][tr * 4];
            float4 bv = *(const float4*)&Bs[m][tk * 4];
            float ax[4] = {av.x, av.y, av.z, av.w};
            float bx[4] = {bv.x, bv.y, bv.z, bv.w};
#pragma unroll
            for (int i = 0; i < 4; ++i)
#pragma unroll
                for (int j = 0; j < 4; ++j)
                    acc[i][j] = fmaf(ax[i], bx[j], acc[i][j]);
        }
        __syncthreads();
    }

#pragma unroll
    for (int i = 0; i < 4; ++i) {
        const int row = 256 + rt * 64 + tr * 4 + i;
#pragma unroll
        for (int j = 0; j < 4; ++j)
            WCB[(size_t)row * K + kt * 64 + tk * 4 + j] = f2bf(acc[i][j]);
    }
}

// ---------------------------------------------------------------------------
// Fused GEMM via bf16 MFMA:  [h | Pi | Pj] = A @ WCB^T + BIAS
// Block: 64 rows x 256 cols (4 waves); grid (NPAD/64, 3); blockIdx.y = group
//   (0: h -> PJH h-slots, 1: Pi -> PI, 2: Pj -> PJH pj-slots).
// PJH record per node (1 KB): 64 chunks of {pj[4c..4c+3], h[4c..4c+3]} bf16.
// ---------------------------------------------------------------------------
template <int K>
__global__ __launch_bounds__(256, 2) void gemm_k(const unsigned short* __restrict__ XB,
                                                 const unsigned short* __restrict__ WCB,
                                                 const float* __restrict__ BIAS,
                                                 unsigned short* __restrict__ PI,
                                                 unsigned short* __restrict__ PJH) {
    const int t = threadIdx.x;
    const int lane = t & 63, wid = t >> 6;
    const int l15 = lane & 15, l4 = lane >> 4;
    const int rb = blockIdx.x * 64;
    const int grp = blockIdx.y;                 // 0:h 1:Pi 2:Pj
    const int co = wid * 64;                    // col within group [0,256)

    const unsigned short* pa[4];
#pragma unroll
    for (int m = 0; m < 4; ++m)
        pa[m] = XB + (size_t)(rb + 16 * m + l15) * K + l4 * 8;
    const unsigned short* pb[4];
#pragma unroll
    for (int n = 0; n < 4; ++n)
        pb[n] = WCB + (size_t)(grp * 256 + co + 16 * n + l15) * K + l4 * 8;

    f32x4 acc[4][4];
#pragma unroll
    for (int m = 0; m < 4; ++m)
#pragma unroll
        for (int n = 0; n < 4; ++n) acc[m][n] = (f32x4)(0.f);

#pragma unroll
    for (int ks = 0; ks < K / 32; ++ks) {
        bf16x8 af[4], bfr[4];
#pragma unroll
        for (int m = 0; m < 4; ++m) {
            I4B u; u.i4 = *(const int4*)(pa[m] + ks * 32); af[m] = u.b;
        }
#pragma unroll
        for (int n = 0; n < 4; ++n) {
            I4B u; u.i4 = *(const int4*)(pb[n] + ks * 32); bfr[n] = u.b;
        }
#pragma unroll
        for (int m = 0; m < 4; ++m)
#pragma unroll
            for (int n = 0; n < 4; ++n)
                acc[m][n] = __builtin_amdgcn_mfma_f32_16x16x32_bf16(
                    af[m], bfr[n], acc[m][n], 0, 0, 0);
    }

    float bcol[4];
#pragma unroll
    for (int n = 0; n < 4; ++n) bcol[n] = BIAS[grp * 256 + co + 16 * n + l15];

#pragma unroll
    for (int m = 0; m < 4; ++m) {
        const int row = rb + 16 * m + 4 * l4;
#pragma unroll
        for (int r = 0; r < 4; ++r) {
            if (row + r >= NNODE) continue;
#pragma unroll
            for (int n = 0; n < 4; ++n) {
                const int cc = co + 16 * n + l15;
                const unsigned short v = f2bf(acc[m][n][r] + bcol[n]);
                if (grp == 0)
                    PJH[(size_t)(row + r) * 512 + (cc >> 2) * 8 + 4 + (cc & 3)] = v;
                else if (grp == 1)
                    PI[(size_t)(row + r) * 256 + cc] = v;
                else
                    PJH[(size_t)(row + r) * 512 + (cc >> 2) * 8 + (cc & 3)] = v;
            }
        }
    }
}

// ---------------------------------------------------------------------------
// CSR build
// ---------------------------------------------------------------------------
__device__ __forceinline__ int edge_dst(const int* EI, int e) {
    return (e < NEDGE) ? EI[NEDGE + e] : (e - NEDGE);
}
__device__ __forceinline__ int edge_src(const int* EI, int e) {
    return (e < NEDGE) ? EI[e] : (e - NEDGE);
}

__global__ void hist_k(const int* __restrict__ EI, int* __restrict__ counts) {
    int e = blockIdx.x * 256 + threadIdx.x;
    if (e < NTOT) atomicAdd(&counts[edge_dst(EI, e)], 1);
}

// parallel block-wide scan (Hillis-Steele over 256 chunk sums)
__global__ __launch_bounds__(256) void scan_k(const int* __restrict__ counts,
                                              int* __restrict__ start,
                                              int* __restrict__ cursor) {
    __shared__ int chunk[256];
    const int t = threadIdx.x;
    const int per = (NNODE + 255) / 256;   // 40
    const int base = t * per;

    int sum = 0;
    for (int i = 0; i < per; ++i)
        if (base + i < NNODE) sum += counts[base + i];
    chunk[t] = sum;
    __syncthreads();

#pragma unroll
    for (int off = 1; off < 256; off <<= 1) {
        const int v = (t >= off) ? chunk[t - off] : 0;
        __syncthreads();
        chunk[t] += v;
        __syncthreads();
    }
    if (t == 255) start[NNODE] = chunk[255];

    int acc = chunk[t] - sum;   // exclusive prefix of this thread's chunk
    for (int i = 0; i < per; ++i) {
        int idx = base + i;
        if (idx < NNODE) {
            start[idx] = acc;
            cursor[idx] = acc;
            acc += counts[idx];
        }
    }
}

__global__ void scatter_k(const int* __restrict__ EI, int* __restrict__ cursor,
                          int* __restrict__ elist) {
    int e = blockIdx.x * 256 + threadIdx.x;
    if (e < NTOT) {
        int d = edge_dst(EI, e);
        int pos = atomicAdd(&cursor[d], 1);
        elist[pos] = e;
    }
}

// deterministic order (rank-sort by edge id) + src conversion, fused
__global__ __launch_bounds__(256) void sortsrc_k(const int* __restrict__ EI,
                                                 int* __restrict__ elist,
                                                 const int* __restrict__ start,
                                                 int* __restrict__ elsrc) {
    __shared__ int buf[2048];
    const int d = blockIdx.x;
    const int st = start[d], en = start[d + 1];
    const int deg = en - st;
    const int t = threadIdx.x;

    if (deg > 1 && deg <= 2048) {
        for (int i = t; i < deg; i += 256) buf[i] = elist[st + i];
        __syncthreads();
        for (int i = t; i < deg; i += 256) {
            int id = buf[i], r = 0;
            for (int j = 0; j < deg; ++j) r += (buf[j] < id);
            elist[st + r] = id;
            elsrc[st + r] = edge_src(EI, id);
        }
    } else {
        for (int i = st + t; i < en; i += 256) elsrc[i] = edge_src(EI, elist[i]);
    }
}

// ---------------------------------------------------------------------------
// Fused score + aggregation v5: one wave per dst node, HALF-WAVE per edge.
// d/st/en forced wave-uniform via readfirstlane -> elsrc loads lower to
// scalar (SMEM) loads, off the VMEM critical path.
// Lanes 0-31 process even-index edges, 32-63 odd; lane li owns cols 8li..8li+7.
//   z(e)  = Ws2 . relu(Pi[d] + Pj[src e]) + b2   (5-level shfl per 2 edges)
//   acc  += sigmoid(z) * h[src e]
// Final cross-half combine via shfl_xor(32). Deterministic (fixed partition).
// ---------------------------------------------------------------------------
template <bool LAST>
__global__ __launch_bounds__(256) void scoreaggr_k(const unsigned short* __restrict__ PI,
                                                   const unsigned short* __restrict__ PJH,
                                                   const int* __restrict__ elsrc,
                                                   const int* __restrict__ start,
                                                   const float* __restrict__ Ws2,
                                                   const float* __restrict__ bs2,
                                                   float* __restrict__ OUT,
                                                   unsigned short* __restrict__ XB) {
    const int t = threadIdx.x;
    const int lane = t & 63, wid = t >> 6;
    const int li = lane & 31, half = lane >> 5;
    const int d  = __builtin_amdgcn_readfirstlane(blockIdx.x * 4 + wid);
    const int st = __builtin_amdgcn_readfirstlane(start[d]);
    const int en = __builtin_amdgcn_readfirstlane(start[d + 1]);

    float w2[8];
#pragma unroll
    for (int j = 0; j < 8; ++j) w2[j] = Ws2[8 * li + j];
    const float b2 = bs2[0];

    const uint4 piu = *(const uint4*)(PI + (size_t)d * 256 + 8 * li);
    float pi_[8] = {bflo(piu.x), bfhi(piu.x), bflo(piu.y), bfhi(piu.y),
                    bflo(piu.z), bfhi(piu.z), bflo(piu.w), bfhi(piu.w)};

    float acc[8] = {0.f, 0.f, 0.f, 0.f, 0.f, 0.f, 0.f, 0.f};

#define SA_STEP(SV, MASKED)                                                     \
    {                                                                           \
        const unsigned short* rp = PJH + (size_t)(SV) * 512 + 16 * li;          \
        const uint4 r0 = *(const uint4*)rp;                                     \
        const uint4 r1 = *(const uint4*)(rp + 8);                               \
        float dot = 0.f;                                                        \
        dot = fmaf(fmaxf(pi_[0] + bflo(r0.x), 0.f), w2[0], dot);                \
        dot = fmaf(fmaxf(pi_[1] + bfhi(r0.x), 0.f), w2[1], dot);                \
        dot = fmaf(fmaxf(pi_[2] + bflo(r0.y), 0.f), w2[2], dot);                \
        dot = fmaf(fmaxf(pi_[3] + bfhi(r0.y), 0.f), w2[3], dot);                \
        dot = fmaf(fmaxf(pi_[4] + bflo(r1.x), 0.f), w2[4], dot);                \
        dot = fmaf(fmaxf(pi_[5] + bfhi(r1.x), 0.f), w2[5], dot);                \
        dot = fmaf(fmaxf(pi_[6] + bflo(r1.y), 0.f), w2[6], dot);                \
        dot = fmaf(fmaxf(pi_[7] + bfhi(r1.y), 0.f), w2[7], dot);                \
        dot += __shfl_xor(dot, 16); dot += __shfl_xor(dot, 8);                  \
        dot += __shfl_xor(dot, 4);  dot += __shfl_xor(dot, 2);                  \
        dot += __shfl_xor(dot, 1);                                              \
        float sc = 1.f / (1.f + __expf(-(dot + b2)));                           \
        if (MASKED) sc = half ? 0.f : sc;                                       \
        acc[0] = fmaf(sc, bflo(r0.z), acc[0]);                                  \
        acc[1] = fmaf(sc, bfhi(r0.z), acc[1]);                                  \
        acc[2] = fmaf(sc, bflo(r0.w), acc[2]);                                  \
        acc[3] = fmaf(sc, bfhi(r0.w), acc[3]);                                  \
        acc[4] = fmaf(sc, bflo(r1.z), acc[4]);                                  \
        acc[5] = fmaf(sc, bfhi(r1.z), acc[5]);                                  \
        acc[6] = fmaf(sc, bflo(r1.w), acc[6]);                                  \
        acc[7] = fmaf(sc, bfhi(r1.w), acc[7]);                                  \
    }

    int i = st;
    for (; i + 4 <= en; i += 4) {
        // wave-uniform addresses -> scalar loads
        const int e0 = elsrc[i],     e1 = elsrc[i + 1];
        const int e2 = elsrc[i + 2], e3 = elsrc[i + 3];
        const int sA = half ? e1 : e0;
        const int sB = half ? e3 : e2;
        SA_STEP(sA, false)
        SA_STEP(sB, false)
    }
    if (i + 2 <= en) {
        const int e0 = elsrc[i], e1 = elsrc[i + 1];
        const int sA = half ? e1 : e0;
        SA_STEP(sA, false)
        i += 2;
    }
    if (i < en) {
        const int e0 = elsrc[i];       // both halves load the same edge
        SA_STEP(e0, true)              // half-1 contribution masked to 0
    }
#undef SA_STEP

#pragma unroll
    for (int j = 0; j < 8; ++j) acc[j] += __shfl_xor(acc[j], 32);

    if (half == 0) {
        if (LAST) {
            float4* op = (float4*)(OUT + (size_t)d * 256 + 8 * li);
            op[0] = make_float4(acc[0], acc[1], acc[2], acc[3]);
            op[1] = make_float4(acc[4], acc[5], acc[6], acc[7]);
        } else {
            ushort4 v0, v1;
            v0.x = f2bf(fmaxf(acc[0], 0.f)); v0.y = f2bf(fmaxf(acc[1], 0.f));
            v0.z = f2bf(fmaxf(acc[2], 0.f)); v0.w = f2bf(fmaxf(acc[3], 0.f));
            v1.x = f2bf(fmaxf(acc[4], 0.f)); v1.y = f2bf(fmaxf(acc[5], 0.f));
            v1.z = f2bf(fmaxf(acc[6], 0.f)); v1.w = f2bf(fmaxf(acc[7], 0.f));
            ushort4* xp = (ushort4*)(XB + (size_t)d * 256 + 8 * li);
            xp[0] = v0; xp[1] = v1;
        }
    }
}

// ---------------------------------------------------------------------------
extern "C" void kernel_launch(void* const* d_in, const int* in_sizes, int n_in,
                              void* d_out, int out_size, void* d_ws, size_t ws_size,
                              hipStream_t stream) {
    const float* x  = (const float*)d_in[0];
    const int*   ei = (const int*)d_in[1];

    const float* Wl[3]  = {(const float*)d_in[2],  (const float*)d_in[8],  (const float*)d_in[14]};
    const float* bl[3]  = {(const float*)d_in[3],  (const float*)d_in[9],  (const float*)d_in[15]};
    const float* Ws1[3] = {(const float*)d_in[4],  (const float*)d_in[10], (const float*)d_in[16]};
    const float* bs1[3] = {(const float*)d_in[5],  (const float*)d_in[11], (const float*)d_in[17]};
    const float* Ws2[3] = {(const float*)d_in[6],  (const float*)d_in[12], (const float*)d_in[18]};
    const float* bs2[3] = {(const float*)d_in[7],  (const float*)d_in[13], (const float*)d_in[19]};

    float* out = (float*)d_out;

    // workspace layout
    char* p = (char*)d_ws;
    unsigned short* PJH  = (unsigned short*)p; p += (size_t)NPAD * 512 * 2;  // 10.3 MB
    unsigned short* PI   = (unsigned short*)p; p += (size_t)NPAD * 256 * 2;  // 5.1 MB
    unsigned short* XB   = (unsigned short*)p; p += (size_t)NPAD * 256 * 2;  // 5.1 MB
    unsigned short* XB1  = (unsigned short*)p; p += (size_t)NPAD * 64 * 2;   // 1.3 MB
    unsigned short* WCB1 = (unsigned short*)p; p += 768 * 64 * 2;
    unsigned short* WCB2 = (unsigned short*)p; p += 768 * 256 * 2;
    unsigned short* WCB3 = (unsigned short*)p; p += 768 * 256 * 2;
    float* BIAS   = (float*)p; p += 3 * 768 * 4;
    int*   counts = (int*)p;  p += NNODE * 4;
    int*   startp = (int*)p;  p += (NNODE + 4) * 4;
    int*   cursor = (int*)p;  p += NNODE * 4;
    int*   elist  = (int*)p;  p += (size_t)NTOT * 4;
    int*   elsrc  = (int*)p;  p += (size_t)NTOT * 4;

    const int nFlat = (NTOT + 255) / 256;    // 1290

    // fused setup (castx + pad zero + counts zero + Wl copies + bias dots)
    setup_k<<<(NPAD * 64 + 255) / 256, 256, 0, stream>>>(
        x, XB1, XB + (size_t)NNODE * 256, counts,
        Wl[0], Wl[1], Wl[2], bl[0], bl[1], bl[2],
        Ws1[0], Ws1[1], Ws1[2], bs1[0], bs1[1], bs1[2],
        WCB1, WCB2, WCB3, BIAS);
    combW_k<<<dim3(8, 4, 3), 256, 0, stream>>>(
        Wl[0], Wl[1], Wl[2], Ws1[0], Ws1[1], Ws1[2], WCB1, WCB2, WCB3);

    // CSR build (once; graph shared by all 3 layers)
    hist_k<<<nFlat, 256, 0, stream>>>(ei, counts);
    scan_k<<<1, 256, 0, stream>>>(counts, startp, cursor);
    scatter_k<<<nFlat, 256, 0, stream>>>(ei, cursor, elist);
    sortsrc_k<<<NNODE, 256, 0, stream>>>(ei, elist, startp, elsrc);

    const unsigned short* WCBs[3] = {WCB1, WCB2, WCB3};
    for (int L = 0; L < 3; ++L) {
        if (L == 0)
            gemm_k<64><<<dim3(NPAD / 64, 3), 256, 0, stream>>>(XB1, WCBs[0], BIAS, PI, PJH);
        else
            gemm_k<256><<<dim3(NPAD / 64, 3), 256, 0, stream>>>(XB, WCBs[L], BIAS + L * 768, PI, PJH);

        if (L == 2)
            scoreaggr_k<true><<<NNODE / 4, 256, 0, stream>>>(PI, PJH, elsrc, startp,
                                                             Ws2[L], bs2[L], out, nullptr);
        else
            scoreaggr_k<false><<<NNODE / 4, 256, 0, stream>>>(PI, PJH, elsrc, startp,
                                                              Ws2[L], bs2[L], nullptr, XB);
    }
}

// Round 11
// 286.136 us; speedup vs baseline: 48.6625x; 1.0220x over previous
//
#include <hip/hip_runtime.h>
#include <hip/hip_bf16.h>
#include <math.h>

// Problem constants (from reference)
#define NNODE 10000
#define NPAD  10048             // padded to 64-row multiple for MFMA tiles
#define NEDGE 320000
#define NTOT  (NEDGE + NNODE)   // 330000 incl. self loops
#define INC   64
#define C     256               // HID == OUT_C == 256

typedef short bf16x8 __attribute__((ext_vector_type(8)));
typedef float f32x4  __attribute__((ext_vector_type(4)));

union I4B { int4 i4; bf16x8 b; };

__device__ __forceinline__ unsigned short f2bf(float v) {
    __hip_bfloat16 b = __float2bfloat16(v);   // RNE
    return *reinterpret_cast<unsigned short*>(&b);
}
__device__ __forceinline__ float bflo(unsigned u) { return __uint_as_float(u << 16); }
__device__ __forceinline__ float bfhi(unsigned u) { return __uint_as_float(u & 0xffff0000u); }

// ---------------------------------------------------------------------------
// setupcomb_k: fused one-shot prep (one dispatch)
// Blocks [0, SETUP_BLKS): elementwise setup
//   - XB1[NPAD x 64] = bf16(x), zero pad rows          (layer-1 A operand)
//   - zero pad rows of XB                               (layers-2/3 A operand)
//   - counts[] = 0                                      (CSR histogram init)
//   - WCB rows [0,256) = bf16(Wl) flat copy, 3 layers
//   - BIAS[L][768]: c<256: bl; c<512: bs1+Wi.bl; else Wj.bl
// Blocks [SETUP_BLKS, SETUP_BLKS+96): combW — WCB rows [256,768) =
//   bf16( A @ Wl ), A[r][m] = Ws1[r&255][off+m], off = (r<256?0:256).
//   Tiled 64x64, LDS-staged. bid decomposition: L=bid/32, kt=(bid%32)/8,
//   rt=bid%8 (kt guarded for K=64).
// ---------------------------------------------------------------------------
#define SETUP_BLKS 2512   // NPAD*64/256

__global__ __launch_bounds__(256) void setupcomb_k(
        const float* __restrict__ x, unsigned short* __restrict__ XB1,
        unsigned short* __restrict__ XBpad, int* __restrict__ counts,
        const float* __restrict__ Wl1, const float* __restrict__ Wl2,
        const float* __restrict__ Wl3,
        const float* __restrict__ bl1, const float* __restrict__ bl2,
        const float* __restrict__ bl3,
        const float* __restrict__ Ws11, const float* __restrict__ Ws12,
        const float* __restrict__ Ws13,
        const float* __restrict__ bs11, const float* __restrict__ bs12,
        const float* __restrict__ bs13,
        unsigned short* __restrict__ WCB1, unsigned short* __restrict__ WCB2,
        unsigned short* __restrict__ WCB3, float* __restrict__ BIAS) {
    const int t = threadIdx.x;

    if (blockIdx.x < SETUP_BLKS) {
        const int i = blockIdx.x * 256 + t;

        if (i < NPAD * 64) XB1[i] = (i < NNODE * 64) ? f2bf(x[i]) : (unsigned short)0;
        if (i < (NPAD - NNODE) * 256) XBpad[i] = 0;
        if (i < NNODE) counts[i] = 0;

        if (i < 256 * 64) WCB1[i] = f2bf(Wl1[i]);
        else if (i < 256 * 64 + 256 * 256) {
            int i2 = i - 256 * 64; WCB2[i2] = f2bf(Wl2[i2]);
        } else if (i < 256 * 64 + 2 * 256 * 256) {
            int i3 = i - 256 * 64 - 256 * 256; WCB3[i3] = f2bf(Wl3[i3]);
        }

        if (i < 3 * 768) {
            const int L = i / 768, c = i - L * 768;
            const float* bl  = (L == 0) ? bl1  : (L == 1) ? bl2  : bl3;
            const float* Ws1 = (L == 0) ? Ws11 : (L == 1) ? Ws12 : Ws13;
            const float* bs1 = (L == 0) ? bs11 : (L == 1) ? bs12 : bs13;
            float b;
            if (c < 256) b = bl[c];
            else {
                const int cc = c & 255;
                const int off = (c < 512) ? 0 : 256;
                float s = (c < 512) ? bs1[cc] : 0.f;
                for (int m = 0; m < 256; ++m)
                    s = fmaf(Ws1[cc * 512 + off + m], bl[m], s);
                b = s;
            }
            BIAS[L * 768 + c] = b;
        }
        return;
    }

    // ---- combW part ----
    const int bid = blockIdx.x - SETUP_BLKS;   // [0,96)
    const int L = bid >> 5;
    const int rem = bid & 31;
    const int kt = rem >> 3;
    const int rt = rem & 7;
    const int K = (L == 0) ? 64 : 256;
    if (kt * 64 >= K) return;

    const float* Wl  = (L == 0) ? Wl1  : (L == 1) ? Wl2  : Wl3;
    const float* Ws1 = (L == 0) ? Ws11 : (L == 1) ? Ws12 : Ws13;
    unsigned short* WCB = (L == 0) ? WCB1 : (L == 1) ? WCB2 : WCB3;

    __shared__ float As[32][68];
    __shared__ float Bs[32][68];

    const int tr = t >> 4, tk = t & 15;

    float acc[4][4];
#pragma unroll
    for (int i = 0; i < 4; ++i)
#pragma unroll
        for (int j = 0; j < 4; ++j) acc[i][j] = 0.f;

    for (int mb = 0; mb < 256; mb += 32) {
        {
            const int r = t >> 2, mg = t & 3;
            const int gr = rt * 64 + r;
            const int cc = gr & 255;
            const int off = (gr < 256) ? 0 : 256;
            const float* src = Ws1 + (size_t)cc * 512 + off + mb + mg * 8;
            float4 a0 = *(const float4*)src;
            float4 a1 = *(const float4*)(src + 4);
            As[mg * 8 + 0][r] = a0.x; As[mg * 8 + 1][r] = a0.y;
            As[mg * 8 + 2][r] = a0.z; As[mg * 8 + 3][r] = a0.w;
            As[mg * 8 + 4][r] = a1.x; As[mg * 8 + 5][r] = a1.y;
            As[mg * 8 + 6][r] = a1.z; As[mg * 8 + 7][r] = a1.w;
        }
        {
            const int m = t >> 3, kg = t & 7;
            const float* src = Wl + (size_t)(mb + m) * K + kt * 64 + kg * 8;
            *(float4*)&Bs[m][kg * 8]     = *(const float4*)src;
            *(float4*)&Bs[m][kg * 8 + 4] = *(const float4*)(src + 4);
        }
        __syncthreads();

#pragma unroll 8
        for (int m = 0; m < 32; ++m) {
            float4 av = *(const float4*)&As[m][tr * 4];
            float4 bv = *(const float4*)&Bs[m][tk * 4];
            float ax[4] = {av.x, av.y, av.z, av.w};
            float bx[4] = {bv.x, bv.y, bv.z, bv.w};
#pragma unroll
            for (int i = 0; i < 4; ++i)
#pragma unroll
                for (int j = 0; j < 4; ++j)
                    acc[i][j] = fmaf(ax[i], bx[j], acc[i][j]);
        }
        __syncthreads();
    }

#pragma unroll
    for (int i = 0; i < 4; ++i) {
        const int row = 256 + rt * 64 + tr * 4 + i;
#pragma unroll
        for (int j = 0; j < 4; ++j)
            WCB[(size_t)row * K + kt * 64 + tk * 4 + j] = f2bf(acc[i][j]);
    }
}

// ---------------------------------------------------------------------------
// Fused GEMM via bf16 MFMA:  [h | Pi | Pj] = A @ WCB^T + BIAS
// Block: 64 rows x 256 cols (4 waves); grid (NPAD/64, 3); blockIdx.y = group
//   (0: h -> PJH h-slots, 1: Pi -> PI, 2: Pj -> PJH pj-slots).
// PJH record per node (1 KB): 64 chunks of {pj[4c..4c+3], h[4c..4c+3]} bf16.
// Depth-1 fragment prefetch: loads for ks+1 issued before the MFMAs of ks.
// ---------------------------------------------------------------------------
template <int K>
__global__ __launch_bounds__(256, 2) void gemm_k(const unsigned short* __restrict__ XB,
                                                 const unsigned short* __restrict__ WCB,
                                                 const float* __restrict__ BIAS,
                                                 unsigned short* __restrict__ PI,
                                                 unsigned short* __restrict__ PJH) {
    const int t = threadIdx.x;
    const int lane = t & 63, wid = t >> 6;
    const int l15 = lane & 15, l4 = lane >> 4;
    const int rb = blockIdx.x * 64;
    const int grp = blockIdx.y;                 // 0:h 1:Pi 2:Pj
    const int co = wid * 64;                    // col within group [0,256)

    const unsigned short* pa[4];
#pragma unroll
    for (int m = 0; m < 4; ++m)
        pa[m] = XB + (size_t)(rb + 16 * m + l15) * K + l4 * 8;
    const unsigned short* pb[4];
#pragma unroll
    for (int n = 0; n < 4; ++n)
        pb[n] = WCB + (size_t)(grp * 256 + co + 16 * n + l15) * K + l4 * 8;

    f32x4 acc[4][4];
#pragma unroll
    for (int m = 0; m < 4; ++m)
#pragma unroll
        for (int n = 0; n < 4; ++n) acc[m][n] = (f32x4)(0.f);

    constexpr int NKS = K / 32;
    bf16x8 af[4], bfr[4];
    // prime ks = 0
#pragma unroll
    for (int m = 0; m < 4; ++m) { I4B u; u.i4 = *(const int4*)(pa[m]); af[m] = u.b; }
#pragma unroll
    for (int n = 0; n < 4; ++n) { I4B u; u.i4 = *(const int4*)(pb[n]); bfr[n] = u.b; }

#pragma unroll
    for (int ks = 0; ks < NKS; ++ks) {
        bf16x8 naf[4], nbf[4];
        if (ks + 1 < NKS) {
#pragma unroll
            for (int m = 0; m < 4; ++m) {
                I4B u; u.i4 = *(const int4*)(pa[m] + (ks + 1) * 32); naf[m] = u.b;
            }
#pragma unroll
            for (int n = 0; n < 4; ++n) {
                I4B u; u.i4 = *(const int4*)(pb[n] + (ks + 1) * 32); nbf[n] = u.b;
            }
        }
#pragma unroll
        for (int m = 0; m < 4; ++m)
#pragma unroll
            for (int n = 0; n < 4; ++n)
                acc[m][n] = __builtin_amdgcn_mfma_f32_16x16x32_bf16(
                    af[m], bfr[n], acc[m][n], 0, 0, 0);
        if (ks + 1 < NKS) {
#pragma unroll
            for (int m = 0; m < 4; ++m) af[m] = naf[m];
#pragma unroll
            for (int n = 0; n < 4; ++n) bfr[n] = nbf[n];
        }
    }

    float bcol[4];
#pragma unroll
    for (int n = 0; n < 4; ++n) bcol[n] = BIAS[grp * 256 + co + 16 * n + l15];

#pragma unroll
    for (int m = 0; m < 4; ++m) {
        const int row = rb + 16 * m + 4 * l4;
#pragma unroll
        for (int r = 0; r < 4; ++r) {
            if (row + r >= NNODE) continue;
#pragma unroll
            for (int n = 0; n < 4; ++n) {
                const int cc = co + 16 * n + l15;
                const unsigned short v = f2bf(acc[m][n][r] + bcol[n]);
                if (grp == 0)
                    PJH[(size_t)(row + r) * 512 + (cc >> 2) * 8 + 4 + (cc & 3)] = v;
                else if (grp == 1)
                    PI[(size_t)(row + r) * 256 + cc] = v;
                else
                    PJH[(size_t)(row + r) * 512 + (cc >> 2) * 8 + (cc & 3)] = v;
            }
        }
    }
}

// ---------------------------------------------------------------------------
// CSR build
// ---------------------------------------------------------------------------
__device__ __forceinline__ int edge_dst(const int* EI, int e) {
    return (e < NEDGE) ? EI[NEDGE + e] : (e - NEDGE);
}
__device__ __forceinline__ int edge_src(const int* EI, int e) {
    return (e < NEDGE) ? EI[e] : (e - NEDGE);
}

__global__ void hist_k(const int* __restrict__ EI, int* __restrict__ counts) {
    int e = blockIdx.x * 256 + threadIdx.x;
    if (e < NTOT) atomicAdd(&counts[edge_dst(EI, e)], 1);
}

// parallel block-wide scan (Hillis-Steele over 256 chunk sums)
__global__ __launch_bounds__(256) void scan_k(const int* __restrict__ counts,
                                              int* __restrict__ start,
                                              int* __restrict__ cursor) {
    __shared__ int chunk[256];
    const int t = threadIdx.x;
    const int per = (NNODE + 255) / 256;   // 40
    const int base = t * per;

    int sum = 0;
    for (int i = 0; i < per; ++i)
        if (base + i < NNODE) sum += counts[base + i];
    chunk[t] = sum;
    __syncthreads();

#pragma unroll
    for (int off = 1; off < 256; off <<= 1) {
        const int v = (t >= off) ? chunk[t - off] : 0;
        __syncthreads();
        chunk[t] += v;
        __syncthreads();
    }
    if (t == 255) start[NNODE] = chunk[255];

    int acc = chunk[t] - sum;   // exclusive prefix of this thread's chunk
    for (int i = 0; i < per; ++i) {
        int idx = base + i;
        if (idx < NNODE) {
            start[idx] = acc;
            cursor[idx] = acc;
            acc += counts[idx];
        }
    }
}

__global__ void scatter_k(const int* __restrict__ EI, int* __restrict__ cursor,
                          int* __restrict__ elist) {
    int e = blockIdx.x * 256 + threadIdx.x;
    if (e < NTOT) {
        int d = edge_dst(EI, e);
        int pos = atomicAdd(&cursor[d], 1);
        elist[pos] = e;
    }
}

// deterministic order (rank-sort by edge id) + src conversion, fused
__global__ __launch_bounds__(256) void sortsrc_k(const int* __restrict__ EI,
                                                 int* __restrict__ elist,
                                                 const int* __restrict__ start,
                                                 int* __restrict__ elsrc) {
    __shared__ int buf[2048];
    const int d = blockIdx.x;
    const int st = start[d], en = start[d + 1];
    const int deg = en - st;
    const int t = threadIdx.x;

    if (deg > 1 && deg <= 2048) {
        for (int i = t; i < deg; i += 256) buf[i] = elist[st + i];
        __syncthreads();
        for (int i = t; i < deg; i += 256) {
            int id = buf[i], r = 0;
            for (int j = 0; j < deg; ++j) r += (buf[j] < id);
            elist[st + r] = id;
            elsrc[st + r] = edge_src(EI, id);
        }
    } else {
        for (int i = st + t; i < en; i += 256) elsrc[i] = edge_src(EI, elist[i]);
    }
}

// ---------------------------------------------------------------------------
// Fused score + aggregation v6: one wave per dst node, HALF-WAVE per edge,
// DEPTH-2 SOFTWARE-PIPELINED gathers (register rotation A/B + elsrc ahead).
// Lanes 0-31 process even-index edges, 32-63 odd; lane li owns cols 8li..8li+7.
//   z(e)  = Ws2 . relu(Pi[d] + Pj[src e]) + b2   (5-level shfl per 2 edges)
//   acc  += sigmoid(z) * h[src e]
// Step s covers edges (st+2s, st+2s+1); processed strictly in order ->
// deterministic, bit-identical to v5.
// ---------------------------------------------------------------------------
template <bool LAST>
__global__ __launch_bounds__(256) void scoreaggr_k(const unsigned short* __restrict__ PI,
                                                   const unsigned short* __restrict__ PJH,
                                                   const int* __restrict__ elsrc,
                                                   const int* __restrict__ start,
                                                   const float* __restrict__ Ws2,
                                                   const float* __restrict__ bs2,
                                                   float* __restrict__ OUT,
                                                   unsigned short* __restrict__ XB) {
    const int t = threadIdx.x;
    const int lane = t & 63, wid = t >> 6;
    const int li = lane & 31, half = lane >> 5;
    const int d  = __builtin_amdgcn_readfirstlane(blockIdx.x * 4 + wid);
    const int st = __builtin_amdgcn_readfirstlane(start[d]);
    const int en = __builtin_amdgcn_readfirstlane(start[d + 1]);

    float w2[8];
#pragma unroll
    for (int j = 0; j < 8; ++j) w2[j] = Ws2[8 * li + j];
    const float b2 = bs2[0];

    const uint4 piu = *(const uint4*)(PI + (size_t)d * 256 + 8 * li);
    float pi_[8] = {bflo(piu.x), bfhi(piu.x), bflo(piu.y), bfhi(piu.y),
                    bflo(piu.z), bfhi(piu.z), bflo(piu.w), bfhi(piu.w)};

    float acc[8] = {0.f, 0.f, 0.f, 0.f, 0.f, 0.f, 0.f, 0.f};

#define SA_COMPUTE(R0, R1, MASKED)                                              \
    {                                                                           \
        float dot = 0.f;                                                        \
        dot = fmaf(fmaxf(pi_[0] + bflo((R0).x), 0.f), w2[0], dot);              \
        dot = fmaf(fmaxf(pi_[1] + bfhi((R0).x), 0.f), w2[1], dot);              \
        dot = fmaf(fmaxf(pi_[2] + bflo((R0).y), 0.f), w2[2], dot);              \
        dot = fmaf(fmaxf(pi_[3] + bfhi((R0).y), 0.f), w2[3], dot);              \
        dot = fmaf(fmaxf(pi_[4] + bflo((R1).x), 0.f), w2[4], dot);              \
        dot = fmaf(fmaxf(pi_[5] + bfhi((R1).x), 0.f), w2[5], dot);              \
        dot = fmaf(fmaxf(pi_[6] + bflo((R1).y), 0.f), w2[6], dot);              \
        dot = fmaf(fmaxf(pi_[7] + bfhi((R1).y), 0.f), w2[7], dot);              \
        dot += __shfl_xor(dot, 16); dot += __shfl_xor(dot, 8);                  \
        dot += __shfl_xor(dot, 4);  dot += __shfl_xor(dot, 2);                  \
        dot += __shfl_xor(dot, 1);                                              \
        float sc = 1.f / (1.f + __expf(-(dot + b2)));                           \
        if (MASKED) sc = half ? 0.f : sc;                                       \
        acc[0] = fmaf(sc, bflo((R0).z), acc[0]);                                \
        acc[1] = fmaf(sc, bfhi((R0).z), acc[1]);                                \
        acc[2] = fmaf(sc, bflo((R0).w), acc[2]);                                \
        acc[3] = fmaf(sc, bfhi((R0).w), acc[3]);                                \
        acc[4] = fmaf(sc, bflo((R1).z), acc[4]);                                \
        acc[5] = fmaf(sc, bfhi((R1).z), acc[5]);                                \
        acc[6] = fmaf(sc, bflo((R1).w), acc[6]);                                \
        acc[7] = fmaf(sc, bfhi((R1).w), acc[7]);                                \
    }

    const int ns   = (en - st) >> 1;        // full edge pairs (steps)
    const int tail = st + (ns << 1);        // == en (even) or en-1 (odd)

    uint4 A0 = {0,0,0,0}, A1 = {0,0,0,0};   // step s   (compute now)
    uint4 B0 = {0,0,0,0}, B1 = {0,0,0,0};   // step s+1 (in flight)
    int eC = 0;                             // src for step s+2 (address ready)

    if (ns > 0) {
        const int x0 = elsrc[st], x1 = elsrc[st + 1];
        const unsigned short* rp = PJH + (size_t)(half ? x1 : x0) * 512 + 16 * li;
        A0 = *(const uint4*)rp; A1 = *(const uint4*)(rp + 8);
    }
    if (ns > 1) {
        const int x0 = elsrc[st + 2], x1 = elsrc[st + 3];
        const unsigned short* rp = PJH + (size_t)(half ? x1 : x0) * 512 + 16 * li;
        B0 = *(const uint4*)rp; B1 = *(const uint4*)(rp + 8);
    }
    if (ns > 2) {
        const int x0 = elsrc[st + 4], x1 = elsrc[st + 5];
        eC = half ? x1 : x0;
    }

#pragma unroll 2
    for (int s = 0; s < ns; ++s) {
        uint4 C0, C1;
        const bool hasC = (s + 2 < ns);
        if (hasC) {
            const unsigned short* rp = PJH + (size_t)eC * 512 + 16 * li;
            C0 = *(const uint4*)rp; C1 = *(const uint4*)(rp + 8);
        }
        if (s + 3 < ns) {
            const int base = st + ((s + 3) << 1);
            const int x0 = elsrc[base], x1 = elsrc[base + 1];
            eC = half ? x1 : x0;
        }
        SA_COMPUTE(A0, A1, false);
        A0 = B0; A1 = B1;
        if (hasC) { B0 = C0; B1 = C1; }
    }
    if (tail < en) {
        const int s = elsrc[tail];          // both halves load the same edge
        const unsigned short* rp = PJH + (size_t)s * 512 + 16 * li;
        const uint4 T0 = *(const uint4*)rp, T1 = *(const uint4*)(rp + 8);
        SA_COMPUTE(T0, T1, true)            // half-1 contribution masked to 0
    }
#undef SA_COMPUTE

#pragma unroll
    for (int j = 0; j < 8; ++j) acc[j] += __shfl_xor(acc[j], 32);

    if (half == 0) {
        if (LAST) {
            float4* op = (float4*)(OUT + (size_t)d * 256 + 8 * li);
            op[0] = make_float4(acc[0], acc[1], acc[2], acc[3]);
            op[1] = make_float4(acc[4], acc[5], acc[6], acc[7]);
        } else {
            ushort4 v0, v1;
            v0.x = f2bf(fmaxf(acc[0], 0.f)); v0.y = f2bf(fmaxf(acc[1], 0.f));
            v0.z = f2bf(fmaxf(acc[2], 0.f)); v0.w = f2bf(fmaxf(acc[3], 0.f));
            v1.x = f2bf(fmaxf(acc[4], 0.f)); v1.y = f2bf(fmaxf(acc[5], 0.f));
            v1.z = f2bf(fmaxf(acc[6], 0.f)); v1.w = f2bf(fmaxf(acc[7], 0.f));
            ushort4* xp = (ushort4*)(XB + (size_t)d * 256 + 8 * li);
            xp[0] = v0; xp[1] = v1;
        }
    }
}

// ---------------------------------------------------------------------------
extern "C" void kernel_launch(void* const* d_in, const int* in_sizes, int n_in,
                              void* d_out, int out_size, void* d_ws, size_t ws_size,
                              hipStream_t stream) {
    const float* x  = (const float*)d_in[0];
    const int*   ei = (const int*)d_in[1];

    const float* Wl[3]  = {(const float*)d_in[2],  (const float*)d_in[8],  (const float*)d_in[14]};
    const float* bl[3]  = {(const float*)d_in[3],  (const float*)d_in[9],  (const float*)d_in[15]};
    const float* Ws1[3] = {(const float*)d_in[4],  (const float*)d_in[10], (const float*)d_in[16]};
    const float* bs1[3] = {(const float*)d_in[5],  (const float*)d_in[11], (const float*)d_in[17]};
    const float* Ws2[3] = {(const float*)d_in[6],  (const float*)d_in[12], (const float*)d_in[18]};
    const float* bs2[3] = {(const float*)d_in[7],  (const float*)d_in[13], (const float*)d_in[19]};

    float* out = (float*)d_out;

    // workspace layout
    char* p = (char*)d_ws;
    unsigned short* PJH  = (unsigned short*)p; p += (size_t)NPAD * 512 * 2;  // 10.3 MB
    unsigned short* PI   = (unsigned short*)p; p += (size_t)NPAD * 256 * 2;  // 5.1 MB
    unsigned short* XB   = (unsigned short*)p; p += (size_t)NPAD * 256 * 2;  // 5.1 MB
    unsigned short* XB1  = (unsigned short*)p; p += (size_t)NPAD * 64 * 2;   // 1.3 MB
    unsigned short* WCB1 = (unsigned short*)p; p += 768 * 64 * 2;
    unsigned short* WCB2 = (unsigned short*)p; p += 768 * 256 * 2;
    unsigned short* WCB3 = (unsigned short*)p; p += 768 * 256 * 2;
    float* BIAS   = (float*)p; p += 3 * 768 * 4;
    int*   counts = (int*)p;  p += NNODE * 4;
    int*   startp = (int*)p;  p += (NNODE + 4) * 4;
    int*   cursor = (int*)p;  p += NNODE * 4;
    int*   elist  = (int*)p;  p += (size_t)NTOT * 4;
    int*   elsrc  = (int*)p;  p += (size_t)NTOT * 4;

    const int nFlat = (NTOT + 255) / 256;    // 1290

    // fused setup + weight-combine (one dispatch)
    setupcomb_k<<<SETUP_BLKS + 96, 256, 0, stream>>>(
        x, XB1, XB + (size_t)NNODE * 256, counts,
        Wl[0], Wl[1], Wl[2], bl[0], bl[1], bl[2],
        Ws1[0], Ws1[1], Ws1[2], bs1[0], bs1[1], bs1[2],
        WCB1, WCB2, WCB3, BIAS);

    // CSR build (once; graph shared by all 3 layers)
    hist_k<<<nFlat, 256, 0, stream>>>(ei, counts);
    scan_k<<<1, 256, 0, stream>>>(counts, startp, cursor);
    scatter_k<<<nFlat, 256, 0, stream>>>(ei, cursor, elist);
    sortsrc_k<<<NNODE, 256, 0, stream>>>(ei, elist, startp, elsrc);

    const unsigned short* WCBs[3] = {WCB1, WCB2, WCB3};
    for (int L = 0; L < 3; ++L) {
        if (L == 0)
            gemm_k<64><<<dim3(NPAD / 64, 3), 256, 0, stream>>>(XB1, WCBs[0], BIAS, PI, PJH);
        else
            gemm_k<256><<<dim3(NPAD / 64, 3), 256, 0, stream>>>(XB, WCBs[L], BIAS + L * 768, PI, PJH);

        if (L == 2)
            scoreaggr_k<true><<<NNODE / 4, 256, 0, stream>>>(PI, PJH, elsrc, startp,
                                                             Ws2[L], bs2[L], out, nullptr);
        else
            scoreaggr_k<false><<<NNODE / 4, 256, 0, stream>>>(PI, PJH, elsrc, startp,
                                                              Ws2[L], bs2[L], nullptr, XB);
    }
}

// Round 13
// 278.185 us; speedup vs baseline: 50.0533x; 1.0286x over previous
//
#include <hip/hip_runtime.h>
#include <hip/hip_bf16.h>
#include <math.h>

// Problem constants (from reference)
#define NNODE 10000
#define NPAD  10048             // padded to 64-row multiple for MFMA tiles
#define NEDGE 320000
#define NTOT  (NEDGE + NNODE)   // 330000 incl. self loops
#define INC   64
#define C     256               // HID == OUT_C == 256

typedef short bf16x8 __attribute__((ext_vector_type(8)));
typedef float f32x4  __attribute__((ext_vector_type(4)));

union I4B { int4 i4; bf16x8 b; };

__device__ __forceinline__ unsigned short f2bf(float v) {
    __hip_bfloat16 b = __float2bfloat16(v);   // RNE
    return *reinterpret_cast<unsigned short*>(&b);
}
__device__ __forceinline__ float bflo(unsigned u) { return __uint_as_float(u << 16); }
__device__ __forceinline__ float bfhi(unsigned u) { return __uint_as_float(u & 0xffff0000u); }

// VALU DPP add: v += v_from_lane((lane+N) mod 16 within each 16-row).
// row_ror:N ctrl = 0x120+N. dpp_ctrl must be a literal -> template param.
template <int CTRL>
__device__ __forceinline__ float dpp_ror_add(float v) {
    int x = __builtin_amdgcn_update_dpp(0, __float_as_int(v), CTRL, 0xF, 0xF, true);
    return v + __int_as_float(x);
}

// ---------------------------------------------------------------------------
// setupcomb_k: fused one-shot prep (one dispatch)
// Blocks [0, SETUP_BLKS): elementwise setup
// Blocks [SETUP_BLKS, +96): combW — WCB rows [256,768) = bf16(A @ Wl)
// ---------------------------------------------------------------------------
#define SETUP_BLKS 2512   // NPAD*64/256

__global__ __launch_bounds__(256) void setupcomb_k(
        const float* __restrict__ x, unsigned short* __restrict__ XB1,
        unsigned short* __restrict__ XBpad, int* __restrict__ counts,
        const float* __restrict__ Wl1, const float* __restrict__ Wl2,
        const float* __restrict__ Wl3,
        const float* __restrict__ bl1, const float* __restrict__ bl2,
        const float* __restrict__ bl3,
        const float* __restrict__ Ws11, const float* __restrict__ Ws12,
        const float* __restrict__ Ws13,
        const float* __restrict__ bs11, const float* __restrict__ bs12,
        const float* __restrict__ bs13,
        unsigned short* __restrict__ WCB1, unsigned short* __restrict__ WCB2,
        unsigned short* __restrict__ WCB3, float* __restrict__ BIAS) {
    const int t = threadIdx.x;

    if (blockIdx.x < SETUP_BLKS) {
        const int i = blockIdx.x * 256 + t;

        if (i < NPAD * 64) XB1[i] = (i < NNODE * 64) ? f2bf(x[i]) : (unsigned short)0;
        if (i < (NPAD - NNODE) * 256) XBpad[i] = 0;
        if (i < NNODE) counts[i] = 0;

        if (i < 256 * 64) WCB1[i] = f2bf(Wl1[i]);
        else if (i < 256 * 64 + 256 * 256) {
            int i2 = i - 256 * 64; WCB2[i2] = f2bf(Wl2[i2]);
        } else if (i < 256 * 64 + 2 * 256 * 256) {
            int i3 = i - 256 * 64 - 256 * 256; WCB3[i3] = f2bf(Wl3[i3]);
        }

        if (i < 3 * 768) {
            const int L = i / 768, c = i - L * 768;
            const float* bl  = (L == 0) ? bl1  : (L == 1) ? bl2  : bl3;
            const float* Ws1 = (L == 0) ? Ws11 : (L == 1) ? Ws12 : Ws13;
            const float* bs1 = (L == 0) ? bs11 : (L == 1) ? bs12 : bs13;
            float b;
            if (c < 256) b = bl[c];
            else {
                const int cc = c & 255;
                const int off = (c < 512) ? 0 : 256;
                float s = (c < 512) ? bs1[cc] : 0.f;
                for (int m = 0; m < 256; ++m)
                    s = fmaf(Ws1[cc * 512 + off + m], bl[m], s);
                b = s;
            }
            BIAS[L * 768 + c] = b;
        }
        return;
    }

    // ---- combW part ----
    const int bid = blockIdx.x - SETUP_BLKS;   // [0,96)
    const int L = bid >> 5;
    const int rem = bid & 31;
    const int kt = rem >> 3;
    const int rt = rem & 7;
    const int K = (L == 0) ? 64 : 256;
    if (kt * 64 >= K) return;

    const float* Wl  = (L == 0) ? Wl1  : (L == 1) ? Wl2  : Wl3;
    const float* Ws1 = (L == 0) ? Ws11 : (L == 1) ? Ws12 : Ws13;
    unsigned short* WCB = (L == 0) ? WCB1 : (L == 1) ? WCB2 : WCB3;

    __shared__ float As[32][68];
    __shared__ float Bs[32][68];

    const int tr = t >> 4, tk = t & 15;

    float acc[4][4];
#pragma unroll
    for (int i = 0; i < 4; ++i)
#pragma unroll
        for (int j = 0; j < 4; ++j) acc[i][j] = 0.f;

    for (int mb = 0; mb < 256; mb += 32) {
        {
            const int r = t >> 2, mg = t & 3;
            const int gr = rt * 64 + r;
            const int cc = gr & 255;
            const int off = (gr < 256) ? 0 : 256;
            const float* src = Ws1 + (size_t)cc * 512 + off + mb + mg * 8;
            float4 a0 = *(const float4*)src;
            float4 a1 = *(const float4*)(src + 4);
            As[mg * 8 + 0][r] = a0.x; As[mg * 8 + 1][r] = a0.y;
            As[mg * 8 + 2][r] = a0.z; As[mg * 8 + 3][r] = a0.w;
            As[mg * 8 + 4][r] = a1.x; As[mg * 8 + 5][r] = a1.y;
            As[mg * 8 + 6][r] = a1.z; As[mg * 8 + 7][r] = a1.w;
        }
        {
            const int m = t >> 3, kg = t & 7;
            const float* src = Wl + (size_t)(mb + m) * K + kt * 64 + kg * 8;
            *(float4*)&Bs[m][kg * 8]     = *(const float4*)src;
            *(float4*)&Bs[m][kg * 8 + 4] = *(const float4*)(src + 4);
        }
        __syncthreads();

#pragma unroll 8
        for (int m = 0; m < 32; ++m) {
            float4 av = *(const float4*)&As[m][tr * 4];
            float4 bv = *(const float4*)&Bs[m][tk * 4];
            float ax[4] = {av.x, av.y, av.z, av.w};
            float bx[4] = {bv.x, bv.y, bv.z, bv.w};
#pragma unroll
            for (int i = 0; i < 4; ++i)
#pragma unroll
                for (int j = 0; j < 4; ++j)
                    acc[i][j] = fmaf(ax[i], bx[j], acc[i][j]);
        }
        __syncthreads();
    }

#pragma unroll
    for (int i = 0; i < 4; ++i) {
        const int row = 256 + rt * 64 + tr * 4 + i;
#pragma unroll
        for (int j = 0; j < 4; ++j)
            WCB[(size_t)row * K + kt * 64 + tk * 4 + j] = f2bf(acc[i][j]);
    }
}

// ---------------------------------------------------------------------------
// Fused GEMM via bf16 MFMA:  [h | Pi | Pj] = A @ WCB^T + BIAS
// Block: 64 rows x 256 cols (4 waves); grid (NPAD/64, 3); blockIdx.y = group
//   (0: h -> PJH[+256] half, 1: Pi -> PI, 2: Pj -> PJH[+0] half).
// PJH record per node (1 KB): pj[256] bf16 | h[256] bf16  (split layout ->
// contiguous stores across l15 lanes).
// Depth-1 fragment prefetch: loads for ks+1 issued before the MFMAs of ks.
// ---------------------------------------------------------------------------
template <int K>
__global__ __launch_bounds__(256, 2) void gemm_k(const unsigned short* __restrict__ XB,
                                                 const unsigned short* __restrict__ WCB,
                                                 const float* __restrict__ BIAS,
                                                 unsigned short* __restrict__ PI,
                                                 unsigned short* __restrict__ PJH) {
    const int t = threadIdx.x;
    const int lane = t & 63, wid = t >> 6;
    const int l15 = lane & 15, l4 = lane >> 4;
    const int rb = blockIdx.x * 64;
    const int grp = blockIdx.y;                 // 0:h 1:Pi 2:Pj
    const int co = wid * 64;                    // col within group [0,256)

    const unsigned short* pa[4];
#pragma unroll
    for (int m = 0; m < 4; ++m)
        pa[m] = XB + (size_t)(rb + 16 * m + l15) * K + l4 * 8;
    const unsigned short* pb[4];
#pragma unroll
    for (int n = 0; n < 4; ++n)
        pb[n] = WCB + (size_t)(grp * 256 + co + 16 * n + l15) * K + l4 * 8;

    f32x4 acc[4][4];
#pragma unroll
    for (int m = 0; m < 4; ++m)
#pragma unroll
        for (int n = 0; n < 4; ++n) acc[m][n] = (f32x4)(0.f);

    constexpr int NKS = K / 32;
    bf16x8 af[4], bfr[4];
#pragma unroll
    for (int m = 0; m < 4; ++m) { I4B u; u.i4 = *(const int4*)(pa[m]); af[m] = u.b; }
#pragma unroll
    for (int n = 0; n < 4; ++n) { I4B u; u.i4 = *(const int4*)(pb[n]); bfr[n] = u.b; }

#pragma unroll
    for (int ks = 0; ks < NKS; ++ks) {
        bf16x8 naf[4], nbf[4];
        if (ks + 1 < NKS) {
#pragma unroll
            for (int m = 0; m < 4; ++m) {
                I4B u; u.i4 = *(const int4*)(pa[m] + (ks + 1) * 32); naf[m] = u.b;
            }
#pragma unroll
            for (int n = 0; n < 4; ++n) {
                I4B u; u.i4 = *(const int4*)(pb[n] + (ks + 1) * 32); nbf[n] = u.b;
            }
        }
#pragma unroll
        for (int m = 0; m < 4; ++m)
#pragma unroll
            for (int n = 0; n < 4; ++n)
                acc[m][n] = __builtin_amdgcn_mfma_f32_16x16x32_bf16(
                    af[m], bfr[n], acc[m][n], 0, 0, 0);
        if (ks + 1 < NKS) {
#pragma unroll
            for (int m = 0; m < 4; ++m) af[m] = naf[m];
#pragma unroll
            for (int n = 0; n < 4; ++n) bfr[n] = nbf[n];
        }
    }

    float bcol[4];
#pragma unroll
    for (int n = 0; n < 4; ++n) bcol[n] = BIAS[grp * 256 + co + 16 * n + l15];

#pragma unroll
    for (int m = 0; m < 4; ++m) {
        const int row = rb + 16 * m + 4 * l4;
#pragma unroll
        for (int r = 0; r < 4; ++r) {
            if (row + r >= NNODE) continue;
#pragma unroll
            for (int n = 0; n < 4; ++n) {
                const int cc = co + 16 * n + l15;
                const unsigned short v = f2bf(acc[m][n][r] + bcol[n]);
                if (grp == 0)
                    PJH[(size_t)(row + r) * 512 + 256 + cc] = v;   // h half
                else if (grp == 1)
                    PI[(size_t)(row + r) * 256 + cc] = v;
                else
                    PJH[(size_t)(row + r) * 512 + cc] = v;         // pj half
            }
        }
    }
}

// ---------------------------------------------------------------------------
// CSR build
// ---------------------------------------------------------------------------
__device__ __forceinline__ int edge_dst(const int* EI, int e) {
    return (e < NEDGE) ? EI[NEDGE + e] : (e - NEDGE);
}
__device__ __forceinline__ int edge_src(const int* EI, int e) {
    return (e < NEDGE) ? EI[e] : (e - NEDGE);
}

__global__ void hist_k(const int* __restrict__ EI, int* __restrict__ counts) {
    int e = blockIdx.x * 256 + threadIdx.x;
    if (e < NTOT) atomicAdd(&counts[edge_dst(EI, e)], 1);
}

// parallel block-wide scan (Hillis-Steele over 256 chunk sums)
__global__ __launch_bounds__(256) void scan_k(const int* __restrict__ counts,
                                              int* __restrict__ start,
                                              int* __restrict__ cursor) {
    __shared__ int chunk[256];
    const int t = threadIdx.x;
    const int per = (NNODE + 255) / 256;   // 40
    const int base = t * per;

    int sum = 0;
    for (int i = 0; i < per; ++i)
        if (base + i < NNODE) sum += counts[base + i];
    chunk[t] = sum;
    __syncthreads();

#pragma unroll
    for (int off = 1; off < 256; off <<= 1) {
        const int v = (t >= off) ? chunk[t - off] : 0;
        __syncthreads();
        chunk[t] += v;
        __syncthreads();
    }
    if (t == 255) start[NNODE] = chunk[255];

    int acc = chunk[t] - sum;   // exclusive prefix of this thread's chunk
    for (int i = 0; i < per; ++i) {
        int idx = base + i;
        if (idx < NNODE) {
            start[idx] = acc;
            cursor[idx] = acc;
            acc += counts[idx];
        }
    }
}

__global__ void scatter_k(const int* __restrict__ EI, int* __restrict__ cursor,
                          int* __restrict__ elist) {
    int e = blockIdx.x * 256 + threadIdx.x;
    if (e < NTOT) {
        int d = edge_dst(EI, e);
        int pos = atomicAdd(&cursor[d], 1);
        elist[pos] = e;
    }
}

// deterministic order (rank-sort by edge id) + src conversion, fused
__global__ __launch_bounds__(256) void sortsrc_k(const int* __restrict__ EI,
                                                 int* __restrict__ elist,
                                                 const int* __restrict__ start,
                                                 int* __restrict__ elsrc) {
    __shared__ int buf[2048];
    const int d = blockIdx.x;
    const int st = start[d], en = start[d + 1];
    const int deg = en - st;
    const int t = threadIdx.x;

    if (deg > 1 && deg <= 2048) {
        for (int i = t; i < deg; i += 256) buf[i] = elist[st + i];
        __syncthreads();
        for (int i = t; i < deg; i += 256) {
            int id = buf[i], r = 0;
            for (int j = 0; j < deg; ++j) r += (buf[j] < id);
            elist[st + r] = id;
            elsrc[st + r] = edge_src(EI, id);
        }
    } else {
        for (int i = st + t; i < en; i += 256) elsrc[i] = edge_src(EI, elist[i]);
    }
}

// ---------------------------------------------------------------------------
// Fused score + aggregation v7: one wave per dst node, HALF-WAVE per edge,
// depth-2 pipelined gathers, and a VALU-DPP z-reduction:
//   4x v_add_f32 row_ror (1/2/4/8) within each 16-row  (all-lane row sums)
//   + 1 ds_swizzle xor16 (immediate, within 32-group)  (half-wave total)
// replacing 5 dependent ds_bpermute shuffles (~250cy -> ~60cy chain).
// Lanes 0-31 process even-index edges, 32-63 odd; lane li owns cols 8li..8li+7.
// Deterministic (fixed partition + in-order steps).
// ---------------------------------------------------------------------------
template <bool LAST>
__global__ __launch_bounds__(256) void scoreaggr_k(const unsigned short* __restrict__ PI,
                                                   const unsigned short* __restrict__ PJH,
                                                   const int* __restrict__ elsrc,
                                                   const int* __restrict__ start,
                                                   const float* __restrict__ Ws2,
                                                   const float* __restrict__ bs2,
                                                   float* __restrict__ OUT,
                                                   unsigned short* __restrict__ XB) {
    const int t = threadIdx.x;
    const int lane = t & 63, wid = t >> 6;
    const int li = lane & 31, half = lane >> 5;
    const int d  = __builtin_amdgcn_readfirstlane(blockIdx.x * 4 + wid);
    const int st = __builtin_amdgcn_readfirstlane(start[d]);
    const int en = __builtin_amdgcn_readfirstlane(start[d + 1]);

    float w2[8];
#pragma unroll
    for (int j = 0; j < 8; ++j) w2[j] = Ws2[8 * li + j];
    const float b2 = bs2[0];

    const uint4 piu = *(const uint4*)(PI + (size_t)d * 256 + 8 * li);
    float pi_[8] = {bflo(piu.x), bfhi(piu.x), bflo(piu.y), bfhi(piu.y),
                    bflo(piu.z), bfhi(piu.z), bflo(piu.w), bfhi(piu.w)};

    float acc[8] = {0.f, 0.f, 0.f, 0.f, 0.f, 0.f, 0.f, 0.f};

#define SA_COMPUTE(PJ, HV, MASKED)                                              \
    {                                                                           \
        float dot = 0.f;                                                        \
        dot = fmaf(fmaxf(pi_[0] + bflo((PJ).x), 0.f), w2[0], dot);              \
        dot = fmaf(fmaxf(pi_[1] + bfhi((PJ).x), 0.f), w2[1], dot);              \
        dot = fmaf(fmaxf(pi_[2] + bflo((PJ).y), 0.f), w2[2], dot);              \
        dot = fmaf(fmaxf(pi_[3] + bfhi((PJ).y), 0.f), w2[3], dot);              \
        dot = fmaf(fmaxf(pi_[4] + bflo((PJ).z), 0.f), w2[4], dot);              \
        dot = fmaf(fmaxf(pi_[5] + bfhi((PJ).z), 0.f), w2[5], dot);              \
        dot = fmaf(fmaxf(pi_[6] + bflo((PJ).w), 0.f), w2[6], dot);              \
        dot = fmaf(fmaxf(pi_[7] + bfhi((PJ).w), 0.f), w2[7], dot);              \
        dot = dpp_ror_add<0x121>(dot);                                          \
        dot = dpp_ror_add<0x122>(dot);                                          \
        dot = dpp_ror_add<0x124>(dot);                                          \
        dot = dpp_ror_add<0x128>(dot);                                          \
        dot += __int_as_float(__builtin_amdgcn_ds_swizzle(                      \
                   __float_as_int(dot), 0x401F));                               \
        float sc = 1.f / (1.f + __expf(-(dot + b2)));                           \
        if (MASKED) sc = half ? 0.f : sc;                                       \
        acc[0] = fmaf(sc, bflo((HV).x), acc[0]);                                \
        acc[1] = fmaf(sc, bfhi((HV).x), acc[1]);                                \
        acc[2] = fmaf(sc, bflo((HV).y), acc[2]);                                \
        acc[3] = fmaf(sc, bfhi((HV).y), acc[3]);                                \
        acc[4] = fmaf(sc, bflo((HV).z), acc[4]);                                \
        acc[5] = fmaf(sc, bfhi((HV).z), acc[5]);                                \
        acc[6] = fmaf(sc, bflo((HV).w), acc[6]);                                \
        acc[7] = fmaf(sc, bfhi((HV).w), acc[7]);                                \
    }

    const int ns   = (en - st) >> 1;        // full edge pairs (steps)
    const int tail = st + (ns << 1);        // == en (even) or en-1 (odd)

    uint4 A0 = {0,0,0,0}, A1 = {0,0,0,0};   // step s   (pj, h)
    uint4 B0 = {0,0,0,0}, B1 = {0,0,0,0};   // step s+1 (in flight)
    int eC = 0;                             // src for step s+2

    if (ns > 0) {
        const int x0 = elsrc[st], x1 = elsrc[st + 1];
        const unsigned short* rp = PJH + (size_t)(half ? x1 : x0) * 512;
        A0 = *(const uint4*)(rp + 8 * li);
        A1 = *(const uint4*)(rp + 256 + 8 * li);
    }
    if (ns > 1) {
        const int x0 = elsrc[st + 2], x1 = elsrc[st + 3];
        const unsigned short* rp = PJH + (size_t)(half ? x1 : x0) * 512;
        B0 = *(const uint4*)(rp + 8 * li);
        B1 = *(const uint4*)(rp + 256 + 8 * li);
    }
    if (ns > 2) {
        const int x0 = elsrc[st + 4], x1 = elsrc[st + 5];
        eC = half ? x1 : x0;
    }

#pragma unroll 2
    for (int s = 0; s < ns; ++s) {
        uint4 C0, C1;
        const bool hasC = (s + 2 < ns);
        if (hasC) {
            const unsigned short* rp = PJH + (size_t)eC * 512;
            C0 = *(const uint4*)(rp + 8 * li);
            C1 = *(const uint4*)(rp + 256 + 8 * li);
        }
        if (s + 3 < ns) {
            const int base = st + ((s + 3) << 1);
            const int x0 = elsrc[base], x1 = elsrc[base + 1];
            eC = half ? x1 : x0;
        }
        SA_COMPUTE(A0, A1, false);
        A0 = B0; A1 = B1;
        if (hasC) { B0 = C0; B1 = C1; }
    }
    if (tail < en) {
        const int s = elsrc[tail];          // both halves load the same edge
        const unsigned short* rp = PJH + (size_t)s * 512;
        const uint4 T0 = *(const uint4*)(rp + 8 * li);
        const uint4 T1 = *(const uint4*)(rp + 256 + 8 * li);
        SA_COMPUTE(T0, T1, true)            // half-1 contribution masked to 0
    }
#undef SA_COMPUTE

#pragma unroll
    for (int j = 0; j < 8; ++j) acc[j] += __shfl_xor(acc[j], 32);

    if (half == 0) {
        if (LAST) {
            float4* op = (float4*)(OUT + (size_t)d * 256 + 8 * li);
            op[0] = make_float4(acc[0], acc[1], acc[2], acc[3]);
            op[1] = make_float4(acc[4], acc[5], acc[6], acc[7]);
        } else {
            ushort4 v0, v1;
            v0.x = f2bf(fmaxf(acc[0], 0.f)); v0.y = f2bf(fmaxf(acc[1], 0.f));
            v0.z = f2bf(fmaxf(acc[2], 0.f)); v0.w = f2bf(fmaxf(acc[3], 0.f));
            v1.x = f2bf(fmaxf(acc[4], 0.f)); v1.y = f2bf(fmaxf(acc[5], 0.f));
            v1.z = f2bf(fmaxf(acc[6], 0.f)); v1.w = f2bf(fmaxf(acc[7], 0.f));
            ushort4* xp = (ushort4*)(XB + (size_t)d * 256 + 8 * li);
            xp[0] = v0; xp[1] = v1;
        }
    }
}

// ---------------------------------------------------------------------------
extern "C" void kernel_launch(void* const* d_in, const int* in_sizes, int n_in,
                              void* d_out, int out_size, void* d_ws, size_t ws_size,
                              hipStream_t stream) {
    const float* x  = (const float*)d_in[0];
    const int*   ei = (const int*)d_in[1];

    const float* Wl[3]  = {(const float*)d_in[2],  (const float*)d_in[8],  (const float*)d_in[14]};
    const float* bl[3]  = {(const float*)d_in[3],  (const float*)d_in[9],  (const float*)d_in[15]};
    const float* Ws1[3] = {(const float*)d_in[4],  (const float*)d_in[10], (const float*)d_in[16]};
    const float* bs1[3] = {(const float*)d_in[5],  (const float*)d_in[11], (const float*)d_in[17]};
    const float* Ws2[3] = {(const float*)d_in[6],  (const float*)d_in[12], (const float*)d_in[18]};
    const float* bs2[3] = {(const float*)d_in[7],  (const float*)d_in[13], (const float*)d_in[19]};

    float* out = (float*)d_out;

    // workspace layout
    char* p = (char*)d_ws;
    unsigned short* PJH  = (unsigned short*)p; p += (size_t)NPAD * 512 * 2;  // 10.3 MB
    unsigned short* PI   = (unsigned short*)p; p += (size_t)NPAD * 256 * 2;  // 5.1 MB
    unsigned short* XB   = (unsigned short*)p; p += (size_t)NPAD * 256 * 2;  // 5.1 MB
    unsigned short* XB1  = (unsigned short*)p; p += (size_t)NPAD * 64 * 2;   // 1.3 MB
    unsigned short* WCB1 = (unsigned short*)p; p += 768 * 64 * 2;
    unsigned short* WCB2 = (unsigned short*)p; p += 768 * 256 * 2;
    unsigned short* WCB3 = (unsigned short*)p; p += 768 * 256 * 2;
    float* BIAS   = (float*)p; p += 3 * 768 * 4;
    int*   counts = (int*)p;  p += NNODE * 4;
    int*   startp = (int*)p;  p += (NNODE + 4) * 4;
    int*   cursor = (int*)p;  p += NNODE * 4;
    int*   elist  = (int*)p;  p += (size_t)NTOT * 4;
    int*   elsrc  = (int*)p;  p += (size_t)NTOT * 4;

    const int nFlat = (NTOT + 255) / 256;    // 1290

    // fused setup + weight-combine (one dispatch)
    setupcomb_k<<<SETUP_BLKS + 96, 256, 0, stream>>>(
        x, XB1, XB + (size_t)NNODE * 256, counts,
        Wl[0], Wl[1], Wl[2], bl[0], bl[1], bl[2],
        Ws1[0], Ws1[1], Ws1[2], bs1[0], bs1[1], bs1[2],
        WCB1, WCB2, WCB3, BIAS);

    // CSR build (once; graph shared by all 3 layers)
    hist_k<<<nFlat, 256, 0, stream>>>(ei, counts);
    scan_k<<<1, 256, 0, stream>>>(counts, startp, cursor);
    scatter_k<<<nFlat, 256, 0, stream>>>(ei, cursor, elist);
    sortsrc_k<<<NNODE, 256, 0, stream>>>(ei, elist, startp, elsrc);

    const unsigned short* WCBs[3] = {WCB1, WCB2, WCB3};
    for (int L = 0; L < 3; ++L) {
        if (L == 0)
            gemm_k<64><<<dim3(NPAD / 64, 3), 256, 0, stream>>>(XB1, WCBs[0], BIAS, PI, PJH);
        else
            gemm_k<256><<<dim3(NPAD / 64, 3), 256, 0, stream>>>(XB, WCBs[L], BIAS + L * 768, PI, PJH);

        if (L == 2)
            scoreaggr_k<true><<<NNODE / 4, 256, 0, stream>>>(PI, PJH, elsrc, startp,
                                                             Ws2[L], bs2[L], out, nullptr);
        else
            scoreaggr_k<false><<<NNODE / 4, 256, 0, stream>>>(PI, PJH, elsrc, startp,
                                                              Ws2[L], bs2[L], nullptr, XB);
    }
}

// Round 14
// 277.873 us; speedup vs baseline: 50.1096x; 1.0011x over previous
//
#include <hip/hip_runtime.h>
#include <hip/hip_bf16.h>
#include <math.h>

// Problem constants (from reference)
#define NNODE 10000
#define NPAD  10048             // padded to 64-row multiple for MFMA tiles
#define NEDGE 320000
#define NTOT  (NEDGE + NNODE)   // 330000 incl. self loops
#define INC   64
#define C     256               // HID == OUT_C == 256

typedef short bf16x8 __attribute__((ext_vector_type(8)));
typedef float f32x4  __attribute__((ext_vector_type(4)));

union I4B { int4 i4; bf16x8 b; };

__device__ __forceinline__ unsigned short f2bf(float v) {
    __hip_bfloat16 b = __float2bfloat16(v);   // RNE
    return *reinterpret_cast<unsigned short*>(&b);
}
__device__ __forceinline__ float bflo(unsigned u) { return __uint_as_float(u << 16); }
__device__ __forceinline__ float bfhi(unsigned u) { return __uint_as_float(u & 0xffff0000u); }

// VALU DPP add: v += v_from_lane((lane+N) mod 16 within each 16-row).
// row_ror:N ctrl = 0x120+N. dpp_ctrl must be a literal -> template param.
template <int CTRL>
__device__ __forceinline__ float dpp_ror_add(float v) {
    int x = __builtin_amdgcn_update_dpp(0, __float_as_int(v), CTRL, 0xF, 0xF, true);
    return v + __int_as_float(x);
}

// ---------------------------------------------------------------------------
// setupcomb_k: fused one-shot prep (one dispatch)
// Blocks [0, SETUP_BLKS): elementwise setup
// Blocks [SETUP_BLKS, +96): combW — WCB rows [256,768) = bf16(A @ Wl)
// ---------------------------------------------------------------------------
#define SETUP_BLKS 2512   // NPAD*64/256

__global__ __launch_bounds__(256) void setupcomb_k(
        const float* __restrict__ x, unsigned short* __restrict__ XB1,
        unsigned short* __restrict__ XBpad, int* __restrict__ counts,
        const float* __restrict__ Wl1, const float* __restrict__ Wl2,
        const float* __restrict__ Wl3,
        const float* __restrict__ bl1, const float* __restrict__ bl2,
        const float* __restrict__ bl3,
        const float* __restrict__ Ws11, const float* __restrict__ Ws12,
        const float* __restrict__ Ws13,
        const float* __restrict__ bs11, const float* __restrict__ bs12,
        const float* __restrict__ bs13,
        unsigned short* __restrict__ WCB1, unsigned short* __restrict__ WCB2,
        unsigned short* __restrict__ WCB3, float* __restrict__ BIAS) {
    const int t = threadIdx.x;

    if (blockIdx.x < SETUP_BLKS) {
        const int i = blockIdx.x * 256 + t;

        if (i < NPAD * 64) XB1[i] = (i < NNODE * 64) ? f2bf(x[i]) : (unsigned short)0;
        if (i < (NPAD - NNODE) * 256) XBpad[i] = 0;
        if (i < NNODE) counts[i] = 0;

        if (i < 256 * 64) WCB1[i] = f2bf(Wl1[i]);
        else if (i < 256 * 64 + 256 * 256) {
            int i2 = i - 256 * 64; WCB2[i2] = f2bf(Wl2[i2]);
        } else if (i < 256 * 64 + 2 * 256 * 256) {
            int i3 = i - 256 * 64 - 256 * 256; WCB3[i3] = f2bf(Wl3[i3]);
        }

        if (i < 3 * 768) {
            const int L = i / 768, c = i - L * 768;
            const float* bl  = (L == 0) ? bl1  : (L == 1) ? bl2  : bl3;
            const float* Ws1 = (L == 0) ? Ws11 : (L == 1) ? Ws12 : Ws13;
            const float* bs1 = (L == 0) ? bs11 : (L == 1) ? bs12 : bs13;
            float b;
            if (c < 256) b = bl[c];
            else {
                const int cc = c & 255;
                const int off = (c < 512) ? 0 : 256;
                float s = (c < 512) ? bs1[cc] : 0.f;
                for (int m = 0; m < 256; ++m)
                    s = fmaf(Ws1[cc * 512 + off + m], bl[m], s);
                b = s;
            }
            BIAS[L * 768 + c] = b;
        }
        return;
    }

    // ---- combW part ----
    const int bid = blockIdx.x - SETUP_BLKS;   // [0,96)
    const int L = bid >> 5;
    const int rem = bid & 31;
    const int kt = rem >> 3;
    const int rt = rem & 7;
    const int K = (L == 0) ? 64 : 256;
    if (kt * 64 >= K) return;

    const float* Wl  = (L == 0) ? Wl1  : (L == 1) ? Wl2  : Wl3;
    const float* Ws1 = (L == 0) ? Ws11 : (L == 1) ? Ws12 : Ws13;
    unsigned short* WCB = (L == 0) ? WCB1 : (L == 1) ? WCB2 : WCB3;

    __shared__ float As[32][68];
    __shared__ float Bs[32][68];

    const int tr = t >> 4, tk = t & 15;

    float acc[4][4];
#pragma unroll
    for (int i = 0; i < 4; ++i)
#pragma unroll
        for (int j = 0; j < 4; ++j) acc[i][j] = 0.f;

    for (int mb = 0; mb < 256; mb += 32) {
        {
            const int r = t >> 2, mg = t & 3;
            const int gr = rt * 64 + r;
            const int cc = gr & 255;
            const int off = (gr < 256) ? 0 : 256;
            const float* src = Ws1 + (size_t)cc * 512 + off + mb + mg * 8;
            float4 a0 = *(const float4*)src;
            float4 a1 = *(const float4*)(src + 4);
            As[mg * 8 + 0][r] = a0.x; As[mg * 8 + 1][r] = a0.y;
            As[mg * 8 + 2][r] = a0.z; As[mg * 8 + 3][r] = a0.w;
            As[mg * 8 + 4][r] = a1.x; As[mg * 8 + 5][r] = a1.y;
            As[mg * 8 + 6][r] = a1.z; As[mg * 8 + 7][r] = a1.w;
        }
        {
            const int m = t >> 3, kg = t & 7;
            const float* src = Wl + (size_t)(mb + m) * K + kt * 64 + kg * 8;
            *(float4*)&Bs[m][kg * 8]     = *(const float4*)src;
            *(float4*)&Bs[m][kg * 8 + 4] = *(const float4*)(src + 4);
        }
        __syncthreads();

#pragma unroll 8
        for (int m = 0; m < 32; ++m) {
            float4 av = *(const float4*)&As[m][tr * 4];
            float4 bv = *(const float4*)&Bs[m][tk * 4];
            float ax[4] = {av.x, av.y, av.z, av.w};
            float bx[4] = {bv.x, bv.y, bv.z, bv.w};
#pragma unroll
            for (int i = 0; i < 4; ++i)
#pragma unroll
                for (int j = 0; j < 4; ++j)
                    acc[i][j] = fmaf(ax[i], bx[j], acc[i][j]);
        }
        __syncthreads();
    }

#pragma unroll
    for (int i = 0; i < 4; ++i) {
        const int row = 256 + rt * 64 + tr * 4 + i;
#pragma unroll
        for (int j = 0; j < 4; ++j)
            WCB[(size_t)row * K + kt * 64 + tk * 4 + j] = f2bf(acc[i][j]);
    }
}

// ---------------------------------------------------------------------------
// Fused GEMM via bf16 MFMA:  [h | Pi | Pj] = A @ WCB^T + BIAS
// Block: 64 rows x 256 cols (4 waves); grid (NPAD/64, 3); blockIdx.y = group
//   (0: h -> PJH[+256] half, 1: Pi -> PI, 2: Pj -> PJH[+0] half).
// PJH record per node (1 KB): pj[256] bf16 | h[256] bf16 (split layout).
// Depth-1 fragment prefetch; min 3 blocks/CU for latency hiding.
// ---------------------------------------------------------------------------
template <int K>
__global__ __launch_bounds__(256, 3) void gemm_k(const unsigned short* __restrict__ XB,
                                                 const unsigned short* __restrict__ WCB,
                                                 const float* __restrict__ BIAS,
                                                 unsigned short* __restrict__ PI,
                                                 unsigned short* __restrict__ PJH) {
    const int t = threadIdx.x;
    const int lane = t & 63, wid = t >> 6;
    const int l15 = lane & 15, l4 = lane >> 4;
    const int rb = blockIdx.x * 64;
    const int grp = blockIdx.y;                 // 0:h 1:Pi 2:Pj
    const int co = wid * 64;                    // col within group [0,256)

    const unsigned short* pa[4];
#pragma unroll
    for (int m = 0; m < 4; ++m)
        pa[m] = XB + (size_t)(rb + 16 * m + l15) * K + l4 * 8;
    const unsigned short* pb[4];
#pragma unroll
    for (int n = 0; n < 4; ++n)
        pb[n] = WCB + (size_t)(grp * 256 + co + 16 * n + l15) * K + l4 * 8;

    f32x4 acc[4][4];
#pragma unroll
    for (int m = 0; m < 4; ++m)
#pragma unroll
        for (int n = 0; n < 4; ++n) acc[m][n] = (f32x4)(0.f);

    constexpr int NKS = K / 32;
    bf16x8 af[4], bfr[4];
#pragma unroll
    for (int m = 0; m < 4; ++m) { I4B u; u.i4 = *(const int4*)(pa[m]); af[m] = u.b; }
#pragma unroll
    for (int n = 0; n < 4; ++n) { I4B u; u.i4 = *(const int4*)(pb[n]); bfr[n] = u.b; }

#pragma unroll
    for (int ks = 0; ks < NKS; ++ks) {
        bf16x8 naf[4], nbf[4];
        if (ks + 1 < NKS) {
#pragma unroll
            for (int m = 0; m < 4; ++m) {
                I4B u; u.i4 = *(const int4*)(pa[m] + (ks + 1) * 32); naf[m] = u.b;
            }
#pragma unroll
            for (int n = 0; n < 4; ++n) {
                I4B u; u.i4 = *(const int4*)(pb[n] + (ks + 1) * 32); nbf[n] = u.b;
            }
        }
#pragma unroll
        for (int m = 0; m < 4; ++m)
#pragma unroll
            for (int n = 0; n < 4; ++n)
                acc[m][n] = __builtin_amdgcn_mfma_f32_16x16x32_bf16(
                    af[m], bfr[n], acc[m][n], 0, 0, 0);
        if (ks + 1 < NKS) {
#pragma unroll
            for (int m = 0; m < 4; ++m) af[m] = naf[m];
#pragma unroll
            for (int n = 0; n < 4; ++n) bfr[n] = nbf[n];
        }
    }

    float bcol[4];
#pragma unroll
    for (int n = 0; n < 4; ++n) bcol[n] = BIAS[grp * 256 + co + 16 * n + l15];

#pragma unroll
    for (int m = 0; m < 4; ++m) {
        const int row = rb + 16 * m + 4 * l4;
#pragma unroll
        for (int r = 0; r < 4; ++r) {
            if (row + r >= NNODE) continue;
#pragma unroll
            for (int n = 0; n < 4; ++n) {
                const int cc = co + 16 * n + l15;
                const unsigned short v = f2bf(acc[m][n][r] + bcol[n]);
                if (grp == 0)
                    PJH[(size_t)(row + r) * 512 + 256 + cc] = v;   // h half
                else if (grp == 1)
                    PI[(size_t)(row + r) * 256 + cc] = v;
                else
                    PJH[(size_t)(row + r) * 512 + cc] = v;         // pj half
            }
        }
    }
}

// ---------------------------------------------------------------------------
// CSR build
// ---------------------------------------------------------------------------
__device__ __forceinline__ int edge_dst(const int* EI, int e) {
    return (e < NEDGE) ? EI[NEDGE + e] : (e - NEDGE);
}
__device__ __forceinline__ int edge_src(const int* EI, int e) {
    return (e < NEDGE) ? EI[e] : (e - NEDGE);
}

__global__ void hist_k(const int* __restrict__ EI, int* __restrict__ counts) {
    int e = blockIdx.x * 256 + threadIdx.x;
    if (e < NTOT) atomicAdd(&counts[edge_dst(EI, e)], 1);
}

// parallel block-wide scan (Hillis-Steele over 256 chunk sums)
__global__ __launch_bounds__(256) void scan_k(const int* __restrict__ counts,
                                              int* __restrict__ start,
                                              int* __restrict__ cursor) {
    __shared__ int chunk[256];
    const int t = threadIdx.x;
    const int per = (NNODE + 255) / 256;   // 40
    const int base = t * per;

    int sum = 0;
    for (int i = 0; i < per; ++i)
        if (base + i < NNODE) sum += counts[base + i];
    chunk[t] = sum;
    __syncthreads();

#pragma unroll
    for (int off = 1; off < 256; off <<= 1) {
        const int v = (t >= off) ? chunk[t - off] : 0;
        __syncthreads();
        chunk[t] += v;
        __syncthreads();
    }
    if (t == 255) start[NNODE] = chunk[255];

    int acc = chunk[t] - sum;   // exclusive prefix of this thread's chunk
    for (int i = 0; i < per; ++i) {
        int idx = base + i;
        if (idx < NNODE) {
            start[idx] = acc;
            cursor[idx] = acc;
            acc += counts[idx];
        }
    }
}

__global__ void scatter_k(const int* __restrict__ EI, int* __restrict__ cursor,
                          int* __restrict__ elist) {
    int e = blockIdx.x * 256 + threadIdx.x;
    if (e < NTOT) {
        int d = edge_dst(EI, e);
        int pos = atomicAdd(&cursor[d], 1);
        elist[pos] = e;
    }
}

// deterministic order (rank-sort by edge id) + src conversion, fused.
// v2: 8 nodes per block, one 32-lane group per node (deg <= 256 via LDS);
// block-wide fallback pass for 256 < deg <= 2048 (same envelope as before).
__global__ __launch_bounds__(256) void sortsrc_k(const int* __restrict__ EI,
                                                 int* __restrict__ elist,
                                                 const int* __restrict__ start,
                                                 int* __restrict__ elsrc) {
    __shared__ int buf[2048];
    const int t = threadIdx.x;
    const int g = t >> 5, li = t & 31;
    const int d = blockIdx.x * 8 + g;
    const int st = start[d], en = start[d + 1];
    const int deg = en - st;
    int* mybuf = buf + g * 256;

    if (deg >= 1 && deg <= 256) {
        for (int i = li; i < deg; i += 32) mybuf[i] = elist[st + i];
        // same-wave program order: stores above visible to the reads below
        for (int i = li; i < deg; i += 32) {
            const int id = mybuf[i];
            int r = 0;
            for (int j = 0; j < deg; ++j) r += (mybuf[j] < id);
            elist[st + r] = id;
            elsrc[st + r] = edge_src(EI, id);
        }
    }
    __syncthreads();

    // rare big buckets: block-cooperative rank-sort
    for (int gg = 0; gg < 8; ++gg) {
        const int dd = blockIdx.x * 8 + gg;
        const int st2 = start[dd], en2 = start[dd + 1];
        const int dg = en2 - st2;
        if (dg > 256 && dg <= 2048) {
            __syncthreads();
            for (int i = t; i < dg; i += 256) buf[i] = elist[st2 + i];
            __syncthreads();
            for (int i = t; i < dg; i += 256) {
                const int id = buf[i];
                int r = 0;
                for (int j = 0; j < dg; ++j) r += (buf[j] < id);
                elist[st2 + r] = id;
                elsrc[st2 + r] = edge_src(EI, id);
            }
            __syncthreads();
        }
    }
}

// ---------------------------------------------------------------------------
// Fused score + aggregation v7: one wave per dst node, HALF-WAVE per edge,
// depth-2 pipelined gathers, VALU-DPP z-reduction (4x row_ror + xor16).
// Deterministic (fixed partition + in-order steps).
// ---------------------------------------------------------------------------
template <bool LAST>
__global__ __launch_bounds__(256) void scoreaggr_k(const unsigned short* __restrict__ PI,
                                                   const unsigned short* __restrict__ PJH,
                                                   const int* __restrict__ elsrc,
                                                   const int* __restrict__ start,
                                                   const float* __restrict__ Ws2,
                                                   const float* __restrict__ bs2,
                                                   float* __restrict__ OUT,
                                                   unsigned short* __restrict__ XB) {
    const int t = threadIdx.x;
    const int lane = t & 63, wid = t >> 6;
    const int li = lane & 31, half = lane >> 5;
    const int d  = __builtin_amdgcn_readfirstlane(blockIdx.x * 4 + wid);
    const int st = __builtin_amdgcn_readfirstlane(start[d]);
    const int en = __builtin_amdgcn_readfirstlane(start[d + 1]);

    float w2[8];
#pragma unroll
    for (int j = 0; j < 8; ++j) w2[j] = Ws2[8 * li + j];
    const float b2 = bs2[0];

    const uint4 piu = *(const uint4*)(PI + (size_t)d * 256 + 8 * li);
    float pi_[8] = {bflo(piu.x), bfhi(piu.x), bflo(piu.y), bfhi(piu.y),
                    bflo(piu.z), bfhi(piu.z), bflo(piu.w), bfhi(piu.w)};

    float acc[8] = {0.f, 0.f, 0.f, 0.f, 0.f, 0.f, 0.f, 0.f};

#define SA_COMPUTE(PJ, HV, MASKED)                                              \
    {                                                                           \
        float dot = 0.f;                                                        \
        dot = fmaf(fmaxf(pi_[0] + bflo((PJ).x), 0.f), w2[0], dot);              \
        dot = fmaf(fmaxf(pi_[1] + bfhi((PJ).x), 0.f), w2[1], dot);              \
        dot = fmaf(fmaxf(pi_[2] + bflo((PJ).y), 0.f), w2[2], dot);              \
        dot = fmaf(fmaxf(pi_[3] + bfhi((PJ).y), 0.f), w2[3], dot);              \
        dot = fmaf(fmaxf(pi_[4] + bflo((PJ).z), 0.f), w2[4], dot);              \
        dot = fmaf(fmaxf(pi_[5] + bfhi((PJ).z), 0.f), w2[5], dot);              \
        dot = fmaf(fmaxf(pi_[6] + bflo((PJ).w), 0.f), w2[6], dot);              \
        dot = fmaf(fmaxf(pi_[7] + bfhi((PJ).w), 0.f), w2[7], dot);              \
        dot = dpp_ror_add<0x121>(dot);                                          \
        dot = dpp_ror_add<0x122>(dot);                                          \
        dot = dpp_ror_add<0x124>(dot);                                          \
        dot = dpp_ror_add<0x128>(dot);                                          \
        dot += __int_as_float(__builtin_amdgcn_ds_swizzle(                      \
                   __float_as_int(dot), 0x401F));                               \
        float sc = 1.f / (1.f + __expf(-(dot + b2)));                           \
        if (MASKED) sc = half ? 0.f : sc;                                       \
        acc[0] = fmaf(sc, bflo((HV).x), acc[0]);                                \
        acc[1] = fmaf(sc, bfhi((HV).x), acc[1]);                                \
        acc[2] = fmaf(sc, bflo((HV).y), acc[2]);                                \
        acc[3] = fmaf(sc, bfhi((HV).y), acc[3]);                                \
        acc[4] = fmaf(sc, bflo((HV).z), acc[4]);                                \
        acc[5] = fmaf(sc, bfhi((HV).z), acc[5]);                                \
        acc[6] = fmaf(sc, bflo((HV).w), acc[6]);                                \
        acc[7] = fmaf(sc, bfhi((HV).w), acc[7]);                                \
    }

    const int ns   = (en - st) >> 1;        // full edge pairs (steps)
    const int tail = st + (ns << 1);        // == en (even) or en-1 (odd)

    uint4 A0 = {0,0,0,0}, A1 = {0,0,0,0};   // step s   (pj, h)
    uint4 B0 = {0,0,0,0}, B1 = {0,0,0,0};   // step s+1 (in flight)
    int eC = 0;                             // src for step s+2

    if (ns > 0) {
        const int x0 = elsrc[st], x1 = elsrc[st + 1];
        const unsigned short* rp = PJH + (size_t)(half ? x1 : x0) * 512;
        A0 = *(const uint4*)(rp + 8 * li);
        A1 = *(const uint4*)(rp + 256 + 8 * li);
    }
    if (ns > 1) {
        const int x0 = elsrc[st + 2], x1 = elsrc[st + 3];
        const unsigned short* rp = PJH + (size_t)(half ? x1 : x0) * 512;
        B0 = *(const uint4*)(rp + 8 * li);
        B1 = *(const uint4*)(rp + 256 + 8 * li);
    }
    if (ns > 2) {
        const int x0 = elsrc[st + 4], x1 = elsrc[st + 5];
        eC = half ? x1 : x0;
    }

#pragma unroll 2
    for (int s = 0; s < ns; ++s) {
        uint4 C0, C1;
        const bool hasC = (s + 2 < ns);
        if (hasC) {
            const unsigned short* rp = PJH + (size_t)eC * 512;
            C0 = *(const uint4*)(rp + 8 * li);
            C1 = *(const uint4*)(rp + 256 + 8 * li);
        }
        if (s + 3 < ns) {
            const int base = st + ((s + 3) << 1);
            const int x0 = elsrc[base], x1 = elsrc[base + 1];
            eC = half ? x1 : x0;
        }
        SA_COMPUTE(A0, A1, false);
        A0 = B0; A1 = B1;
        if (hasC) { B0 = C0; B1 = C1; }
    }
    if (tail < en) {
        const int s = elsrc[tail];          // both halves load the same edge
        const unsigned short* rp = PJH + (size_t)s * 512;
        const uint4 T0 = *(const uint4*)(rp + 8 * li);
        const uint4 T1 = *(const uint4*)(rp + 256 + 8 * li);
        SA_COMPUTE(T0, T1, true)            // half-1 contribution masked to 0
    }
#undef SA_COMPUTE

#pragma unroll
    for (int j = 0; j < 8; ++j) acc[j] += __shfl_xor(acc[j], 32);

    if (half == 0) {
        if (LAST) {
            float4* op = (float4*)(OUT + (size_t)d * 256 + 8 * li);
            op[0] = make_float4(acc[0], acc[1], acc[2], acc[3]);
            op[1] = make_float4(acc[4], acc[5], acc[6], acc[7]);
        } else {
            ushort4 v0, v1;
            v0.x = f2bf(fmaxf(acc[0], 0.f)); v0.y = f2bf(fmaxf(acc[1], 0.f));
            v0.z = f2bf(fmaxf(acc[2], 0.f)); v0.w = f2bf(fmaxf(acc[3], 0.f));
            v1.x = f2bf(fmaxf(acc[4], 0.f)); v1.y = f2bf(fmaxf(acc[5], 0.f));
            v1.z = f2bf(fmaxf(acc[6], 0.f)); v1.w = f2bf(fmaxf(acc[7], 0.f));
            ushort4* xp = (ushort4*)(XB + (size_t)d * 256 + 8 * li);
            xp[0] = v0; xp[1] = v1;
        }
    }
}

// ---------------------------------------------------------------------------
extern "C" void kernel_launch(void* const* d_in, const int* in_sizes, int n_in,
                              void* d_out, int out_size, void* d_ws, size_t ws_size,
                              hipStream_t stream) {
    const float* x  = (const float*)d_in[0];
    const int*   ei = (const int*)d_in[1];

    const float* Wl[3]  = {(const float*)d_in[2],  (const float*)d_in[8],  (const float*)d_in[14]};
    const float* bl[3]  = {(const float*)d_in[3],  (const float*)d_in[9],  (const float*)d_in[15]};
    const float* Ws1[3] = {(const float*)d_in[4],  (const float*)d_in[10], (const float*)d_in[16]};
    const float* bs1[3] = {(const float*)d_in[5],  (const float*)d_in[11], (const float*)d_in[17]};
    const float* Ws2[3] = {(const float*)d_in[6],  (const float*)d_in[12], (const float*)d_in[18]};
    const float* bs2[3] = {(const float*)d_in[7],  (const float*)d_in[13], (const float*)d_in[19]};

    float* out = (float*)d_out;

    // workspace layout
    char* p = (char*)d_ws;
    unsigned short* PJH  = (unsigned short*)p; p += (size_t)NPAD * 512 * 2;  // 10.3 MB
    unsigned short* PI   = (unsigned short*)p; p += (size_t)NPAD * 256 * 2;  // 5.1 MB
    unsigned short* XB   = (unsigned short*)p; p += (size_t)NPAD * 256 * 2;  // 5.1 MB
    unsigned short* XB1  = (unsigned short*)p; p += (size_t)NPAD * 64 * 2;   // 1.3 MB
    unsigned short* WCB1 = (unsigned short*)p; p += 768 * 64 * 2;
    unsigned short* WCB2 = (unsigned short*)p; p += 768 * 256 * 2;
    unsigned short* WCB3 = (unsigned short*)p; p += 768 * 256 * 2;
    float* BIAS   = (float*)p; p += 3 * 768 * 4;
    int*   counts = (int*)p;  p += NNODE * 4;
    int*   startp = (int*)p;  p += (NNODE + 4) * 4;
    int*   cursor = (int*)p;  p += NNODE * 4;
    int*   elist  = (int*)p;  p += (size_t)NTOT * 4;
    int*   elsrc  = (int*)p;  p += (size_t)NTOT * 4;

    const int nFlat = (NTOT + 255) / 256;    // 1290

    // fused setup + weight-combine (one dispatch)
    setupcomb_k<<<SETUP_BLKS + 96, 256, 0, stream>>>(
        x, XB1, XB + (size_t)NNODE * 256, counts,
        Wl[0], Wl[1], Wl[2], bl[0], bl[1], bl[2],
        Ws1[0], Ws1[1], Ws1[2], bs1[0], bs1[1], bs1[2],
        WCB1, WCB2, WCB3, BIAS);

    // CSR build (once; graph shared by all 3 layers)
    hist_k<<<nFlat, 256, 0, stream>>>(ei, counts);
    scan_k<<<1, 256, 0, stream>>>(counts, startp, cursor);
    scatter_k<<<nFlat, 256, 0, stream>>>(ei, cursor, elist);
    sortsrc_k<<<NNODE / 8, 256, 0, stream>>>(ei, elist, startp, elsrc);

    const unsigned short* WCBs[3] = {WCB1, WCB2, WCB3};
    for (int L = 0; L < 3; ++L) {
        if (L == 0)
            gemm_k<64><<<dim3(NPAD / 64, 3), 256, 0, stream>>>(XB1, WCBs[0], BIAS, PI, PJH);
        else
            gemm_k<256><<<dim3(NPAD / 64, 3), 256, 0, stream>>>(XB, WCBs[L], BIAS + L * 768, PI, PJH);

        if (L == 2)
            scoreaggr_k<true><<<NNODE / 4, 256, 0, stream>>>(PI, PJH, elsrc, startp,
                                                             Ws2[L], bs2[L], out, nullptr);
        else
            scoreaggr_k<false><<<NNODE / 4, 256, 0, stream>>>(PI, PJH, elsrc, startp,
                                                              Ws2[L], bs2[L], nullptr, XB);
    }
}